// Round 4
// baseline (1343.707 us; speedup 1.0000x reference)
//
#include <hip/hip_runtime.h>
#include <hip/hip_bf16.h>
#include <cmath>

// ---------------------------------------------------------------------------
// Pipeline: y1 = bn_relu(dcn(x, w_off1, b_off1, w1, b1))        (4,128,64,64)
//           up = up_depthwise(y1, w_up, f=2)                    (4,128,128,128)
//           out = bn_relu(dcn(up, w_off2, b_off2, w2, b2))      (4,128,128,128)
// DCN GEMM on mfma_f32_16x16x32_bf16 with split-bf16 (hi/lo, 3 products).
// Workspace: om1 | y1 | up | om2 ; w1-split parked in `up` (dead until
// upsample), w2-split parked in `y1` (dead after upsample).
// ---------------------------------------------------------------------------

#define EPSV 1e-5f

typedef __attribute__((ext_vector_type(8))) short short8;
typedef __attribute__((ext_vector_type(4))) float f32x4;

__device__ __forceinline__ ushort f2bf(float f) {
    union { float f; uint u; } v; v.f = f;
    const uint r = v.u + 0x7fffu + ((v.u >> 16) & 1u);   // RNE
    return (ushort)(r >> 16);
}
__device__ __forceinline__ float bf2f(ushort h) {
    union { uint u; float f; } v; v.u = ((uint)h) << 16;
    return v.f;
}

// ---------------- weight split: fp32 -> bf16 hi/lo --------------------------
__global__ __launch_bounds__(256) void wsplit_kernel(
    const float* __restrict__ w, ushort* __restrict__ hi,
    ushort* __restrict__ lo, int n)
{
    const int i = blockIdx.x * 256 + threadIdx.x;
    if (i >= n) return;
    const float f = w[i];
    const ushort h = f2bf(f);
    hi[i] = h;
    lo[i] = f2bf(f - bf2f(h));
}

// ---------------- offset conv: 3x3, pad 1, 27 output channels ---------------
template <int CIN, int HH, int WW, int SPLIT, int CC>
__global__ __launch_bounds__(WW * SPLIT) void conv_off_kernel(
    const float* __restrict__ in,    // (B, CIN, HH, WW)
    const float* __restrict__ wt,    // (27, CIN, 3, 3)
    const float* __restrict__ bias,  // (27)
    float* __restrict__ om)          // (B, 27, HH, WW)
{
    constexpr int POS  = WW;
    constexpr int NT   = WW * SPLIT;
    constexpr int CPG  = CIN / SPLIT;
    constexpr int NCH  = CPG / CC;
    constexpr int SLABN = SPLIT * CC * 3 * POS;
    constexpr int REDN  = 27 * SPLIT * POS;
    constexpr int SMEMN = (SLABN > REDN) ? SLABN : REDN;

    __shared__ __align__(16) float smem[SMEMN];
    float* slab = smem;
    float* red  = smem;

    const int tid = threadIdx.x;
    const int pos = tid & (POS - 1);
    const int g   = tid / POS;
    const int row = blockIdx.x;
    const int b   = blockIdx.y;

    const float* ib = in + (size_t)b * CIN * HH * WW;
    const int cbs = __builtin_amdgcn_readfirstlane(g * CPG);

    float acc[27];
#pragma unroll
    for (int o = 0; o < 27; ++o) acc[o] = 0.f;

    for (int ch = 0; ch < NCH; ++ch) {
        const int c0 = ch * CC;
        for (int i = tid; i < SLABN; i += NT) {
            const int gg = i / (CC * 3 * POS);
            const int r1 = i - gg * (CC * 3 * POS);
            const int cc = r1 / (3 * POS);
            const int r2 = r1 - cc * 3 * POS;
            const int rr = r2 / POS;
            const int px = r2 - rr * POS;
            const int c  = gg * CPG + c0 + cc;
            const int iy = row + rr - 1;
            float v = 0.f;
            if (iy >= 0 && iy < HH) v = ib[((size_t)c * HH + iy) * WW + px];
            slab[i] = v;
        }
        __syncthreads();

        const float* myslab = slab + g * (CC * 3 * POS);
        for (int cc = 0; cc < CC; ++cc) {
            const float* sl = myslab + cc * 3 * POS;
            float v[9];
            const int xm = (pos > 0) ? pos - 1 : 0;
            const int xp = (pos < POS - 1) ? pos + 1 : POS - 1;
#pragma unroll
            for (int r = 0; r < 3; ++r) {
                const float tl = sl[r * POS + xm];
                const float tc = sl[r * POS + pos];
                const float tr = sl[r * POS + xp];
                v[r * 3 + 0] = (pos > 0) ? tl : 0.f;
                v[r * 3 + 1] = tc;
                v[r * 3 + 2] = (pos < POS - 1) ? tr : 0.f;
            }
            const float* wp = wt + (size_t)(cbs + c0 + cc) * 9;
#pragma unroll
            for (int o = 0; o < 27; ++o) {
                const float* w9 = wp + (size_t)o * CIN * 9;
#pragma unroll
                for (int k = 0; k < 9; ++k)
                    acc[o] = fmaf(w9[k], v[k], acc[o]);
            }
        }
        __syncthreads();
    }

#pragma unroll
    for (int o = 0; o < 27; ++o) red[(o * SPLIT + g) * POS + pos] = acc[o];
    __syncthreads();

    float* ob = om + (size_t)b * 27 * HH * WW + (size_t)row * WW;
    for (int i = tid; i < 27 * POS; i += NT) {
        const int o  = i / POS;
        const int px = i - o * POS;
        float s = bias[o];
#pragma unroll
        for (int gg = 0; gg < SPLIT; ++gg)
            s += red[(o * SPLIT + gg) * POS + px];
        ob[(size_t)o * HH * WW + px] = s;
    }
}

// ---------------- bilinear sampler: one KC=32 chunk into LDS (hi/lo bf16) ---
// Branchless: 4 unconditional clamped loads per sample; validity folded into
// weights. Two batches of 4 samples -> 16 loads in flight per batch.
template <int CIN, int HH, int WW, int POS, int KS>
__device__ __forceinline__ void sample_chunk(
    const float* __restrict__ xb, const float* __restrict__ offy,
    const float* __restrict__ offx, const float* __restrict__ mskp,
    ushort* __restrict__ Shi, ushort* __restrict__ Slo,
    int tt, int p0, int kbase)
{
    constexpr int HW = HH * WW;
    const int pp = tt & (POS - 1);
    const int j0 = (tt / POS) * 8;
    const int p  = p0 + pp;
    const int yy = p / WW;
    const int xx = p - yy * WW;
    uint hw[4], lw[4];
#pragma unroll
    for (int hb = 0; hb < 2; ++hb) {
        float v[4][4];
        float wt[4][4];
#pragma unroll
        for (int j = 0; j < 4; ++j) {
            const int kg = kbase + j0 + hb * 4 + j;
            const int c  = (kg * 7282) >> 16;       // /9 (exact for kg<3641*9)
            const int k9 = kg - c * 9;
            const int ky = (k9 * 11) >> 5;          // /3 for 0..8
            const int kx = k9 - ky * 3;
            const float py = (float)(yy + ky - 1) + offy[k9 * POS + pp];
            const float px = (float)(xx + kx - 1) + offx[k9 * POS + pp];
            const float y0f = floorf(py), x0f = floorf(px);
            const int   y0  = (int)y0f,  x0 = (int)x0f;
            const int yc0 = min(max(y0, 0), HH - 1);
            const int yc1 = min(max(y0 + 1, 0), HH - 1);
            const int xc0 = min(max(x0, 0), WW - 1);
            const int xc1 = min(max(x0 + 1, 0), WW - 1);
            const float* chp = xb + (size_t)c * HW;
            v[j][0] = chp[yc0 * WW + xc0];
            v[j][1] = chp[yc0 * WW + xc1];
            v[j][2] = chp[yc1 * WW + xc0];
            v[j][3] = chp[yc1 * WW + xc1];
            const float wy1 = py - y0f, wx1 = px - x0f;
            const float m   = mskp[k9 * POS + pp];
            const float fy0 = (y0 >= 0  && y0 < HH)      ? (1.f - wy1) * m : 0.f;
            const float fy1 = (y0 >= -1 && y0 < HH - 1)  ? wy1 * m         : 0.f;
            const float fx0 = (x0 >= 0  && x0 < WW)      ? (1.f - wx1)     : 0.f;
            const float fx1 = (x0 >= -1 && x0 < WW - 1)  ? wx1             : 0.f;
            wt[j][0] = fy0 * fx0; wt[j][1] = fy0 * fx1;
            wt[j][2] = fy1 * fx0; wt[j][3] = fy1 * fx1;
        }
#pragma unroll
        for (int j = 0; j < 4; ++j) {
            const float s = v[j][0] * wt[j][0] + v[j][1] * wt[j][1]
                          + v[j][2] * wt[j][2] + v[j][3] * wt[j][3];
            const ushort h = f2bf(s);
            const ushort l = f2bf(s - bf2f(h));
            const int jj = hb * 4 + j;
            const int wi = jj >> 1;
            if (jj & 1) { hw[wi] |= ((uint)h) << 16; lw[wi] |= ((uint)l) << 16; }
            else        { hw[wi] = (uint)h;          lw[wi] = (uint)l; }
        }
    }
    uint4 hv; hv.x = hw[0]; hv.y = hw[1]; hv.z = hw[2]; hv.w = hw[3];
    uint4 lv; lv.x = lw[0]; lv.y = lw[1]; lv.z = lw[2]; lv.w = lw[3];
    *(uint4*)&Shi[pp * KS + j0] = hv;
    *(uint4*)&Slo[pp * KS + j0] = lv;
}

// ---------------- fused DCN on MFMA: sample + GEMM + bias + BN + ReLU -------
// Tile: POS positions x 128 co. Waves/block = (POS/16) * KWAVES.
// Per chunk (KC=32), pipelined: {B-frags from LDS, A-frags -> regs (APRE)} ->
// {sample next chunk: its VALU+gather hides A/B latency} -> {24 MFMAs} -> bar.
// KWAVES>1: K split across wave groups, staged LDS reduce at the end.
template <int CIN, int HH, int WW, int POS, int KWAVES, int MINW>
__global__ __launch_bounds__((POS / 16) * KWAVES * 64, MINW) void dcn_mfma_kernel(
    const float* __restrict__ xin,   // (B, CIN, HH, WW)
    const float* __restrict__ om,    // (B, 27, HH, WW)
    const ushort* __restrict__ whi,  // (128, CIN*9) bf16 hi
    const ushort* __restrict__ wlo,  // (128, CIN*9) bf16 lo
    const float* __restrict__ bias,
    const float* __restrict__ gam, const float* __restrict__ bet,
    const float* __restrict__ mu,  const float* __restrict__ var,
    float* __restrict__ out)         // (B, 128, HH*WW)
{
    constexpr int HW   = HH * WW;
    constexpr int K    = CIN * 9;
    constexpr int NPQ  = POS / 16;            // position quarters
    constexpr int NT   = NPQ * KWAVES * 64;
    constexpr int KC   = 32;
    constexpr int KS   = 40;                  // S row stride (ushort), pad 8
    constexpr int KG   = K / KWAVES;
    constexpr int NCH  = KG / KC;
    constexpr int SBUF = POS * KS;            // ushorts per (buf, hi|lo)
    constexpr bool APRE = (KWAVES == 1);      // A-frag register prefetch

    extern __shared__ __align__(16) char smem[];
    float*  offy  = (float*)smem;             // 9*POS
    float*  offx  = offy + 9 * POS;
    float*  mskp  = offx + 9 * POS;
    float*  invp  = mskp + 9 * POS;           // 128
    float*  shp   = invp + 128;               // 128
    ushort* Sbase = (ushort*)(shp + 128);     // KWAVES*4*SBUF ushorts

    const int tid = threadIdx.x;
    const int nt  = HW / POS;
    const int b   = blockIdx.x / nt;
    const int p0  = (blockIdx.x - b * nt) * POS;

    const float* omb = om + (size_t)b * 27 * HW;
    for (int i = tid; i < 9 * POS; i += NT) {
        const int k = i / POS, pp = i & (POS - 1);
        const int p = p0 + pp;
        offy[i] = omb[(size_t)k * HW + p];
        offx[i] = omb[(size_t)(9 + k) * HW + p];
        const float mv = omb[(size_t)(18 + k) * HW + p];
        mskp[i] = 1.0f / (1.0f + expf(-mv));
    }
    for (int i = tid; i < 128; i += NT) {
        const float iv = gam[i] * rsqrtf(var[i] + EPSV);
        invp[i] = iv;
        shp[i]  = bet[i] - mu[i] * iv + bias[i] * iv;
    }
    __syncthreads();

    const float* xb   = xin + (size_t)b * CIN * HW;
    const int lane    = tid & 63;
    const int w       = tid >> 6;
    const int wq      = w & (NPQ - 1);
    const int kgid    = w / NPQ;
    const int tt      = tid & (NPQ * 64 - 1);
    const int kbase_g = kgid * KG;

    ushort* S00 = Sbase + kgid * (4 * SBUF);

    f32x4 acc[8];
#pragma unroll
    for (int mt = 0; mt < 8; ++mt) acc[mt] = (f32x4){0.f, 0.f, 0.f, 0.f};

    const int mrow = lane & 15;
    const int kq   = lane >> 4;

    sample_chunk<CIN, HH, WW, POS, KS>(xb, offy, offx, mskp,
                                       S00, S00 + SBUF, tt, p0, kbase_g);
    __syncthreads();

    for (int ch = 0; ch < NCH; ++ch) {
        const int cur = ch & 1;
        ushort* Sc = S00 + (cur * 2) * SBUF;
        // 1. B fragments from LDS
        const int boff = (wq * 16 + mrow) * KS + kq * 8;
        const short8 bh = *(const short8*)&Sc[boff];
        const short8 bl = *(const short8*)&Sc[SBUF + boff];
        const size_t abase = (size_t)mrow * K + (size_t)(kbase_g + ch * KC)
                           + (size_t)(kq * 8);
        if constexpr (APRE) {
            // 2. A fragments -> registers (issued before sampling)
            short8 ah[8], al[8];
#pragma unroll
            for (int mt = 0; mt < 8; ++mt) {
                const size_t ao = abase + (size_t)(mt * 16) * K;
                ah[mt] = *(const short8*)(whi + ao);
                al[mt] = *(const short8*)(wlo + ao);
            }
            // 3. sample next chunk (hides A/B latency)
            if (ch + 1 < NCH) {
                ushort* Sn = S00 + ((cur ^ 1) * 2) * SBUF;
                sample_chunk<CIN, HH, WW, POS, KS>(xb, offy, offx, mskp,
                                                   Sn, Sn + SBUF, tt, p0,
                                                   kbase_g + (ch + 1) * KC);
            }
            // 4. MFMA
#pragma unroll
            for (int mt = 0; mt < 8; ++mt) {
                acc[mt] = __builtin_amdgcn_mfma_f32_16x16x32_bf16(al[mt], bh, acc[mt], 0, 0, 0);
                acc[mt] = __builtin_amdgcn_mfma_f32_16x16x32_bf16(ah[mt], bl, acc[mt], 0, 0, 0);
                acc[mt] = __builtin_amdgcn_mfma_f32_16x16x32_bf16(ah[mt], bh, acc[mt], 0, 0, 0);
            }
        } else {
            if (ch + 1 < NCH) {
                ushort* Sn = S00 + ((cur ^ 1) * 2) * SBUF;
                sample_chunk<CIN, HH, WW, POS, KS>(xb, offy, offx, mskp,
                                                   Sn, Sn + SBUF, tt, p0,
                                                   kbase_g + (ch + 1) * KC);
            }
#pragma unroll
            for (int mt = 0; mt < 8; ++mt) {
                const size_t ao = abase + (size_t)(mt * 16) * K;
                const short8 ah = *(const short8*)(whi + ao);
                const short8 al = *(const short8*)(wlo + ao);
                acc[mt] = __builtin_amdgcn_mfma_f32_16x16x32_bf16(al, bh, acc[mt], 0, 0, 0);
                acc[mt] = __builtin_amdgcn_mfma_f32_16x16x32_bf16(ah, bl, acc[mt], 0, 0, 0);
                acc[mt] = __builtin_amdgcn_mfma_f32_16x16x32_bf16(ah, bh, acc[mt], 0, 0, 0);
            }
        }
        __syncthreads();
    }

    const int pcolb = wq * 16 + mrow;
    constexpr int RS = POS + 1;               // red row stride (floats)
    constexpr int SL = 128 * RS;              // red slot size
    float* red = (float*)Sbase;

    if constexpr (KWAVES == 4) {
        if (kgid >= 2) {
#pragma unroll
            for (int mt = 0; mt < 8; ++mt)
#pragma unroll
                for (int r = 0; r < 4; ++r) {
                    const int co = mt * 16 + kq * 4 + r;
                    red[(kgid - 2) * SL + co * RS + pcolb] = acc[mt][r];
                }
        }
        __syncthreads();
        if (kgid < 2) {
#pragma unroll
            for (int mt = 0; mt < 8; ++mt)
#pragma unroll
                for (int r = 0; r < 4; ++r) {
                    const int co = mt * 16 + kq * 4 + r;
                    acc[mt][r] += red[kgid * SL + co * RS + pcolb];
                }
        }
        __syncthreads();
        if (kgid == 1) {
#pragma unroll
            for (int mt = 0; mt < 8; ++mt)
#pragma unroll
                for (int r = 0; r < 4; ++r) {
                    const int co = mt * 16 + kq * 4 + r;
                    red[co * RS + pcolb] = acc[mt][r];
                }
        }
        __syncthreads();
        if (kgid == 0) {
#pragma unroll
            for (int mt = 0; mt < 8; ++mt)
#pragma unroll
                for (int r = 0; r < 4; ++r) {
                    const int co = mt * 16 + kq * 4 + r;
                    acc[mt][r] += red[co * RS + pcolb];
                }
        }
    } else if constexpr (KWAVES == 2) {
        if (kgid == 1) {
#pragma unroll
            for (int mt = 0; mt < 8; ++mt)
#pragma unroll
                for (int r = 0; r < 4; ++r) {
                    const int co = mt * 16 + kq * 4 + r;
                    red[co * RS + pcolb] = acc[mt][r];
                }
        }
        __syncthreads();
        if (kgid == 0) {
#pragma unroll
            for (int mt = 0; mt < 8; ++mt)
#pragma unroll
                for (int r = 0; r < 4; ++r) {
                    const int co = mt * 16 + kq * 4 + r;
                    acc[mt][r] += red[co * RS + pcolb];
                }
        }
    }

    if (kgid == 0) {
        float* outb = out + (size_t)b * 128 * HW + p0 + pcolb;
#pragma unroll
        for (int mt = 0; mt < 8; ++mt)
#pragma unroll
            for (int r = 0; r < 4; ++r) {
                const int co = mt * 16 + kq * 4 + r;
                outb[(size_t)co * HW] = fmaxf(acc[mt][r] * invp[co] + shp[co], 0.f);
            }
    }
}

// ---------------- depthwise transposed-conv upsample x2 (k=4, pad 2) --------
__global__ __launch_bounds__(256) void upsample_kernel(
    const float* __restrict__ y,    // (4,128,64,64)
    const float* __restrict__ wup,  // (128,1,4,4)
    float* __restrict__ out)        // (4,128,128,128)
{
    const int idx = blockIdx.x * 256 + threadIdx.x;
    const int ox = idx & 127;
    const int oy = (idx >> 7) & 127;
    const int c  = (idx >> 14) & 127;
    const int b  = idx >> 21;

    const float* yc = y + (size_t)(b * 128 + c) * 4096;
    const float* wc = wup + c * 16;

    float acc = 0.f;
#pragma unroll
    for (int ky = 0; ky < 4; ++ky) {
        const int qy = oy + ky - 2;
        if (qy & 1) continue;
        const int iy = qy >> 1;
        if (iy < 0 || iy >= 64) continue;
#pragma unroll
        for (int kx = 0; kx < 4; ++kx) {
            const int qx = ox + kx - 2;
            if (qx & 1) continue;
            const int ix = qx >> 1;
            if (ix < 0 || ix >= 64) continue;
            acc += yc[iy * 64 + ix] * wc[(3 - ky) * 4 + (3 - kx)];
        }
    }
    out[idx] = acc;
}

// ---------------------------------------------------------------------------
extern "C" void kernel_launch(void* const* d_in, const int* in_sizes, int n_in,
                              void* d_out, int out_size, void* d_ws, size_t ws_size,
                              hipStream_t stream) {
    const float* x      = (const float*)d_in[0];
    const float* w_off1 = (const float*)d_in[1];
    const float* b_off1 = (const float*)d_in[2];
    const float* w1     = (const float*)d_in[3];
    const float* b1     = (const float*)d_in[4];
    const float* g1v    = (const float*)d_in[5];
    const float* be1    = (const float*)d_in[6];
    const float* m1     = (const float*)d_in[7];
    const float* v1     = (const float*)d_in[8];
    const float* w_up   = (const float*)d_in[9];
    const float* w_off2 = (const float*)d_in[10];
    const float* b_off2 = (const float*)d_in[11];
    const float* w2     = (const float*)d_in[12];
    const float* b2     = (const float*)d_in[13];
    const float* g2v    = (const float*)d_in[14];
    const float* be2    = (const float*)d_in[15];
    const float* m2     = (const float*)d_in[16];
    const float* v2     = (const float*)d_in[17];

    float* ws  = (float*)d_ws;
    float* om1 = ws;                     // 4*27*4096   =   442368 f
    float* y1  = om1 + 442368;           // 4*128*4096  =  2097152 f
    float* up  = y1 + 2097152;           // 4*128*16384 =  8388608 f
    float* om2 = up + 8388608;           // 4*27*16384  =  1769472 f
    float* outf = (float*)d_out;

    // w1 split parked in `up` (dead until upsample overwrites it)
    ushort* w1hi = (ushort*)up;          // 294912 ushort
    ushort* w1lo = w1hi + 294912;
    // w2 split parked in `y1` (dead after upsample reads it)
    ushort* w2hi = (ushort*)y1;          // 147456 ushort
    ushort* w2lo = w2hi + 147456;

    // prep: split w1 -> bf16 hi/lo
    wsplit_kernel<<<(294912 + 255) / 256, 256, 0, stream>>>(w1, w1hi, w1lo, 294912);

    {   // om1 = conv3x3(x, w_off1) + b_off1
        dim3 grid(64, 4);
        conv_off_kernel<256, 64, 64, 8, 8><<<grid, 512, 0, stream>>>(
            x, w_off1, b_off1, om1);
    }
    // y1 = bn_relu(dcn1) — MFMA, POS=32, 4-way K-split, 512 blocks x 8 waves
    // LDS: 3456 + 1024 + 4*4*1280*2 = 45440
    dcn_mfma_kernel<256, 64, 64, 32, 4, 4><<<4 * (4096 / 32), 512, 45440, stream>>>(
        x, om1, w1hi, w1lo, b1, g1v, be1, m1, v1, y1);
    // up = depthwise transposed upsample (clobbers w1 split — now dead)
    upsample_kernel<<<8388608 / 256, 256, 0, stream>>>(y1, w_up, up);
    // prep: split w2 -> bf16 hi/lo (y1 now dead)
    wsplit_kernel<<<(147456 + 255) / 256, 256, 0, stream>>>(w2, w2hi, w2lo, 147456);
    {   // om2 = conv3x3(up, w_off2) + b_off2
        dim3 grid(128, 4);
        conv_off_kernel<128, 128, 128, 2, 8><<<grid, 256, 0, stream>>>(
            up, w_off2, b_off2, om2);
    }
    // out = bn_relu(dcn2) — MFMA, POS=64, 1024 blocks x 4 waves, A-prefetch
    // LDS: 6912 + 1024 + 1*4*2560*2 = 28416
    dcn_mfma_kernel<128, 128, 128, 64, 1, 3><<<4 * (16384 / 64), 256, 28416, stream>>>(
        up, om2, w2hi, w2lo, b2, g2v, be2, m2, v2, outf);
}

// Round 5
// 1022.615 us; speedup vs baseline: 1.3140x; 1.3140x over previous
//
#include <hip/hip_runtime.h>
#include <hip/hip_bf16.h>
#include <cmath>

// ---------------------------------------------------------------------------
// Pipeline: y1 = bn_relu(dcn(x, w_off1, b_off1, w1, b1))        (4,128,64,64)
//           up = up_depthwise(y1, w_up, f=2)                    (4,128,128,128)
//           out = bn_relu(dcn(up, w_off2, b_off2, w2, b2))      (4,128,128,128)
// DCN GEMM on mfma_f32_16x16x32_bf16, split-bf16 (hi/lo, 3 products).
// K-order permuted to k9-major (k = k9*CIN + c): one KC=32 chunk = one
// kernel-tap x 32 consecutive channels -> bilinear entries (offsets+weights)
// hoisted to LDS once per block; sampler is 4 loads + 4 FMAs per sample.
// Workspace: om1 | y1 | up | om2 ; w1-split parked in `up`, w2-split in `y1`.
// ---------------------------------------------------------------------------

#define EPSV 1e-5f

typedef __attribute__((ext_vector_type(8))) short short8;
typedef __attribute__((ext_vector_type(4))) float f32x4;

__device__ __forceinline__ ushort f2bf(float f) {
    union { float f; uint u; } v; v.f = f;
    const uint r = v.u + 0x7fffu + ((v.u >> 16) & 1u);   // RNE
    return (ushort)(r >> 16);
}
__device__ __forceinline__ float bf2f(ushort h) {
    union { uint u; float f; } v; v.u = ((uint)h) << 16;
    return v.f;
}

// ---------------- weight split+permute: fp32 -> bf16 hi/lo, k9-major --------
__global__ __launch_bounds__(256) void wsplit_kernel(
    const float* __restrict__ w,     // (CO, CIN, 3, 3)
    ushort* __restrict__ hi, ushort* __restrict__ lo, int cin, int n)
{
    const int i = blockIdx.x * 256 + threadIdx.x;
    if (i >= n) return;
    const int cin9 = cin * 9;
    const int co = i / cin9;
    const int r  = i - co * cin9;
    const int c  = r / 9;
    const int k9 = r - c * 9;
    const float f = w[i];
    const ushort h = f2bf(f);
    const int o = co * cin9 + k9 * cin + c;   // k9-major K layout
    hi[o] = h;
    lo[o] = f2bf(f - bf2f(h));
}

// ---------------- offset conv: 3x3, pad 1, 27 output channels ---------------
template <int CIN, int HH, int WW, int SPLIT, int CC>
__global__ __launch_bounds__(WW * SPLIT) void conv_off_kernel(
    const float* __restrict__ in,    // (B, CIN, HH, WW)
    const float* __restrict__ wt,    // (27, CIN, 3, 3)
    const float* __restrict__ bias,  // (27)
    float* __restrict__ om)          // (B, 27, HH, WW)
{
    constexpr int POS  = WW;
    constexpr int NT   = WW * SPLIT;
    constexpr int CPG  = CIN / SPLIT;
    constexpr int NCH  = CPG / CC;
    constexpr int SLABN = SPLIT * CC * 3 * POS;
    constexpr int REDN  = 27 * SPLIT * POS;
    constexpr int SMEMN = (SLABN > REDN) ? SLABN : REDN;

    __shared__ __align__(16) float smem[SMEMN];
    float* slab = smem;
    float* red  = smem;

    const int tid = threadIdx.x;
    const int pos = tid & (POS - 1);
    const int g   = tid / POS;
    const int row = blockIdx.x;
    const int b   = blockIdx.y;

    const float* ib = in + (size_t)b * CIN * HH * WW;
    const int cbs = __builtin_amdgcn_readfirstlane(g * CPG);

    float acc[27];
#pragma unroll
    for (int o = 0; o < 27; ++o) acc[o] = 0.f;

    for (int ch = 0; ch < NCH; ++ch) {
        const int c0 = ch * CC;
        for (int i = tid; i < SLABN; i += NT) {
            const int gg = i / (CC * 3 * POS);
            const int r1 = i - gg * (CC * 3 * POS);
            const int cc = r1 / (3 * POS);
            const int r2 = r1 - cc * 3 * POS;
            const int rr = r2 / POS;
            const int px = r2 - rr * POS;
            const int c  = gg * CPG + c0 + cc;
            const int iy = row + rr - 1;
            float v = 0.f;
            if (iy >= 0 && iy < HH) v = ib[((size_t)c * HH + iy) * WW + px];
            slab[i] = v;
        }
        __syncthreads();

        const float* myslab = slab + g * (CC * 3 * POS);
        for (int cc = 0; cc < CC; ++cc) {
            const float* sl = myslab + cc * 3 * POS;
            float v[9];
            const int xm = (pos > 0) ? pos - 1 : 0;
            const int xp = (pos < POS - 1) ? pos + 1 : POS - 1;
#pragma unroll
            for (int r = 0; r < 3; ++r) {
                const float tl = sl[r * POS + xm];
                const float tc = sl[r * POS + pos];
                const float tr = sl[r * POS + xp];
                v[r * 3 + 0] = (pos > 0) ? tl : 0.f;
                v[r * 3 + 1] = tc;
                v[r * 3 + 2] = (pos < POS - 1) ? tr : 0.f;
            }
            const float* wp = wt + (size_t)(cbs + c0 + cc) * 9;
#pragma unroll
            for (int o = 0; o < 27; ++o) {
                const float* w9 = wp + (size_t)o * CIN * 9;
#pragma unroll
                for (int k = 0; k < 9; ++k)
                    acc[o] = fmaf(w9[k], v[k], acc[o]);
            }
        }
        __syncthreads();
    }

#pragma unroll
    for (int o = 0; o < 27; ++o) red[(o * SPLIT + g) * POS + pos] = acc[o];
    __syncthreads();

    float* ob = om + (size_t)b * 27 * HH * WW + (size_t)row * WW;
    for (int i = tid; i < 27 * POS; i += NT) {
        const int o  = i / POS;
        const int px = i - o * POS;
        float s = bias[o];
#pragma unroll
        for (int gg = 0; gg < SPLIT; ++gg)
            s += red[(o * SPLIT + gg) * POS + px];
        ob[(size_t)o * HH * WW + px] = s;
    }
}

// ---------------- sampler: one KC=32 chunk (one k9, 32 channels) ------------
// Entry (offsets+weights) precomputed in LDS; per lane: 1 entry read, then
// 8 channels x {4 unconditional loads + 4 FMAs}, bf16 hi/lo split, 2 stores.
template <int CIN, int HH, int WW, int POS, int KS>
__device__ __forceinline__ void sample_chunk(
    const float* __restrict__ xb, const int4* __restrict__ eoff,
    const float4* __restrict__ ewt, ushort* __restrict__ Shi,
    ushort* __restrict__ Slo, int tt, int gchunk)
{
    constexpr int HW = HH * WW;
    constexpr int G  = CIN / 32;             // chunks per k9
    const int pp = tt & (POS - 1);
    const int j0 = (tt / POS) * 8;
    const int k9 = gchunk / G;
    const int cb = (gchunk - k9 * G) * 32 + j0;
    const int ei = k9 * POS + pp;
    const int4   e  = eoff[ei];
    const float4 wv = ewt[ei];
    const float* chp = xb + (size_t)cb * HW;
    float s[8];
#pragma unroll
    for (int j = 0; j < 8; ++j) {
        s[j] = chp[e.x] * wv.x + chp[e.y] * wv.y
             + chp[e.z] * wv.z + chp[e.w] * wv.w;
        chp += HW;
    }
    uint hw[4], lw[4];
#pragma unroll
    for (int q = 0; q < 4; ++q) {
        const ushort h0 = f2bf(s[2 * q]);
        const ushort h1 = f2bf(s[2 * q + 1]);
        const float  l0 = s[2 * q]     - bf2f(h0);
        const float  l1 = s[2 * q + 1] - bf2f(h1);
        hw[q] = (uint)h0 | ((uint)h1 << 16);
        lw[q] = (uint)f2bf(l0) | ((uint)f2bf(l1) << 16);
    }
    uint4 hv; hv.x = hw[0]; hv.y = hw[1]; hv.z = hw[2]; hv.w = hw[3];
    uint4 lv; lv.x = lw[0]; lv.y = lw[1]; lv.z = lw[2]; lv.w = lw[3];
    *(uint4*)&Shi[pp * KS + j0] = hv;
    *(uint4*)&Slo[pp * KS + j0] = lv;
}

// ---------------- fused DCN on MFMA: sample + GEMM + bias + BN + ReLU -------
// Tile: POS positions x 128 co. Per chunk: B-frags from LDS, sample next
// chunk (gathers in flight), A-frags loaded inline per-mt (nothing held
// across the sampler -> no spill). KWAVES>1: K split, LDS reduce at end.
template <int CIN, int HH, int WW, int POS, int KWAVES, int MINW>
__global__ __launch_bounds__((POS / 16) * KWAVES * 64, MINW) void dcn_mfma_kernel(
    const float* __restrict__ xin,   // (B, CIN, HH, WW)
    const float* __restrict__ om,    // (B, 27, HH, WW)
    const ushort* __restrict__ whi,  // (128, K) bf16 hi, k9-major
    const ushort* __restrict__ wlo,  // (128, K) bf16 lo, k9-major
    const float* __restrict__ bias,
    const float* __restrict__ gam, const float* __restrict__ bet,
    const float* __restrict__ mu,  const float* __restrict__ var,
    float* __restrict__ out)         // (B, 128, HH*WW)
{
    constexpr int HW   = HH * WW;
    constexpr int K    = CIN * 9;
    constexpr int NPQ  = POS / 16;
    constexpr int NT   = NPQ * KWAVES * 64;
    constexpr int KC   = 32;
    constexpr int KS   = 40;                  // S row stride (ushort), pad 8
    constexpr int NCHT = K / KC;              // total chunks
    constexpr int NCH  = NCHT / KWAVES;       // chunks per K-group
    constexpr int SBUF = POS * KS;            // ushorts per (buf, hi|lo)

    extern __shared__ __align__(16) char smem[];
    int4*   eoff  = (int4*)smem;              // 9*POS
    float4* ewt   = (float4*)(eoff + 9 * POS);
    float*  invp  = (float*)(ewt + 9 * POS);  // 128
    float*  shp   = invp + 128;               // 128
    ushort* Sbase = (ushort*)(shp + 128);     // KWAVES*4*SBUF ushorts

    const int tid = threadIdx.x;
    const int nt  = HW / POS;
    const int b   = blockIdx.x / nt;
    const int p0  = (blockIdx.x - b * nt) * POS;

    // ---- precompute bilinear entries: offsets + mask-folded weights ----
    const float* omb = om + (size_t)b * 27 * HW;
    for (int i = tid; i < 9 * POS; i += NT) {
        const int k9 = i / POS, pp = i - k9 * POS;
        const int p  = p0 + pp;
        const int yy = p / WW;
        const int xx = p - yy * WW;
        const float oy = omb[(size_t)k9 * HW + p];
        const float ox = omb[(size_t)(9 + k9) * HW + p];
        const float mv = omb[(size_t)(18 + k9) * HW + p];
        const float m  = 1.0f / (1.0f + expf(-mv));
        const int ky = (k9 * 11) >> 5;        // /3 for 0..8
        const int kx = k9 - ky * 3;
        const float py = (float)(yy + ky - 1) + oy;
        const float px = (float)(xx + kx - 1) + ox;
        const float y0f = floorf(py), x0f = floorf(px);
        const int   y0  = (int)y0f,  x0 = (int)x0f;
        const int yc0 = min(max(y0, 0), HH - 1);
        const int yc1 = min(max(y0 + 1, 0), HH - 1);
        const int xc0 = min(max(x0, 0), WW - 1);
        const int xc1 = min(max(x0 + 1, 0), WW - 1);
        const float wy1 = py - y0f, wx1 = px - x0f;
        const float fy0 = (y0 >= 0  && y0 < HH)     ? (1.f - wy1) * m : 0.f;
        const float fy1 = (y0 >= -1 && y0 < HH - 1) ? wy1 * m         : 0.f;
        const float fx0 = (x0 >= 0  && x0 < WW)     ? (1.f - wx1)     : 0.f;
        const float fx1 = (x0 >= -1 && x0 < WW - 1) ? wx1             : 0.f;
        int4 e; e.x = yc0 * WW + xc0; e.y = yc0 * WW + xc1;
                e.z = yc1 * WW + xc0; e.w = yc1 * WW + xc1;
        float4 wv; wv.x = fy0 * fx0; wv.y = fy0 * fx1;
                   wv.z = fy1 * fx0; wv.w = fy1 * fx1;
        eoff[i] = e;
        ewt[i]  = wv;
    }
    for (int i = tid; i < 128; i += NT) {
        const float iv = gam[i] * rsqrtf(var[i] + EPSV);
        invp[i] = iv;
        shp[i]  = bet[i] - mu[i] * iv + bias[i] * iv;
    }
    __syncthreads();

    const float* xb   = xin + (size_t)b * CIN * HW;
    const int lane = tid & 63;
    const int w    = tid >> 6;
    const int wq   = w & (NPQ - 1);
    const int kgid = w / NPQ;
    const int tt   = tid & (NPQ * 64 - 1);

    ushort* S00 = Sbase + kgid * (4 * SBUF);

    f32x4 acc[8];
#pragma unroll
    for (int mt = 0; mt < 8; ++mt) acc[mt] = (f32x4){0.f, 0.f, 0.f, 0.f};

    const int mrow = lane & 15;
    const int kq   = lane >> 4;

    sample_chunk<CIN, HH, WW, POS, KS>(xb, eoff, ewt, S00, S00 + SBUF,
                                       tt, kgid * NCH);
    __syncthreads();

    for (int ch = 0; ch < NCH; ++ch) {
        const int cur = ch & 1;
        ushort* Sc = S00 + (cur * 2) * SBUF;
        // B fragments from LDS (waited early; small)
        const int boff = (wq * 16 + mrow) * KS + kq * 8;
        const short8 bh = *(const short8*)&Sc[boff];
        const short8 bl = *(const short8*)&Sc[SBUF + boff];
        // sample next chunk first: its 32 gathers overlap the MFMA section
        if (ch + 1 < NCH) {
            ushort* Sn = S00 + ((cur ^ 1) * 2) * SBUF;
            sample_chunk<CIN, HH, WW, POS, KS>(xb, eoff, ewt, Sn, Sn + SBUF,
                                               tt, kgid * NCH + ch + 1);
        }
        // A fragments inline per-mt (nothing held across the sampler)
        const size_t abase = (size_t)mrow * K
                           + (size_t)(kgid * NCH + ch) * KC + (size_t)(kq * 8);
#pragma unroll
        for (int mt = 0; mt < 8; ++mt) {
            const size_t ao = abase + (size_t)(mt * 16) * K;
            const short8 ah = *(const short8*)(whi + ao);
            const short8 al = *(const short8*)(wlo + ao);
            acc[mt] = __builtin_amdgcn_mfma_f32_16x16x32_bf16(al, bh, acc[mt], 0, 0, 0);
            acc[mt] = __builtin_amdgcn_mfma_f32_16x16x32_bf16(ah, bl, acc[mt], 0, 0, 0);
            acc[mt] = __builtin_amdgcn_mfma_f32_16x16x32_bf16(ah, bh, acc[mt], 0, 0, 0);
        }
        __syncthreads();
    }

    const int pcolb = wq * 16 + mrow;
    constexpr int RS = POS + 1;
    constexpr int SL = 128 * RS;
    float* red = (float*)Sbase;

    if constexpr (KWAVES == 4) {
        if (kgid >= 2) {
#pragma unroll
            for (int mt = 0; mt < 8; ++mt)
#pragma unroll
                for (int r = 0; r < 4; ++r) {
                    const int co = mt * 16 + kq * 4 + r;
                    red[(kgid - 2) * SL + co * RS + pcolb] = acc[mt][r];
                }
        }
        __syncthreads();
        if (kgid < 2) {
#pragma unroll
            for (int mt = 0; mt < 8; ++mt)
#pragma unroll
                for (int r = 0; r < 4; ++r) {
                    const int co = mt * 16 + kq * 4 + r;
                    acc[mt][r] += red[kgid * SL + co * RS + pcolb];
                }
        }
        __syncthreads();
        if (kgid == 1) {
#pragma unroll
            for (int mt = 0; mt < 8; ++mt)
#pragma unroll
                for (int r = 0; r < 4; ++r) {
                    const int co = mt * 16 + kq * 4 + r;
                    red[co * RS + pcolb] = acc[mt][r];
                }
        }
        __syncthreads();
        if (kgid == 0) {
#pragma unroll
            for (int mt = 0; mt < 8; ++mt)
#pragma unroll
                for (int r = 0; r < 4; ++r) {
                    const int co = mt * 16 + kq * 4 + r;
                    acc[mt][r] += red[co * RS + pcolb];
                }
        }
    } else if constexpr (KWAVES == 2) {
        if (kgid == 1) {
#pragma unroll
            for (int mt = 0; mt < 8; ++mt)
#pragma unroll
                for (int r = 0; r < 4; ++r) {
                    const int co = mt * 16 + kq * 4 + r;
                    red[co * RS + pcolb] = acc[mt][r];
                }
        }
        __syncthreads();
        if (kgid == 0) {
#pragma unroll
            for (int mt = 0; mt < 8; ++mt)
#pragma unroll
                for (int r = 0; r < 4; ++r) {
                    const int co = mt * 16 + kq * 4 + r;
                    acc[mt][r] += red[co * RS + pcolb];
                }
        }
    }

    if (kgid == 0) {
        float* outb = out + (size_t)b * 128 * HW + p0 + pcolb;
#pragma unroll
        for (int mt = 0; mt < 8; ++mt)
#pragma unroll
            for (int r = 0; r < 4; ++r) {
                const int co = mt * 16 + kq * 4 + r;
                outb[(size_t)co * HW] = fmaxf(acc[mt][r] * invp[co] + shp[co], 0.f);
            }
    }
}

// ---------------- depthwise transposed-conv upsample x2 (k=4, pad 2) --------
__global__ __launch_bounds__(256) void upsample_kernel(
    const float* __restrict__ y,    // (4,128,64,64)
    const float* __restrict__ wup,  // (128,1,4,4)
    float* __restrict__ out)        // (4,128,128,128)
{
    const int idx = blockIdx.x * 256 + threadIdx.x;
    const int ox = idx & 127;
    const int oy = (idx >> 7) & 127;
    const int c  = (idx >> 14) & 127;
    const int b  = idx >> 21;

    const float* yc = y + (size_t)(b * 128 + c) * 4096;
    const float* wc = wup + c * 16;

    float acc = 0.f;
#pragma unroll
    for (int ky = 0; ky < 4; ++ky) {
        const int qy = oy + ky - 2;
        if (qy & 1) continue;
        const int iy = qy >> 1;
        if (iy < 0 || iy >= 64) continue;
#pragma unroll
        for (int kx = 0; kx < 4; ++kx) {
            const int qx = ox + kx - 2;
            if (qx & 1) continue;
            const int ix = qx >> 1;
            if (ix < 0 || ix >= 64) continue;
            acc += yc[iy * 64 + ix] * wc[(3 - ky) * 4 + (3 - kx)];
        }
    }
    out[idx] = acc;
}

// ---------------------------------------------------------------------------
extern "C" void kernel_launch(void* const* d_in, const int* in_sizes, int n_in,
                              void* d_out, int out_size, void* d_ws, size_t ws_size,
                              hipStream_t stream) {
    const float* x      = (const float*)d_in[0];
    const float* w_off1 = (const float*)d_in[1];
    const float* b_off1 = (const float*)d_in[2];
    const float* w1     = (const float*)d_in[3];
    const float* b1     = (const float*)d_in[4];
    const float* g1v    = (const float*)d_in[5];
    const float* be1    = (const float*)d_in[6];
    const float* m1     = (const float*)d_in[7];
    const float* v1     = (const float*)d_in[8];
    const float* w_up   = (const float*)d_in[9];
    const float* w_off2 = (const float*)d_in[10];
    const float* b_off2 = (const float*)d_in[11];
    const float* w2     = (const float*)d_in[12];
    const float* b2     = (const float*)d_in[13];
    const float* g2v    = (const float*)d_in[14];
    const float* be2    = (const float*)d_in[15];
    const float* m2     = (const float*)d_in[16];
    const float* v2     = (const float*)d_in[17];

    float* ws  = (float*)d_ws;
    float* om1 = ws;                     // 4*27*4096   =   442368 f
    float* y1  = om1 + 442368;           // 4*128*4096  =  2097152 f
    float* up  = y1 + 2097152;           // 4*128*16384 =  8388608 f
    float* om2 = up + 8388608;           // 4*27*16384  =  1769472 f
    float* outf = (float*)d_out;

    // w1 split parked in `up` (dead until upsample overwrites it)
    ushort* w1hi = (ushort*)up;          // 294912 ushort
    ushort* w1lo = w1hi + 294912;
    // w2 split parked in `y1` (dead after upsample reads it)
    ushort* w2hi = (ushort*)y1;          // 147456 ushort
    ushort* w2lo = w2hi + 147456;

    // prep: split+permute w1 -> bf16 hi/lo (k9-major)
    wsplit_kernel<<<(294912 + 255) / 256, 256, 0, stream>>>(w1, w1hi, w1lo, 256, 294912);

    {   // om1 = conv3x3(x, w_off1) + b_off1
        dim3 grid(64, 4);
        conv_off_kernel<256, 64, 64, 8, 8><<<grid, 512, 0, stream>>>(
            x, w_off1, b_off1, om1);
    }
    // y1 = bn_relu(dcn1) — MFMA, POS=32, 4-way K-split, 512 blocks x 8 waves
    // LDS: 9216 + 1024 + 4*4*(32*40)*2 = 51200
    dcn_mfma_kernel<256, 64, 64, 32, 4, 4><<<4 * (4096 / 32), 512, 51200, stream>>>(
        x, om1, w1hi, w1lo, b1, g1v, be1, m1, v1, y1);
    // up = depthwise transposed upsample (clobbers w1 split — now dead)
    upsample_kernel<<<8388608 / 256, 256, 0, stream>>>(y1, w_up, up);
    // prep: split+permute w2 -> bf16 hi/lo (y1 now dead)
    wsplit_kernel<<<(147456 + 255) / 256, 256, 0, stream>>>(w2, w2hi, w2lo, 128, 147456);
    {   // om2 = conv3x3(up, w_off2) + b_off2
        dim3 grid(128, 4);
        conv_off_kernel<128, 128, 128, 2, 8><<<grid, 256, 0, stream>>>(
            up, w_off2, b_off2, om2);
    }
    // out = bn_relu(dcn2) — MFMA, POS=64, 1024 blocks x 4 waves
    // LDS: 18432 + 1024 + 1*4*(64*40)*2 = 39936
    dcn_mfma_kernel<128, 128, 128, 64, 1, 4><<<4 * (16384 / 64), 256, 39936, stream>>>(
        up, om2, w2hi, w2lo, b2, g2v, be2, m2, v2, outf);
}

// Round 6
// 1020.761 us; speedup vs baseline: 1.3164x; 1.0018x over previous
//
#include <hip/hip_runtime.h>
#include <hip/hip_bf16.h>
#include <cmath>

// ---------------------------------------------------------------------------
// Pipeline: y1 = bn_relu(dcn(x, w_off1, b_off1, w1, b1))        (4,128,64,64)
//           up = up_depthwise(y1, w_up, f=2)                    (4,128,128,128)
//           out = bn_relu(dcn(up, w_off2, b_off2, w2, b2))      (4,128,128,128)
// DCN GEMM on mfma_f32_16x16x32_bf16, split-bf16 (hi/lo, 3 products).
// K kept channel-major (k = c*9 + k9, natural layout): a KC=32 chunk touches
// each channel plane exactly once per block (L2-friendly; R5's k9-major
// permutation caused 9x HBM re-fetch, 520 MB). Bilinear entries
// (offsets + mask-folded weights) hoisted to LDS once per block; sampler is
// 1 LDS entry + 4 loads + 4 FMAs per sample.
// Workspace: om1 | y1 | up | om2 ; w1-split parked in `up`, w2-split in `y1`.
// ---------------------------------------------------------------------------

#define EPSV 1e-5f

typedef __attribute__((ext_vector_type(8))) short short8;
typedef __attribute__((ext_vector_type(4))) float f32x4;

__device__ __forceinline__ ushort f2bf(float f) {
    union { float f; uint u; } v; v.f = f;
    const uint r = v.u + 0x7fffu + ((v.u >> 16) & 1u);   // RNE
    return (ushort)(r >> 16);
}
__device__ __forceinline__ float bf2f(ushort h) {
    union { uint u; float f; } v; v.u = ((uint)h) << 16;
    return v.f;
}

// ---------------- weight split: fp32 -> bf16 hi/lo (natural K layout) -------
__global__ __launch_bounds__(256) void wsplit_kernel(
    const float* __restrict__ w, ushort* __restrict__ hi,
    ushort* __restrict__ lo, int n)
{
    const int i = blockIdx.x * 256 + threadIdx.x;
    if (i >= n) return;
    const float f = w[i];
    const ushort h = f2bf(f);
    hi[i] = h;
    lo[i] = f2bf(f - bf2f(h));
}

// ---------------- offset conv: 3x3, pad 1, 27 output channels ---------------
template <int CIN, int HH, int WW, int SPLIT, int CC>
__global__ __launch_bounds__(WW * SPLIT) void conv_off_kernel(
    const float* __restrict__ in,    // (B, CIN, HH, WW)
    const float* __restrict__ wt,    // (27, CIN, 3, 3)
    const float* __restrict__ bias,  // (27)
    float* __restrict__ om)          // (B, 27, HH, WW)
{
    constexpr int POS  = WW;
    constexpr int NT   = WW * SPLIT;
    constexpr int CPG  = CIN / SPLIT;
    constexpr int NCH  = CPG / CC;
    constexpr int SLABN = SPLIT * CC * 3 * POS;
    constexpr int REDN  = 27 * SPLIT * POS;
    constexpr int SMEMN = (SLABN > REDN) ? SLABN : REDN;

    __shared__ __align__(16) float smem[SMEMN];
    float* slab = smem;
    float* red  = smem;

    const int tid = threadIdx.x;
    const int pos = tid & (POS - 1);
    const int g   = tid / POS;
    const int row = blockIdx.x;
    const int b   = blockIdx.y;

    const float* ib = in + (size_t)b * CIN * HH * WW;
    const int cbs = __builtin_amdgcn_readfirstlane(g * CPG);

    float acc[27];
#pragma unroll
    for (int o = 0; o < 27; ++o) acc[o] = 0.f;

    for (int ch = 0; ch < NCH; ++ch) {
        const int c0 = ch * CC;
        for (int i = tid; i < SLABN; i += NT) {
            const int gg = i / (CC * 3 * POS);
            const int r1 = i - gg * (CC * 3 * POS);
            const int cc = r1 / (3 * POS);
            const int r2 = r1 - cc * 3 * POS;
            const int rr = r2 / POS;
            const int px = r2 - rr * POS;
            const int c  = gg * CPG + c0 + cc;
            const int iy = row + rr - 1;
            float v = 0.f;
            if (iy >= 0 && iy < HH) v = ib[((size_t)c * HH + iy) * WW + px];
            slab[i] = v;
        }
        __syncthreads();

        const float* myslab = slab + g * (CC * 3 * POS);
        for (int cc = 0; cc < CC; ++cc) {
            const float* sl = myslab + cc * 3 * POS;
            float v[9];
            const int xm = (pos > 0) ? pos - 1 : 0;
            const int xp = (pos < POS - 1) ? pos + 1 : POS - 1;
#pragma unroll
            for (int r = 0; r < 3; ++r) {
                const float tl = sl[r * POS + xm];
                const float tc = sl[r * POS + pos];
                const float tr = sl[r * POS + xp];
                v[r * 3 + 0] = (pos > 0) ? tl : 0.f;
                v[r * 3 + 1] = tc;
                v[r * 3 + 2] = (pos < POS - 1) ? tr : 0.f;
            }
            const float* wp = wt + (size_t)(cbs + c0 + cc) * 9;
#pragma unroll
            for (int o = 0; o < 27; ++o) {
                const float* w9 = wp + (size_t)o * CIN * 9;
#pragma unroll
                for (int k = 0; k < 9; ++k)
                    acc[o] = fmaf(w9[k], v[k], acc[o]);
            }
        }
        __syncthreads();
    }

#pragma unroll
    for (int o = 0; o < 27; ++o) red[(o * SPLIT + g) * POS + pos] = acc[o];
    __syncthreads();

    float* ob = om + (size_t)b * 27 * HH * WW + (size_t)row * WW;
    for (int i = tid; i < 27 * POS; i += NT) {
        const int o  = i / POS;
        const int px = i - o * POS;
        float s = bias[o];
#pragma unroll
        for (int gg = 0; gg < SPLIT; ++gg)
            s += red[(o * SPLIT + gg) * POS + px];
        ob[(size_t)o * HH * WW + px] = s;
    }
}

// ---------------- sampler: one KC=32 chunk, channel-major K -----------------
// Per lane: 8 consecutive k = c*9+k9 (spans ~1 channel); per sample:
// 1 LDS entry read + 4 unconditional clamped loads + 4 FMAs; hi/lo split.
template <int CIN, int HH, int WW, int POS, int KS>
__device__ __forceinline__ void sample_chunk(
    const float* __restrict__ xb, const int4* __restrict__ eoff,
    const float4* __restrict__ ewt, ushort* __restrict__ Shi,
    ushort* __restrict__ Slo, int tt, int kbase)
{
    constexpr int HW = HH * WW;
    const int pp = tt & (POS - 1);
    const int j0 = (tt / POS) * 8;
    float s[8];
#pragma unroll
    for (int j = 0; j < 8; ++j) {
        const int kg = kbase + j0 + j;
        const int c  = (kg * 7282) >> 16;       // /9 (exact for kg<2304)
        const int k9 = kg - c * 9;
        const int ei = k9 * POS + pp;
        const int4   e  = eoff[ei];
        const float4 wv = ewt[ei];
        const float* chp = xb + (size_t)c * HW;
        s[j] = chp[e.x] * wv.x + chp[e.y] * wv.y
             + chp[e.z] * wv.z + chp[e.w] * wv.w;
    }
    uint hw[4], lw[4];
#pragma unroll
    for (int q = 0; q < 4; ++q) {
        const ushort h0 = f2bf(s[2 * q]);
        const ushort h1 = f2bf(s[2 * q + 1]);
        const float  l0 = s[2 * q]     - bf2f(h0);
        const float  l1 = s[2 * q + 1] - bf2f(h1);
        hw[q] = (uint)h0 | ((uint)h1 << 16);
        lw[q] = (uint)f2bf(l0) | ((uint)f2bf(l1) << 16);
    }
    uint4 hv; hv.x = hw[0]; hv.y = hw[1]; hv.z = hw[2]; hv.w = hw[3];
    uint4 lv; lv.x = lw[0]; lv.y = lw[1]; lv.z = lw[2]; lv.w = lw[3];
    *(uint4*)&Shi[pp * KS + j0] = hv;
    *(uint4*)&Slo[pp * KS + j0] = lv;
}

// ---------------- fused DCN on MFMA: sample + GEMM + bias + BN + ReLU -------
// Tile: POS positions x 128 co. Per chunk: B-frags from LDS, sample next
// chunk (gathers in flight over the MFMA section), A-frags inline per-mt
// (nothing held across the sampler -> no spill). KWAVES>1: K split across
// wave groups, staged LDS reduce at the end.
template <int CIN, int HH, int WW, int POS, int KWAVES, int MINW>
__global__ __launch_bounds__((POS / 16) * KWAVES * 64, MINW) void dcn_mfma_kernel(
    const float* __restrict__ xin,   // (B, CIN, HH, WW)
    const float* __restrict__ om,    // (B, 27, HH, WW)
    const ushort* __restrict__ whi,  // (128, K) bf16 hi
    const ushort* __restrict__ wlo,  // (128, K) bf16 lo
    const float* __restrict__ bias,
    const float* __restrict__ gam, const float* __restrict__ bet,
    const float* __restrict__ mu,  const float* __restrict__ var,
    float* __restrict__ out)         // (B, 128, HH*WW)
{
    constexpr int HW   = HH * WW;
    constexpr int K    = CIN * 9;
    constexpr int NPQ  = POS / 16;
    constexpr int NT   = NPQ * KWAVES * 64;
    constexpr int KC   = 32;
    constexpr int KS   = 40;                  // S row stride (ushort), pad 8
    constexpr int NCHT = K / KC;              // total chunks
    constexpr int NCH  = NCHT / KWAVES;       // chunks per K-group
    constexpr int SBUF = POS * KS;            // ushorts per (buf, hi|lo)

    extern __shared__ __align__(16) char smem[];
    int4*   eoff  = (int4*)smem;              // 9*POS
    float4* ewt   = (float4*)(eoff + 9 * POS);
    float*  invp  = (float*)(ewt + 9 * POS);  // 128
    float*  shp   = invp + 128;               // 128
    ushort* Sbase = (ushort*)(shp + 128);     // KWAVES*4*SBUF ushorts

    const int tid = threadIdx.x;
    const int nt  = HW / POS;
    const int b   = blockIdx.x / nt;
    const int p0  = (blockIdx.x - b * nt) * POS;

    // ---- precompute bilinear entries: offsets + mask-folded weights ----
    const float* omb = om + (size_t)b * 27 * HW;
    for (int i = tid; i < 9 * POS; i += NT) {
        const int k9 = i / POS, pp = i - k9 * POS;
        const int p  = p0 + pp;
        const int yy = p / WW;
        const int xx = p - yy * WW;
        const float oy = omb[(size_t)k9 * HW + p];
        const float ox = omb[(size_t)(9 + k9) * HW + p];
        const float mv = omb[(size_t)(18 + k9) * HW + p];
        const float m  = 1.0f / (1.0f + expf(-mv));
        const int ky = (k9 * 11) >> 5;        // /3 for 0..8
        const int kx = k9 - ky * 3;
        const float py = (float)(yy + ky - 1) + oy;
        const float px = (float)(xx + kx - 1) + ox;
        const float y0f = floorf(py), x0f = floorf(px);
        const int   y0  = (int)y0f,  x0 = (int)x0f;
        const int yc0 = min(max(y0, 0), HH - 1);
        const int yc1 = min(max(y0 + 1, 0), HH - 1);
        const int xc0 = min(max(x0, 0), WW - 1);
        const int xc1 = min(max(x0 + 1, 0), WW - 1);
        const float wy1 = py - y0f, wx1 = px - x0f;
        const float fy0 = (y0 >= 0  && y0 < HH)     ? (1.f - wy1) * m : 0.f;
        const float fy1 = (y0 >= -1 && y0 < HH - 1) ? wy1 * m         : 0.f;
        const float fx0 = (x0 >= 0  && x0 < WW)     ? (1.f - wx1)     : 0.f;
        const float fx1 = (x0 >= -1 && x0 < WW - 1) ? wx1             : 0.f;
        int4 e; e.x = yc0 * WW + xc0; e.y = yc0 * WW + xc1;
                e.z = yc1 * WW + xc0; e.w = yc1 * WW + xc1;
        float4 wv; wv.x = fy0 * fx0; wv.y = fy0 * fx1;
                   wv.z = fy1 * fx0; wv.w = fy1 * fx1;
        eoff[i] = e;
        ewt[i]  = wv;
    }
    for (int i = tid; i < 128; i += NT) {
        const float iv = gam[i] * rsqrtf(var[i] + EPSV);
        invp[i] = iv;
        shp[i]  = bet[i] - mu[i] * iv + bias[i] * iv;
    }
    __syncthreads();

    const float* xb   = xin + (size_t)b * CIN * HW;
    const int lane = tid & 63;
    const int w    = tid >> 6;
    const int wq   = w & (NPQ - 1);
    const int kgid = w / NPQ;
    const int tt   = tid & (NPQ * 64 - 1);

    ushort* S00 = Sbase + kgid * (4 * SBUF);

    f32x4 acc[8];
#pragma unroll
    for (int mt = 0; mt < 8; ++mt) acc[mt] = (f32x4){0.f, 0.f, 0.f, 0.f};

    const int mrow = lane & 15;
    const int kq   = lane >> 4;

    sample_chunk<CIN, HH, WW, POS, KS>(xb, eoff, ewt, S00, S00 + SBUF,
                                       tt, kgid * NCH * KC);
    __syncthreads();

    for (int ch = 0; ch < NCH; ++ch) {
        const int cur = ch & 1;
        ushort* Sc = S00 + (cur * 2) * SBUF;
        // B fragments from LDS (waited early; small)
        const int boff = (wq * 16 + mrow) * KS + kq * 8;
        const short8 bh = *(const short8*)&Sc[boff];
        const short8 bl = *(const short8*)&Sc[SBUF + boff];
        // sample next chunk first: its 32 gathers overlap the MFMA section
        if (ch + 1 < NCH) {
            ushort* Sn = S00 + ((cur ^ 1) * 2) * SBUF;
            sample_chunk<CIN, HH, WW, POS, KS>(xb, eoff, ewt, Sn, Sn + SBUF,
                                               tt, (kgid * NCH + ch + 1) * KC);
        }
        // A fragments inline per-mt (nothing held across the sampler)
        const size_t abase = (size_t)mrow * K
                           + (size_t)(kgid * NCH + ch) * KC + (size_t)(kq * 8);
#pragma unroll
        for (int mt = 0; mt < 8; ++mt) {
            const size_t ao = abase + (size_t)(mt * 16) * K;
            const short8 ah = *(const short8*)(whi + ao);
            const short8 al = *(const short8*)(wlo + ao);
            acc[mt] = __builtin_amdgcn_mfma_f32_16x16x32_bf16(al, bh, acc[mt], 0, 0, 0);
            acc[mt] = __builtin_amdgcn_mfma_f32_16x16x32_bf16(ah, bl, acc[mt], 0, 0, 0);
            acc[mt] = __builtin_amdgcn_mfma_f32_16x16x32_bf16(ah, bh, acc[mt], 0, 0, 0);
        }
        __syncthreads();
    }

    const int pcolb = wq * 16 + mrow;
    constexpr int RS = POS + 1;
    constexpr int SL = 128 * RS;
    float* red = (float*)Sbase;

    if constexpr (KWAVES == 4) {
        if (kgid >= 2) {
#pragma unroll
            for (int mt = 0; mt < 8; ++mt)
#pragma unroll
                for (int r = 0; r < 4; ++r) {
                    const int co = mt * 16 + kq * 4 + r;
                    red[(kgid - 2) * SL + co * RS + pcolb] = acc[mt][r];
                }
        }
        __syncthreads();
        if (kgid < 2) {
#pragma unroll
            for (int mt = 0; mt < 8; ++mt)
#pragma unroll
                for (int r = 0; r < 4; ++r) {
                    const int co = mt * 16 + kq * 4 + r;
                    acc[mt][r] += red[kgid * SL + co * RS + pcolb];
                }
        }
        __syncthreads();
        if (kgid == 1) {
#pragma unroll
            for (int mt = 0; mt < 8; ++mt)
#pragma unroll
                for (int r = 0; r < 4; ++r) {
                    const int co = mt * 16 + kq * 4 + r;
                    red[co * RS + pcolb] = acc[mt][r];
                }
        }
        __syncthreads();
        if (kgid == 0) {
#pragma unroll
            for (int mt = 0; mt < 8; ++mt)
#pragma unroll
                for (int r = 0; r < 4; ++r) {
                    const int co = mt * 16 + kq * 4 + r;
                    acc[mt][r] += red[co * RS + pcolb];
                }
        }
    } else if constexpr (KWAVES == 2) {
        if (kgid == 1) {
#pragma unroll
            for (int mt = 0; mt < 8; ++mt)
#pragma unroll
                for (int r = 0; r < 4; ++r) {
                    const int co = mt * 16 + kq * 4 + r;
                    red[co * RS + pcolb] = acc[mt][r];
                }
        }
        __syncthreads();
        if (kgid == 0) {
#pragma unroll
            for (int mt = 0; mt < 8; ++mt)
#pragma unroll
                for (int r = 0; r < 4; ++r) {
                    const int co = mt * 16 + kq * 4 + r;
                    acc[mt][r] += red[co * RS + pcolb];
                }
        }
    }

    if (kgid == 0) {
        float* outb = out + (size_t)b * 128 * HW + p0 + pcolb;
#pragma unroll
        for (int mt = 0; mt < 8; ++mt)
#pragma unroll
            for (int r = 0; r < 4; ++r) {
                const int co = mt * 16 + kq * 4 + r;
                outb[(size_t)co * HW] = fmaxf(acc[mt][r] * invp[co] + shp[co], 0.f);
            }
    }
}

// ---------------- depthwise transposed-conv upsample x2 (k=4, pad 2) --------
__global__ __launch_bounds__(256) void upsample_kernel(
    const float* __restrict__ y,    // (4,128,64,64)
    const float* __restrict__ wup,  // (128,1,4,4)
    float* __restrict__ out)        // (4,128,128,128)
{
    const int idx = blockIdx.x * 256 + threadIdx.x;
    const int ox = idx & 127;
    const int oy = (idx >> 7) & 127;
    const int c  = (idx >> 14) & 127;
    const int b  = idx >> 21;

    const float* yc = y + (size_t)(b * 128 + c) * 4096;
    const float* wc = wup + c * 16;

    float acc = 0.f;
#pragma unroll
    for (int ky = 0; ky < 4; ++ky) {
        const int qy = oy + ky - 2;
        if (qy & 1) continue;
        const int iy = qy >> 1;
        if (iy < 0 || iy >= 64) continue;
#pragma unroll
        for (int kx = 0; kx < 4; ++kx) {
            const int qx = ox + kx - 2;
            if (qx & 1) continue;
            const int ix = qx >> 1;
            if (ix < 0 || ix >= 64) continue;
            acc += yc[iy * 64 + ix] * wc[(3 - ky) * 4 + (3 - kx)];
        }
    }
    out[idx] = acc;
}

// ---------------------------------------------------------------------------
extern "C" void kernel_launch(void* const* d_in, const int* in_sizes, int n_in,
                              void* d_out, int out_size, void* d_ws, size_t ws_size,
                              hipStream_t stream) {
    const float* x      = (const float*)d_in[0];
    const float* w_off1 = (const float*)d_in[1];
    const float* b_off1 = (const float*)d_in[2];
    const float* w1     = (const float*)d_in[3];
    const float* b1     = (const float*)d_in[4];
    const float* g1v    = (const float*)d_in[5];
    const float* be1    = (const float*)d_in[6];
    const float* m1     = (const float*)d_in[7];
    const float* v1     = (const float*)d_in[8];
    const float* w_up   = (const float*)d_in[9];
    const float* w_off2 = (const float*)d_in[10];
    const float* b_off2 = (const float*)d_in[11];
    const float* w2     = (const float*)d_in[12];
    const float* b2     = (const float*)d_in[13];
    const float* g2v    = (const float*)d_in[14];
    const float* be2    = (const float*)d_in[15];
    const float* m2     = (const float*)d_in[16];
    const float* v2     = (const float*)d_in[17];

    float* ws  = (float*)d_ws;
    float* om1 = ws;                     // 4*27*4096   =   442368 f
    float* y1  = om1 + 442368;           // 4*128*4096  =  2097152 f
    float* up  = y1 + 2097152;           // 4*128*16384 =  8388608 f
    float* om2 = up + 8388608;           // 4*27*16384  =  1769472 f
    float* outf = (float*)d_out;

    // w1 split parked in `up` (dead until upsample overwrites it)
    ushort* w1hi = (ushort*)up;          // 294912 ushort
    ushort* w1lo = w1hi + 294912;
    // w2 split parked in `y1` (dead after upsample reads it)
    ushort* w2hi = (ushort*)y1;          // 147456 ushort
    ushort* w2lo = w2hi + 147456;

    // prep: split w1 -> bf16 hi/lo (natural channel-major K layout)
    wsplit_kernel<<<(294912 + 255) / 256, 256, 0, stream>>>(w1, w1hi, w1lo, 294912);

    {   // om1 = conv3x3(x, w_off1) + b_off1
        dim3 grid(64, 4);
        conv_off_kernel<256, 64, 64, 8, 8><<<grid, 512, 0, stream>>>(
            x, w_off1, b_off1, om1);
    }
    // y1 = bn_relu(dcn1) — MFMA, POS=32, 4-way K-split, 512 blocks x 8 waves
    // LDS: 9216 + 1024 + 4*4*(32*40)*2 = 51200
    dcn_mfma_kernel<256, 64, 64, 32, 4, 4><<<4 * (4096 / 32), 512, 51200, stream>>>(
        x, om1, w1hi, w1lo, b1, g1v, be1, m1, v1, y1);
    // up = depthwise transposed upsample (clobbers w1 split — now dead)
    upsample_kernel<<<8388608 / 256, 256, 0, stream>>>(y1, w_up, up);
    // prep: split w2 -> bf16 hi/lo (y1 now dead)
    wsplit_kernel<<<(147456 + 255) / 256, 256, 0, stream>>>(w2, w2hi, w2lo, 147456);
    {   // om2 = conv3x3(up, w_off2) + b_off2
        dim3 grid(128, 4);
        conv_off_kernel<128, 128, 128, 2, 8><<<grid, 256, 0, stream>>>(
            up, w_off2, b_off2, om2);
    }
    // out = bn_relu(dcn2) — MFMA, POS=64, 1024 blocks x 4 waves
    // LDS: 18432 + 1024 + 1*4*(64*40)*2 = 39936
    dcn_mfma_kernel<128, 128, 128, 64, 1, 4><<<4 * (16384 / 64), 256, 39936, stream>>>(
        up, om2, w2hi, w2lo, b2, g2v, be2, m2, v2, outf);
}

// Round 7
// 856.699 us; speedup vs baseline: 1.5685x; 1.1915x over previous
//
#include <hip/hip_runtime.h>
#include <hip/hip_bf16.h>
#include <cmath>

// ---------------------------------------------------------------------------
// Pipeline: y1 = bn_relu(dcn(x, w_off1, b_off1, w1, b1))        (4,128,64,64)
//           up = up_depthwise(y1, w_up, f=2)                    (4,128,128,128)
//           out = bn_relu(dcn(up, w_off2, b_off2, w2, b2))      (4,128,128,128)
// DCN GEMM on mfma_f32_16x16x32_bf16, split-bf16 (hi/lo, 3 products).
// dcn2 (ASTAGE): w2 pre-permuted into per-chunk fragment order; each 16KB
// A-chunk staged into LDS with coalesced loads (shared by all waves),
// removing the 64-lane scattered A-fragment loads that dominated VMEM.
// Bilinear entries (ushort4 offsets + mask-folded float4 weights) hoisted
// to LDS once per block. XCD-swizzled grids for L2 locality.
// Workspace: om1 | y1 | up | om2 ; w1-split parked in `up`, w2-split in `y1`.
// ---------------------------------------------------------------------------

#define EPSV 1e-5f

typedef __attribute__((ext_vector_type(8))) short short8;
typedef __attribute__((ext_vector_type(4))) float f32x4;

__device__ __forceinline__ ushort f2bf(float f) {
    union { float f; uint u; } v; v.f = f;
    const uint r = v.u + 0x7fffu + ((v.u >> 16) & 1u);   // RNE
    return (ushort)(r >> 16);
}
__device__ __forceinline__ float bf2f(ushort h) {
    union { uint u; float f; } v; v.u = ((uint)h) << 16;
    return v.f;
}

// ---------------- weight split: fp32 -> bf16 hi/lo (natural K layout) -------
__global__ __launch_bounds__(256) void wsplit_kernel(
    const float* __restrict__ w, ushort* __restrict__ hi,
    ushort* __restrict__ lo, int n)
{
    const int i = blockIdx.x * 256 + threadIdx.x;
    if (i >= n) return;
    const float f = w[i];
    const ushort h = f2bf(f);
    hi[i] = h;
    lo[i] = f2bf(f - bf2f(h));
}

// ------- weight split: fp32 -> bf16 hi/lo in per-chunk FRAGMENT order -------
// dst[((ch*8 + mt)*64 + lane)*8 + j] = w[co][k], where k = c*9+k9 (natural),
// ch = k>>5, kq = (k&31)>>3, j = k&7, lane = (co&15) | (kq<<4), mt = co>>4.
__global__ __launch_bounds__(256) void wsplit_perm_kernel(
    const float* __restrict__ w, ushort* __restrict__ hi,
    ushort* __restrict__ lo, int cin, int n)
{
    const int i = blockIdx.x * 256 + threadIdx.x;
    if (i >= n) return;
    const int cin9 = cin * 9;
    const int co = i / cin9;
    const int k  = i - co * cin9;            // channel-major K index
    const int ch = k >> 5;
    const int kq = (k & 31) >> 3;
    const int j  = k & 7;
    const int mt = co >> 4;
    const int lane = (co & 15) | (kq << 4);
    const size_t dst = ((size_t)(ch * 8 + mt) * 64 + lane) * 8 + j;
    const float f = w[i];
    const ushort h = f2bf(f);
    hi[dst] = h;
    lo[dst] = f2bf(f - bf2f(h));
}

// ---------------- offset conv: 3x3, pad 1, 27 output channels ---------------
template <int CIN, int HH, int WW, int SPLIT, int CC>
__global__ __launch_bounds__(WW * SPLIT) void conv_off_kernel(
    const float* __restrict__ in,    // (B, CIN, HH, WW)
    const float* __restrict__ wt,    // (27, CIN, 3, 3)
    const float* __restrict__ bias,  // (27)
    float* __restrict__ om)          // (B, 27, HH, WW)
{
    constexpr int POS  = WW;
    constexpr int NT   = WW * SPLIT;
    constexpr int CPG  = CIN / SPLIT;
    constexpr int NCH  = CPG / CC;
    constexpr int SLABN = SPLIT * CC * 3 * POS;
    constexpr int REDN  = 27 * SPLIT * POS;
    constexpr int SMEMN = (SLABN > REDN) ? SLABN : REDN;

    __shared__ __align__(16) float smem[SMEMN];
    float* slab = smem;
    float* red  = smem;

    const int tid = threadIdx.x;
    const int pos = tid & (POS - 1);
    const int g   = tid / POS;
    const int row = blockIdx.x;
    const int b   = blockIdx.y;

    const float* ib = in + (size_t)b * CIN * HH * WW;
    const int cbs = __builtin_amdgcn_readfirstlane(g * CPG);

    float acc[27];
#pragma unroll
    for (int o = 0; o < 27; ++o) acc[o] = 0.f;

    for (int ch = 0; ch < NCH; ++ch) {
        const int c0 = ch * CC;
        for (int i = tid; i < SLABN; i += NT) {
            const int gg = i / (CC * 3 * POS);
            const int r1 = i - gg * (CC * 3 * POS);
            const int cc = r1 / (3 * POS);
            const int r2 = r1 - cc * 3 * POS;
            const int rr = r2 / POS;
            const int px = r2 - rr * POS;
            const int c  = gg * CPG + c0 + cc;
            const int iy = row + rr - 1;
            float v = 0.f;
            if (iy >= 0 && iy < HH) v = ib[((size_t)c * HH + iy) * WW + px];
            slab[i] = v;
        }
        __syncthreads();

        const float* myslab = slab + g * (CC * 3 * POS);
        for (int cc = 0; cc < CC; ++cc) {
            const float* sl = myslab + cc * 3 * POS;
            float v[9];
            const int xm = (pos > 0) ? pos - 1 : 0;
            const int xp = (pos < POS - 1) ? pos + 1 : POS - 1;
#pragma unroll
            for (int r = 0; r < 3; ++r) {
                const float tl = sl[r * POS + xm];
                const float tc = sl[r * POS + pos];
                const float tr = sl[r * POS + xp];
                v[r * 3 + 0] = (pos > 0) ? tl : 0.f;
                v[r * 3 + 1] = tc;
                v[r * 3 + 2] = (pos < POS - 1) ? tr : 0.f;
            }
            const float* wp = wt + (size_t)(cbs + c0 + cc) * 9;
#pragma unroll
            for (int o = 0; o < 27; ++o) {
                const float* w9 = wp + (size_t)o * CIN * 9;
#pragma unroll
                for (int k = 0; k < 9; ++k)
                    acc[o] = fmaf(w9[k], v[k], acc[o]);
            }
        }
        __syncthreads();
    }

#pragma unroll
    for (int o = 0; o < 27; ++o) red[(o * SPLIT + g) * POS + pos] = acc[o];
    __syncthreads();

    float* ob = om + (size_t)b * 27 * HH * WW + (size_t)row * WW;
    for (int i = tid; i < 27 * POS; i += NT) {
        const int o  = i / POS;
        const int px = i - o * POS;
        float s = bias[o];
#pragma unroll
        for (int gg = 0; gg < SPLIT; ++gg)
            s += red[(o * SPLIT + gg) * POS + px];
        ob[(size_t)o * HH * WW + px] = s;
    }
}

// ---------------- sampler: one KC=32 chunk, channel-major K -----------------
// Per lane: 8 consecutive k = c*9+k9; per sample: 1 packed LDS entry read +
// 4 unconditional clamped loads + 4 FMAs; bf16 hi/lo split; 2 LDS stores.
template <int CIN, int HH, int WW, int POS, int KS>
__device__ __forceinline__ void sample_chunk(
    const float* __restrict__ xb, const ushort4* __restrict__ eoffu,
    const float4* __restrict__ ewt, ushort* __restrict__ Shi,
    ushort* __restrict__ Slo, int tt, int kbase)
{
    constexpr int HW = HH * WW;
    const int pp = tt & (POS - 1);
    const int j0 = (tt / POS) * 8;
    float s[8];
#pragma unroll
    for (int j = 0; j < 8; ++j) {
        const int kg = kbase + j0 + j;
        const int c  = (kg * 7282) >> 16;       // /9 (exact for kg<2304)
        const int k9 = kg - c * 9;
        const int ei = k9 * POS + pp;
        const ushort4 e  = eoffu[ei];
        const float4  wv = ewt[ei];
        const float* chp = xb + (size_t)c * HW;
        s[j] = chp[e.x] * wv.x + chp[e.y] * wv.y
             + chp[e.z] * wv.z + chp[e.w] * wv.w;
    }
    uint hw[4], lw[4];
#pragma unroll
    for (int q = 0; q < 4; ++q) {
        const ushort h0 = f2bf(s[2 * q]);
        const ushort h1 = f2bf(s[2 * q + 1]);
        const float  l0 = s[2 * q]     - bf2f(h0);
        const float  l1 = s[2 * q + 1] - bf2f(h1);
        hw[q] = (uint)h0 | ((uint)h1 << 16);
        lw[q] = (uint)f2bf(l0) | ((uint)f2bf(l1) << 16);
    }
    uint4 hv; hv.x = hw[0]; hv.y = hw[1]; hv.z = hw[2]; hv.w = hw[3];
    uint4 lv; lv.x = lw[0]; lv.y = lw[1]; lv.z = lw[2]; lv.w = lw[3];
    *(uint4*)&Shi[pp * KS + j0] = hv;
    *(uint4*)&Slo[pp * KS + j0] = lv;
}

// ---------------- fused DCN on MFMA: sample + GEMM + bias + BN + ReLU -------
// ASTAGE=true (KWAVES=1): per chunk {stage A(16KB, coalesced, shared) ||
// sample(ch+1)} -> barrier -> {B+A frags from LDS, 24 MFMA} -> barrier.
// ASTAGE=false: R6 path (inline scattered A loads), KWAVES K-split + reduce.
template <int CIN, int HH, int WW, int POS, int KWAVES, int MINW, bool ASTAGE>
__global__ __launch_bounds__((POS / 16) * KWAVES * 64, MINW) void dcn_mfma_kernel(
    const float* __restrict__ xin,   // (B, CIN, HH, WW)
    const float* __restrict__ om,    // (B, 27, HH, WW)
    const ushort* __restrict__ whi,  // (128, K) bf16 hi (ASTAGE: fragment order)
    const ushort* __restrict__ wlo,  // (128, K) bf16 lo
    const float* __restrict__ bias,
    const float* __restrict__ gam, const float* __restrict__ bet,
    const float* __restrict__ mu,  const float* __restrict__ var,
    float* __restrict__ out)         // (B, 128, HH*WW)
{
    constexpr int HW   = HH * WW;
    constexpr int K    = CIN * 9;
    constexpr int NPQ  = POS / 16;
    constexpr int NT   = NPQ * KWAVES * 64;
    constexpr int KC   = 32;
    constexpr int KS   = 40;                  // S row stride (ushort), pad 8
    constexpr int NCHT = K / KC;
    constexpr int NCH  = NCHT / KWAVES;
    constexpr int SBUF = POS * KS;            // ushorts per (buf, hi|lo)
    constexpr int ABN  = ASTAGE ? 8192 : 0;   // A-stage ushorts (16KB)

    extern __shared__ __align__(16) char smem[];
    ushort4* eoffu = (ushort4*)smem;              // 9*POS * 8B
    float4*  ewt   = (float4*)(eoffu + 9 * POS); // 9*POS * 16B
    float*   invp  = (float*)(ewt + 9 * POS);    // 128
    float*   shp   = invp + 128;                  // 128
    ushort*  Abuf  = (ushort*)(shp + 128);        // ABN ushorts
    ushort*  Sbase = Abuf + ABN;

    const int tid = threadIdx.x;
    const int nt  = HW / POS;
    // bijective XCD swizzle (gridDim.x % 8 == 0): contiguous work per XCD
    const int cpx = gridDim.x >> 3;
    const int bid = (blockIdx.x & 7) * cpx + (blockIdx.x >> 3);
    const int b   = bid / nt;
    const int p0  = (bid - b * nt) * POS;

    // ---- precompute bilinear entries: packed offsets + mask-folded weights -
    const float* omb = om + (size_t)b * 27 * HW;
    for (int i = tid; i < 9 * POS; i += NT) {
        const int k9 = i / POS, pp = i - k9 * POS;
        const int p  = p0 + pp;
        const int yy = p / WW;
        const int xx = p - yy * WW;
        const float oy = omb[(size_t)k9 * HW + p];
        const float ox = omb[(size_t)(9 + k9) * HW + p];
        const float mv = omb[(size_t)(18 + k9) * HW + p];
        const float m  = 1.0f / (1.0f + expf(-mv));
        const int ky = (k9 * 11) >> 5;        // /3 for 0..8
        const int kx = k9 - ky * 3;
        const float py = (float)(yy + ky - 1) + oy;
        const float px = (float)(xx + kx - 1) + ox;
        const float y0f = floorf(py), x0f = floorf(px);
        const int   y0  = (int)y0f,  x0 = (int)x0f;
        const int yc0 = min(max(y0, 0), HH - 1);
        const int yc1 = min(max(y0 + 1, 0), HH - 1);
        const int xc0 = min(max(x0, 0), WW - 1);
        const int xc1 = min(max(x0 + 1, 0), WW - 1);
        const float wy1 = py - y0f, wx1 = px - x0f;
        const float fy0 = (y0 >= 0  && y0 < HH)     ? (1.f - wy1) * m : 0.f;
        const float fy1 = (y0 >= -1 && y0 < HH - 1) ? wy1 * m         : 0.f;
        const float fx0 = (x0 >= 0  && x0 < WW)     ? (1.f - wx1)     : 0.f;
        const float fx1 = (x0 >= -1 && x0 < WW - 1) ? wx1             : 0.f;
        ushort4 e;
        e.x = (ushort)(yc0 * WW + xc0); e.y = (ushort)(yc0 * WW + xc1);
        e.z = (ushort)(yc1 * WW + xc0); e.w = (ushort)(yc1 * WW + xc1);
        float4 wv; wv.x = fy0 * fx0; wv.y = fy0 * fx1;
                   wv.z = fy1 * fx0; wv.w = fy1 * fx1;
        eoffu[i] = e;
        ewt[i]   = wv;
    }
    for (int i = tid; i < 128; i += NT) {
        const float iv = gam[i] * rsqrtf(var[i] + EPSV);
        invp[i] = iv;
        shp[i]  = bet[i] - mu[i] * iv + bias[i] * iv;
    }
    __syncthreads();

    const float* xb   = xin + (size_t)b * CIN * HW;
    const int lane = tid & 63;
    const int w    = tid >> 6;
    const int wq   = w & (NPQ - 1);
    const int kgid = w / NPQ;
    const int tt   = tid & (NPQ * 64 - 1);

    ushort* S00 = Sbase + kgid * (4 * SBUF);

    f32x4 acc[8];
#pragma unroll
    for (int mt = 0; mt < 8; ++mt) acc[mt] = (f32x4){0.f, 0.f, 0.f, 0.f};

    const int mrow = lane & 15;
    const int kq   = lane >> 4;

    sample_chunk<CIN, HH, WW, POS, KS>(xb, eoffu, ewt, S00, S00 + SBUF,
                                       tt, kgid * NCH * KC);
    __syncthreads();

    for (int ch = 0; ch < NCH; ++ch) {
        const int cur = ch & 1;
        ushort* Sc = S00 + (cur * 2) * SBUF;
        if constexpr (ASTAGE) {
            // ---- stage A(ch): 16KB, coalesced, shared by all waves ----
            const size_t wb = (size_t)ch * 4096;
#pragma unroll
            for (int t = 0; t < 1024 / NT; ++t) {
                const int u = tid + t * NT;
                const ushort* srcp = (u < 512)
                    ? (whi + wb + (size_t)u * 8)
                    : (wlo + wb + (size_t)(u - 512) * 8);
                *(short8*)&Abuf[(size_t)u * 8] = *(const short8*)srcp;
            }
            // ---- sample next chunk (gathers overlap A-stage latency) ----
            if (ch + 1 < NCH) {
                ushort* Sn = S00 + ((cur ^ 1) * 2) * SBUF;
                sample_chunk<CIN, HH, WW, POS, KS>(xb, eoffu, ewt,
                                                   Sn, Sn + SBUF, tt,
                                                   (ch + 1) * KC);
            }
            __syncthreads();   // A visible to all waves; S(ch) ready
            const int boff = (wq * 16 + mrow) * KS + kq * 8;
            const short8 bh = *(const short8*)&Sc[boff];
            const short8 bl = *(const short8*)&Sc[SBUF + boff];
#pragma unroll
            for (int mt = 0; mt < 8; ++mt) {
                const int au = (mt * 64 + lane) * 8;
                const short8 ah = *(const short8*)&Abuf[au];
                const short8 al = *(const short8*)&Abuf[4096 + au];
                acc[mt] = __builtin_amdgcn_mfma_f32_16x16x32_bf16(al, bh, acc[mt], 0, 0, 0);
                acc[mt] = __builtin_amdgcn_mfma_f32_16x16x32_bf16(ah, bl, acc[mt], 0, 0, 0);
                acc[mt] = __builtin_amdgcn_mfma_f32_16x16x32_bf16(ah, bh, acc[mt], 0, 0, 0);
            }
            __syncthreads();   // protect Abuf + S bufs for next iteration
        } else {
            const int boff = (wq * 16 + mrow) * KS + kq * 8;
            const short8 bh = *(const short8*)&Sc[boff];
            const short8 bl = *(const short8*)&Sc[SBUF + boff];
            if (ch + 1 < NCH) {
                ushort* Sn = S00 + ((cur ^ 1) * 2) * SBUF;
                sample_chunk<CIN, HH, WW, POS, KS>(xb, eoffu, ewt,
                                                   Sn, Sn + SBUF, tt,
                                                   (kgid * NCH + ch + 1) * KC);
            }
            const size_t abase = (size_t)mrow * K
                               + (size_t)(kgid * NCH + ch) * KC + (size_t)(kq * 8);
#pragma unroll
            for (int mt = 0; mt < 8; ++mt) {
                const size_t ao = abase + (size_t)(mt * 16) * K;
                const short8 ah = *(const short8*)(whi + ao);
                const short8 al = *(const short8*)(wlo + ao);
                acc[mt] = __builtin_amdgcn_mfma_f32_16x16x32_bf16(al, bh, acc[mt], 0, 0, 0);
                acc[mt] = __builtin_amdgcn_mfma_f32_16x16x32_bf16(ah, bl, acc[mt], 0, 0, 0);
                acc[mt] = __builtin_amdgcn_mfma_f32_16x16x32_bf16(ah, bh, acc[mt], 0, 0, 0);
            }
            __syncthreads();
        }
    }

    const int pcolb = wq * 16 + mrow;
    constexpr int RS = POS + 1;
    constexpr int SL = 128 * RS;
    float* red = (float*)Sbase;

    if constexpr (KWAVES == 4) {
        if (kgid >= 2) {
#pragma unroll
            for (int mt = 0; mt < 8; ++mt)
#pragma unroll
                for (int r = 0; r < 4; ++r) {
                    const int co = mt * 16 + kq * 4 + r;
                    red[(kgid - 2) * SL + co * RS + pcolb] = acc[mt][r];
                }
        }
        __syncthreads();
        if (kgid < 2) {
#pragma unroll
            for (int mt = 0; mt < 8; ++mt)
#pragma unroll
                for (int r = 0; r < 4; ++r) {
                    const int co = mt * 16 + kq * 4 + r;
                    acc[mt][r] += red[kgid * SL + co * RS + pcolb];
                }
        }
        __syncthreads();
        if (kgid == 1) {
#pragma unroll
            for (int mt = 0; mt < 8; ++mt)
#pragma unroll
                for (int r = 0; r < 4; ++r) {
                    const int co = mt * 16 + kq * 4 + r;
                    red[co * RS + pcolb] = acc[mt][r];
                }
        }
        __syncthreads();
        if (kgid == 0) {
#pragma unroll
            for (int mt = 0; mt < 8; ++mt)
#pragma unroll
                for (int r = 0; r < 4; ++r) {
                    const int co = mt * 16 + kq * 4 + r;
                    acc[mt][r] += red[co * RS + pcolb];
                }
        }
    } else if constexpr (KWAVES == 2) {
        if (kgid == 1) {
#pragma unroll
            for (int mt = 0; mt < 8; ++mt)
#pragma unroll
                for (int r = 0; r < 4; ++r) {
                    const int co = mt * 16 + kq * 4 + r;
                    red[co * RS + pcolb] = acc[mt][r];
                }
        }
        __syncthreads();
        if (kgid == 0) {
#pragma unroll
            for (int mt = 0; mt < 8; ++mt)
#pragma unroll
                for (int r = 0; r < 4; ++r) {
                    const int co = mt * 16 + kq * 4 + r;
                    acc[mt][r] += red[co * RS + pcolb];
                }
        }
    }

    if (kgid == 0) {
        float* outb = out + (size_t)b * 128 * HW + p0 + pcolb;
#pragma unroll
        for (int mt = 0; mt < 8; ++mt)
#pragma unroll
            for (int r = 0; r < 4; ++r) {
                const int co = mt * 16 + kq * 4 + r;
                outb[(size_t)co * HW] = fmaxf(acc[mt][r] * invp[co] + shp[co], 0.f);
            }
    }
}

// ---------------- depthwise transposed-conv upsample x2 (k=4, pad 2) --------
__global__ __launch_bounds__(256) void upsample_kernel(
    const float* __restrict__ y,    // (4,128,64,64)
    const float* __restrict__ wup,  // (128,1,4,4)
    float* __restrict__ out)        // (4,128,128,128)
{
    const int idx = blockIdx.x * 256 + threadIdx.x;
    const int ox = idx & 127;
    const int oy = (idx >> 7) & 127;
    const int c  = (idx >> 14) & 127;
    const int b  = idx >> 21;

    const float* yc = y + (size_t)(b * 128 + c) * 4096;
    const float* wc = wup + c * 16;

    float acc = 0.f;
#pragma unroll
    for (int ky = 0; ky < 4; ++ky) {
        const int qy = oy + ky - 2;
        if (qy & 1) continue;
        const int iy = qy >> 1;
        if (iy < 0 || iy >= 64) continue;
#pragma unroll
        for (int kx = 0; kx < 4; ++kx) {
            const int qx = ox + kx - 2;
            if (qx & 1) continue;
            const int ix = qx >> 1;
            if (ix < 0 || ix >= 64) continue;
            acc += yc[iy * 64 + ix] * wc[(3 - ky) * 4 + (3 - kx)];
        }
    }
    out[idx] = acc;
}

// ---------------------------------------------------------------------------
extern "C" void kernel_launch(void* const* d_in, const int* in_sizes, int n_in,
                              void* d_out, int out_size, void* d_ws, size_t ws_size,
                              hipStream_t stream) {
    const float* x      = (const float*)d_in[0];
    const float* w_off1 = (const float*)d_in[1];
    const float* b_off1 = (const float*)d_in[2];
    const float* w1     = (const float*)d_in[3];
    const float* b1     = (const float*)d_in[4];
    const float* g1v    = (const float*)d_in[5];
    const float* be1    = (const float*)d_in[6];
    const float* m1     = (const float*)d_in[7];
    const float* v1     = (const float*)d_in[8];
    const float* w_up   = (const float*)d_in[9];
    const float* w_off2 = (const float*)d_in[10];
    const float* b_off2 = (const float*)d_in[11];
    const float* w2     = (const float*)d_in[12];
    const float* b2     = (const float*)d_in[13];
    const float* g2v    = (const float*)d_in[14];
    const float* be2    = (const float*)d_in[15];
    const float* m2     = (const float*)d_in[16];
    const float* v2     = (const float*)d_in[17];

    float* ws  = (float*)d_ws;
    float* om1 = ws;                     // 4*27*4096   =   442368 f
    float* y1  = om1 + 442368;           // 4*128*4096  =  2097152 f
    float* up  = y1 + 2097152;           // 4*128*16384 =  8388608 f
    float* om2 = up + 8388608;           // 4*27*16384  =  1769472 f
    float* outf = (float*)d_out;

    // w1 split parked in `up` (dead until upsample overwrites it)
    ushort* w1hi = (ushort*)up;          // 294912 ushort
    ushort* w1lo = w1hi + 294912;
    // w2 split parked in `y1` (dead after upsample reads it)
    ushort* w2hi = (ushort*)y1;          // 147456 ushort
    ushort* w2lo = w2hi + 147456;

    // prep: split w1 -> bf16 hi/lo (natural channel-major K layout)
    wsplit_kernel<<<(294912 + 255) / 256, 256, 0, stream>>>(w1, w1hi, w1lo, 294912);

    {   // om1 = conv3x3(x, w_off1) + b_off1
        dim3 grid(64, 4);
        conv_off_kernel<256, 64, 64, 8, 8><<<grid, 512, 0, stream>>>(
            x, w_off1, b_off1, om1);
    }
    // y1 = bn_relu(dcn1) — MFMA, POS=32, 4-way K-split, 512 blocks x 8 waves
    // LDS: 2304 + 4608 + 1024 + 40960 = 48896 -> 3 blocks/CU
    dcn_mfma_kernel<256, 64, 64, 32, 4, 4, false>
        <<<4 * (4096 / 32), 512, 48896, stream>>>(
        x, om1, w1hi, w1lo, b1, g1v, be1, m1, v1, y1);
    // up = depthwise transposed upsample (clobbers w1 split — now dead)
    upsample_kernel<<<8388608 / 256, 256, 0, stream>>>(y1, w_up, up);
    // prep: split w2 -> bf16 hi/lo in fragment order (y1 now dead)
    wsplit_perm_kernel<<<(147456 + 255) / 256, 256, 0, stream>>>(
        w2, w2hi, w2lo, 128, 147456);
    {   // om2 = conv3x3(up, w_off2) + b_off2
        dim3 grid(128, 4);
        conv_off_kernel<128, 128, 128, 2, 8><<<grid, 256, 0, stream>>>(
            up, w_off2, b_off2, om2);
    }
    // out = bn_relu(dcn2) — MFMA, POS=64, 1024 blocks x 4 waves, A-staged
    // LDS: 4608 + 9216 + 1024 + 16384 + 20480 = 51712 -> 3 blocks/CU
    dcn_mfma_kernel<128, 128, 128, 64, 1, 3, true>
        <<<4 * (16384 / 64), 256, 51712, stream>>>(
        up, om2, w2hi, w2lo, b2, g2v, be2, m2, v2, outf);
}

// Round 8
// 746.513 us; speedup vs baseline: 1.8000x; 1.1476x over previous
//
#include <hip/hip_runtime.h>
#include <hip/hip_bf16.h>
#include <cmath>

// ---------------------------------------------------------------------------
// Pipeline: y1 = bn_relu(dcn(x, w_off1, b_off1, w1, b1))        (4,128,64,64)
//           up = up_depthwise(y1, w_up, f=2)                    (4,128,128,128)
//           out = bn_relu(dcn(up, w_off2, b_off2, w2, b2))      (4,128,128,128)
// DCN GEMM on mfma_f32_16x16x32_bf16, split-bf16 (hi/lo, 3 products).
// conv_off: column-tiled (CT=64 + 2-halo slab, no edge branches), channel-
// split across blockIdx.z (conv1: z=1 partial parked in dead om2 space,
// summed inside dcn1's entry precompute) -> 16 waves/CU for both convs.
// dcn2 (ASTAGE): w2 pre-permuted to fragment order, A-chunks staged in LDS.
// Workspace: om1 | y1 | up | om2 ; w1-split parked in `up`, w2-split in `y1`,
// om1B (conv1 z=1 partial) parked in om2.
// ---------------------------------------------------------------------------

#define EPSV 1e-5f

typedef __attribute__((ext_vector_type(8))) short short8;
typedef __attribute__((ext_vector_type(4))) float f32x4;

__device__ __forceinline__ ushort f2bf(float f) {
    union { float f; uint u; } v; v.f = f;
    const uint r = v.u + 0x7fffu + ((v.u >> 16) & 1u);   // RNE
    return (ushort)(r >> 16);
}
__device__ __forceinline__ float bf2f(ushort h) {
    union { uint u; float f; } v; v.u = ((uint)h) << 16;
    return v.f;
}

// ---------------- weight split: fp32 -> bf16 hi/lo (natural K layout) -------
__global__ __launch_bounds__(256) void wsplit_kernel(
    const float* __restrict__ w, ushort* __restrict__ hi,
    ushort* __restrict__ lo, int n)
{
    const int i = blockIdx.x * 256 + threadIdx.x;
    if (i >= n) return;
    const float f = w[i];
    const ushort h = f2bf(f);
    hi[i] = h;
    lo[i] = f2bf(f - bf2f(h));
}

// ------- weight split: fp32 -> bf16 hi/lo in per-chunk FRAGMENT order -------
__global__ __launch_bounds__(256) void wsplit_perm_kernel(
    const float* __restrict__ w, ushort* __restrict__ hi,
    ushort* __restrict__ lo, int cin, int n)
{
    const int i = blockIdx.x * 256 + threadIdx.x;
    if (i >= n) return;
    const int cin9 = cin * 9;
    const int co = i / cin9;
    const int k  = i - co * cin9;            // channel-major K index
    const int ch = k >> 5;
    const int kq = (k & 31) >> 3;
    const int j  = k & 7;
    const int mt = co >> 4;
    const int lane = (co & 15) | (kq << 4);
    const size_t dst = ((size_t)(ch * 8 + mt) * 64 + lane) * 8 + j;
    const float f = w[i];
    const ushort h = f2bf(f);
    hi[dst] = h;
    lo[dst] = f2bf(f - bf2f(h));
}

// ---------------- offset conv: 3x3, pad 1, 27 output channels ---------------
// Column-tiled: block = (row, CT-col tile, b, z-channel-half). Slab staged
// with 2-col halo (zero-padded) -> branch-free inner loop. g wave-uniform
// (CT=64). z>0 blocks write partial (no bias) to omB.
template <int CIN, int ZS, int HH, int WW, int CT, int SPLIT, int CC>
__global__ __launch_bounds__(CT * SPLIT) void conv_off_kernel(
    const float* __restrict__ in,    // (B, CIN, HH, WW)
    const float* __restrict__ wt,    // (27, CIN, 3, 3)
    const float* __restrict__ bias,  // (27)
    float* __restrict__ om,          // (B, 27, HH, WW)  z==0
    float* __restrict__ omB)         // (B, 27, HH, WW)  z==1 partial
{
    constexpr int NT   = CT * SPLIT;
    constexpr int CPB  = CIN / ZS;           // channels per block (z)
    constexpr int CPG  = CPB / SPLIT;        // channels per group
    constexpr int NCH  = CPG / CC;
    constexpr int CTP  = CT + 2;
    constexpr int SLABN = SPLIT * CC * 3 * CTP;
    constexpr int REDN  = 27 * SPLIT * CT;
    constexpr int SMEMN = (SLABN > REDN) ? SLABN : REDN;
    constexpr int NCT  = WW / CT;

    __shared__ __align__(16) float smem[SMEMN];
    float* slab = smem;
    float* red  = smem;

    const int tid = threadIdx.x;
    const int pos = tid & (CT - 1);
    const int g   = tid / CT;                // wave-uniform (CT=64)
    const int row = blockIdx.x / NCT;
    const int c0  = (blockIdx.x - row * NCT) * CT;
    const int b   = blockIdx.y;
    const int z   = blockIdx.z;

    const float* ib = in + (size_t)b * CIN * HH * WW;
    const int cbs = __builtin_amdgcn_readfirstlane(z * CPB + g * CPG);

    float acc[27];
#pragma unroll
    for (int o = 0; o < 27; ++o) acc[o] = 0.f;

    for (int ch = 0; ch < NCH; ++ch) {
        const int c0ch = ch * CC;
        // ---- stage slab with halo: [g][cc][3][CTP], zero-padded ----
        for (int i = tid; i < SLABN; i += NT) {
            const int gg = i / (CC * 3 * CTP);
            const int r1 = i - gg * (CC * 3 * CTP);
            const int cc = r1 / (3 * CTP);
            const int r2 = r1 - cc * 3 * CTP;
            const int rr = r2 / CTP;
            const int px = r2 - rr * CTP;
            const int c  = z * CPB + gg * CPG + c0ch + cc;
            const int iy = row + rr - 1;
            const int ix = c0 + px - 1;
            float v = 0.f;
            if (iy >= 0 && iy < HH && ix >= 0 && ix < WW)
                v = ib[((size_t)c * HH + iy) * WW + ix];
            slab[i] = v;
        }
        __syncthreads();

        // ---- compute: branch-free 3x3 window from halo slab ----
        const float* myslab = slab + g * (CC * 3 * CTP);
        for (int cc = 0; cc < CC; ++cc) {
            const float* sl = myslab + cc * 3 * CTP;
            float v[9];
#pragma unroll
            for (int r = 0; r < 3; ++r) {
                v[r * 3 + 0] = sl[r * CTP + pos];
                v[r * 3 + 1] = sl[r * CTP + pos + 1];
                v[r * 3 + 2] = sl[r * CTP + pos + 2];
            }
            const float* wp = wt + (size_t)(cbs + c0ch + cc) * 9;
#pragma unroll
            for (int o = 0; o < 27; ++o) {
                const float* w9 = wp + (size_t)o * CIN * 9;
#pragma unroll
                for (int k = 0; k < 9; ++k)
                    acc[o] = fmaf(w9[k], v[k], acc[o]);
            }
        }
        __syncthreads();
    }

    // ---- in-block reduce over channel groups (deterministic) ----
#pragma unroll
    for (int o = 0; o < 27; ++o) red[(o * SPLIT + g) * CT + pos] = acc[o];
    __syncthreads();

    float* outp = (z == 0) ? om : omB;
    float* ob = outp + (size_t)b * 27 * HH * WW + (size_t)row * WW + c0;
    for (int i = tid; i < 27 * CT; i += NT) {
        const int o  = i / CT;
        const int px = i - o * CT;
        float s = (z == 0) ? bias[o] : 0.f;
#pragma unroll
        for (int gg = 0; gg < SPLIT; ++gg)
            s += red[(o * SPLIT + gg) * CT + px];
        ob[(size_t)o * HH * WW + px] = s;
    }
}

// ---------------- sampler: one KC=32 chunk, channel-major K -----------------
template <int CIN, int HH, int WW, int POS, int KS>
__device__ __forceinline__ void sample_chunk(
    const float* __restrict__ xb, const ushort4* __restrict__ eoffu,
    const float4* __restrict__ ewt, ushort* __restrict__ Shi,
    ushort* __restrict__ Slo, int tt, int kbase)
{
    constexpr int HW = HH * WW;
    const int pp = tt & (POS - 1);
    const int j0 = (tt / POS) * 8;
    float s[8];
#pragma unroll
    for (int j = 0; j < 8; ++j) {
        const int kg = kbase + j0 + j;
        const int c  = (kg * 7282) >> 16;       // /9 (exact for kg<2304)
        const int k9 = kg - c * 9;
        const int ei = k9 * POS + pp;
        const ushort4 e  = eoffu[ei];
        const float4  wv = ewt[ei];
        const float* chp = xb + (size_t)c * HW;
        s[j] = chp[e.x] * wv.x + chp[e.y] * wv.y
             + chp[e.z] * wv.z + chp[e.w] * wv.w;
    }
    uint hw[4], lw[4];
#pragma unroll
    for (int q = 0; q < 4; ++q) {
        const ushort h0 = f2bf(s[2 * q]);
        const ushort h1 = f2bf(s[2 * q + 1]);
        const float  l0 = s[2 * q]     - bf2f(h0);
        const float  l1 = s[2 * q + 1] - bf2f(h1);
        hw[q] = (uint)h0 | ((uint)h1 << 16);
        lw[q] = (uint)f2bf(l0) | ((uint)f2bf(l1) << 16);
    }
    uint4 hv; hv.x = hw[0]; hv.y = hw[1]; hv.z = hw[2]; hv.w = hw[3];
    uint4 lv; lv.x = lw[0]; lv.y = lw[1]; lv.z = lw[2]; lv.w = lw[3];
    *(uint4*)&Shi[pp * KS + j0] = hv;
    *(uint4*)&Slo[pp * KS + j0] = lv;
}

// ---------------- fused DCN on MFMA: sample + GEMM + bias + BN + ReLU -------
// OMS: om is split (om + omB partials summed in entry precompute).
template <int CIN, int HH, int WW, int POS, int KWAVES, int MINW,
          bool ASTAGE, bool OMS>
__global__ __launch_bounds__((POS / 16) * KWAVES * 64, MINW) void dcn_mfma_kernel(
    const float* __restrict__ xin,   // (B, CIN, HH, WW)
    const float* __restrict__ om,    // (B, 27, HH, WW)
    const float* __restrict__ omB,   // partial (OMS only)
    const ushort* __restrict__ whi,  // (128, K) bf16 hi (ASTAGE: fragment order)
    const ushort* __restrict__ wlo,  // (128, K) bf16 lo
    const float* __restrict__ bias,
    const float* __restrict__ gam, const float* __restrict__ bet,
    const float* __restrict__ mu,  const float* __restrict__ var,
    float* __restrict__ out)         // (B, 128, HH*WW)
{
    constexpr int HW   = HH * WW;
    constexpr int K    = CIN * 9;
    constexpr int NPQ  = POS / 16;
    constexpr int NT   = NPQ * KWAVES * 64;
    constexpr int KC   = 32;
    constexpr int KS   = 40;                  // S row stride (ushort), pad 8
    constexpr int NCHT = K / KC;
    constexpr int NCH  = NCHT / KWAVES;
    constexpr int SBUF = POS * KS;            // ushorts per (buf, hi|lo)
    constexpr int ABN  = ASTAGE ? 8192 : 0;   // A-stage ushorts (16KB)

    extern __shared__ __align__(16) char smem[];
    ushort4* eoffu = (ushort4*)smem;              // 9*POS * 8B
    float4*  ewt   = (float4*)(eoffu + 9 * POS); // 9*POS * 16B
    float*   invp  = (float*)(ewt + 9 * POS);    // 128
    float*   shp   = invp + 128;                  // 128
    ushort*  Abuf  = (ushort*)(shp + 128);        // ABN ushorts
    ushort*  Sbase = Abuf + ABN;

    const int tid = threadIdx.x;
    const int nt  = HW / POS;
    // bijective XCD swizzle (gridDim.x % 8 == 0)
    const int cpx = gridDim.x >> 3;
    const int bid = (blockIdx.x & 7) * cpx + (blockIdx.x >> 3);
    const int b   = bid / nt;
    const int p0  = (bid - b * nt) * POS;

    // ---- precompute bilinear entries: packed offsets + mask-folded weights -
    const float* omb  = om + (size_t)b * 27 * HW;
    const float* ombB = OMS ? (omB + (size_t)b * 27 * HW) : nullptr;
    for (int i = tid; i < 9 * POS; i += NT) {
        const int k9 = i / POS, pp = i - k9 * POS;
        const int p  = p0 + pp;
        const int yy = p / WW;
        const int xx = p - yy * WW;
        float oy = omb[(size_t)k9 * HW + p];
        float ox = omb[(size_t)(9 + k9) * HW + p];
        float mv = omb[(size_t)(18 + k9) * HW + p];
        if constexpr (OMS) {
            oy += ombB[(size_t)k9 * HW + p];
            ox += ombB[(size_t)(9 + k9) * HW + p];
            mv += ombB[(size_t)(18 + k9) * HW + p];
        }
        const float m  = 1.0f / (1.0f + expf(-mv));
        const int ky = (k9 * 11) >> 5;        // /3 for 0..8
        const int kx = k9 - ky * 3;
        const float py = (float)(yy + ky - 1) + oy;
        const float px = (float)(xx + kx - 1) + ox;
        const float y0f = floorf(py), x0f = floorf(px);
        const int   y0  = (int)y0f,  x0 = (int)x0f;
        const int yc0 = min(max(y0, 0), HH - 1);
        const int yc1 = min(max(y0 + 1, 0), HH - 1);
        const int xc0 = min(max(x0, 0), WW - 1);
        const int xc1 = min(max(x0 + 1, 0), WW - 1);
        const float wy1 = py - y0f, wx1 = px - x0f;
        const float fy0 = (y0 >= 0  && y0 < HH)     ? (1.f - wy1) * m : 0.f;
        const float fy1 = (y0 >= -1 && y0 < HH - 1) ? wy1 * m         : 0.f;
        const float fx0 = (x0 >= 0  && x0 < WW)     ? (1.f - wx1)     : 0.f;
        const float fx1 = (x0 >= -1 && x0 < WW - 1) ? wx1             : 0.f;
        ushort4 e;
        e.x = (ushort)(yc0 * WW + xc0); e.y = (ushort)(yc0 * WW + xc1);
        e.z = (ushort)(yc1 * WW + xc0); e.w = (ushort)(yc1 * WW + xc1);
        float4 wv; wv.x = fy0 * fx0; wv.y = fy0 * fx1;
                   wv.z = fy1 * fx0; wv.w = fy1 * fx1;
        eoffu[i] = e;
        ewt[i]   = wv;
    }
    for (int i = tid; i < 128; i += NT) {
        const float iv = gam[i] * rsqrtf(var[i] + EPSV);
        invp[i] = iv;
        shp[i]  = bet[i] - mu[i] * iv + bias[i] * iv;
    }
    __syncthreads();

    const float* xb   = xin + (size_t)b * CIN * HW;
    const int lane = tid & 63;
    const int w    = tid >> 6;
    const int wq   = w & (NPQ - 1);
    const int kgid = w / NPQ;
    const int tt   = tid & (NPQ * 64 - 1);

    ushort* S00 = Sbase + kgid * (4 * SBUF);

    f32x4 acc[8];
#pragma unroll
    for (int mt = 0; mt < 8; ++mt) acc[mt] = (f32x4){0.f, 0.f, 0.f, 0.f};

    const int mrow = lane & 15;
    const int kq   = lane >> 4;

    sample_chunk<CIN, HH, WW, POS, KS>(xb, eoffu, ewt, S00, S00 + SBUF,
                                       tt, kgid * NCH * KC);
    __syncthreads();

    for (int ch = 0; ch < NCH; ++ch) {
        const int cur = ch & 1;
        ushort* Sc = S00 + (cur * 2) * SBUF;
        if constexpr (ASTAGE) {
            // ---- stage A(ch): 16KB, coalesced, shared by all waves ----
            const size_t wb = (size_t)ch * 4096;
#pragma unroll
            for (int t = 0; t < 1024 / NT; ++t) {
                const int u = tid + t * NT;
                const ushort* srcp = (u < 512)
                    ? (whi + wb + (size_t)u * 8)
                    : (wlo + wb + (size_t)(u - 512) * 8);
                *(short8*)&Abuf[(size_t)u * 8] = *(const short8*)srcp;
            }
            // ---- sample next chunk (gathers overlap A-stage latency) ----
            if (ch + 1 < NCH) {
                ushort* Sn = S00 + ((cur ^ 1) * 2) * SBUF;
                sample_chunk<CIN, HH, WW, POS, KS>(xb, eoffu, ewt,
                                                   Sn, Sn + SBUF, tt,
                                                   (ch + 1) * KC);
            }
            __syncthreads();   // A visible to all waves; S(ch) ready
            const int boff = (wq * 16 + mrow) * KS + kq * 8;
            const short8 bh = *(const short8*)&Sc[boff];
            const short8 bl = *(const short8*)&Sc[SBUF + boff];
#pragma unroll
            for (int mt = 0; mt < 8; ++mt) {
                const int au = (mt * 64 + lane) * 8;
                const short8 ah = *(const short8*)&Abuf[au];
                const short8 al = *(const short8*)&Abuf[4096 + au];
                acc[mt] = __builtin_amdgcn_mfma_f32_16x16x32_bf16(al, bh, acc[mt], 0, 0, 0);
                acc[mt] = __builtin_amdgcn_mfma_f32_16x16x32_bf16(ah, bl, acc[mt], 0, 0, 0);
                acc[mt] = __builtin_amdgcn_mfma_f32_16x16x32_bf16(ah, bh, acc[mt], 0, 0, 0);
            }
            __syncthreads();   // protect Abuf + S bufs for next iteration
        } else {
            const int boff = (wq * 16 + mrow) * KS + kq * 8;
            const short8 bh = *(const short8*)&Sc[boff];
            const short8 bl = *(const short8*)&Sc[SBUF + boff];
            if (ch + 1 < NCH) {
                ushort* Sn = S00 + ((cur ^ 1) * 2) * SBUF;
                sample_chunk<CIN, HH, WW, POS, KS>(xb, eoffu, ewt,
                                                   Sn, Sn + SBUF, tt,
                                                   (kgid * NCH + ch + 1) * KC);
            }
            const size_t abase = (size_t)mrow * K
                               + (size_t)(kgid * NCH + ch) * KC + (size_t)(kq * 8);
#pragma unroll
            for (int mt = 0; mt < 8; ++mt) {
                const size_t ao = abase + (size_t)(mt * 16) * K;
                const short8 ah = *(const short8*)(whi + ao);
                const short8 al = *(const short8*)(wlo + ao);
                acc[mt] = __builtin_amdgcn_mfma_f32_16x16x32_bf16(al, bh, acc[mt], 0, 0, 0);
                acc[mt] = __builtin_amdgcn_mfma_f32_16x16x32_bf16(ah, bl, acc[mt], 0, 0, 0);
                acc[mt] = __builtin_amdgcn_mfma_f32_16x16x32_bf16(ah, bh, acc[mt], 0, 0, 0);
            }
            __syncthreads();
        }
    }

    const int pcolb = wq * 16 + mrow;
    constexpr int RS = POS + 1;
    constexpr int SL = 128 * RS;
    float* red = (float*)Sbase;

    if constexpr (KWAVES == 4) {
        if (kgid >= 2) {
#pragma unroll
            for (int mt = 0; mt < 8; ++mt)
#pragma unroll
                for (int r = 0; r < 4; ++r) {
                    const int co = mt * 16 + kq * 4 + r;
                    red[(kgid - 2) * SL + co * RS + pcolb] = acc[mt][r];
                }
        }
        __syncthreads();
        if (kgid < 2) {
#pragma unroll
            for (int mt = 0; mt < 8; ++mt)
#pragma unroll
                for (int r = 0; r < 4; ++r) {
                    const int co = mt * 16 + kq * 4 + r;
                    acc[mt][r] += red[kgid * SL + co * RS + pcolb];
                }
        }
        __syncthreads();
        if (kgid == 1) {
#pragma unroll
            for (int mt = 0; mt < 8; ++mt)
#pragma unroll
                for (int r = 0; r < 4; ++r) {
                    const int co = mt * 16 + kq * 4 + r;
                    red[co * RS + pcolb] = acc[mt][r];
                }
        }
        __syncthreads();
        if (kgid == 0) {
#pragma unroll
            for (int mt = 0; mt < 8; ++mt)
#pragma unroll
                for (int r = 0; r < 4; ++r) {
                    const int co = mt * 16 + kq * 4 + r;
                    acc[mt][r] += red[co * RS + pcolb];
                }
        }
    } else if constexpr (KWAVES == 2) {
        if (kgid == 1) {
#pragma unroll
            for (int mt = 0; mt < 8; ++mt)
#pragma unroll
                for (int r = 0; r < 4; ++r) {
                    const int co = mt * 16 + kq * 4 + r;
                    red[co * RS + pcolb] = acc[mt][r];
                }
        }
        __syncthreads();
        if (kgid == 0) {
#pragma unroll
            for (int mt = 0; mt < 8; ++mt)
#pragma unroll
                for (int r = 0; r < 4; ++r) {
                    const int co = mt * 16 + kq * 4 + r;
                    acc[mt][r] += red[co * RS + pcolb];
                }
        }
    }

    if (kgid == 0) {
        float* outb = out + (size_t)b * 128 * HW + p0 + pcolb;
#pragma unroll
        for (int mt = 0; mt < 8; ++mt)
#pragma unroll
            for (int r = 0; r < 4; ++r) {
                const int co = mt * 16 + kq * 4 + r;
                outb[(size_t)co * HW] = fmaxf(acc[mt][r] * invp[co] + shp[co], 0.f);
            }
    }
}

// ---------------- depthwise transposed-conv upsample x2 (k=4, pad 2) --------
__global__ __launch_bounds__(256) void upsample_kernel(
    const float* __restrict__ y,    // (4,128,64,64)
    const float* __restrict__ wup,  // (128,1,4,4)
    float* __restrict__ out)        // (4,128,128,128)
{
    const int idx = blockIdx.x * 256 + threadIdx.x;
    const int ox = idx & 127;
    const int oy = (idx >> 7) & 127;
    const int c  = (idx >> 14) & 127;
    const int b  = idx >> 21;

    const float* yc = y + (size_t)(b * 128 + c) * 4096;
    const float* wc = wup + c * 16;

    float acc = 0.f;
#pragma unroll
    for (int ky = 0; ky < 4; ++ky) {
        const int qy = oy + ky - 2;
        if (qy & 1) continue;
        const int iy = qy >> 1;
        if (iy < 0 || iy >= 64) continue;
#pragma unroll
        for (int kx = 0; kx < 4; ++kx) {
            const int qx = ox + kx - 2;
            if (qx & 1) continue;
            const int ix = qx >> 1;
            if (ix < 0 || ix >= 64) continue;
            acc += yc[iy * 64 + ix] * wc[(3 - ky) * 4 + (3 - kx)];
        }
    }
    out[idx] = acc;
}

// ---------------------------------------------------------------------------
extern "C" void kernel_launch(void* const* d_in, const int* in_sizes, int n_in,
                              void* d_out, int out_size, void* d_ws, size_t ws_size,
                              hipStream_t stream) {
    const float* x      = (const float*)d_in[0];
    const float* w_off1 = (const float*)d_in[1];
    const float* b_off1 = (const float*)d_in[2];
    const float* w1     = (const float*)d_in[3];
    const float* b1     = (const float*)d_in[4];
    const float* g1v    = (const float*)d_in[5];
    const float* be1    = (const float*)d_in[6];
    const float* m1     = (const float*)d_in[7];
    const float* v1     = (const float*)d_in[8];
    const float* w_up   = (const float*)d_in[9];
    const float* w_off2 = (const float*)d_in[10];
    const float* b_off2 = (const float*)d_in[11];
    const float* w2     = (const float*)d_in[12];
    const float* b2     = (const float*)d_in[13];
    const float* g2v    = (const float*)d_in[14];
    const float* be2    = (const float*)d_in[15];
    const float* m2     = (const float*)d_in[16];
    const float* v2     = (const float*)d_in[17];

    float* ws  = (float*)d_ws;
    float* om1 = ws;                     // 4*27*4096   =   442368 f
    float* y1  = om1 + 442368;           // 4*128*4096  =  2097152 f
    float* up  = y1 + 2097152;           // 4*128*16384 =  8388608 f
    float* om2 = up + 8388608;           // 4*27*16384  =  1769472 f
    float* outf = (float*)d_out;

    // w1 split parked in `up` (dead until upsample overwrites it)
    ushort* w1hi = (ushort*)up;          // 294912 ushort
    ushort* w1lo = w1hi + 294912;
    // w2 split parked in `y1` (dead after upsample reads it)
    ushort* w2hi = (ushort*)y1;          // 147456 ushort
    ushort* w2lo = w2hi + 147456;
    // conv1 z=1 partial parked in om2 (dead until conv2 writes it)
    float* om1B = om2;                   // 442368 f <= 1769472 f

    // prep: split w1 -> bf16 hi/lo (natural channel-major K layout)
    wsplit_kernel<<<(294912 + 255) / 256, 256, 0, stream>>>(w1, w1hi, w1lo, 294912);

    {   // om1/om1B = conv3x3(x, w_off1) + b_off1 — 2-way channel z-split
        // CT=64, SPLIT=8, CC=4: 512 thr, grid 64x4x2=512 -> 16 waves/CU
        dim3 grid(64, 4, 2);
        conv_off_kernel<256, 2, 64, 64, 64, 8, 4><<<grid, 512, 0, stream>>>(
            x, w_off1, b_off1, om1, om1B);
    }
    // y1 = bn_relu(dcn1) — MFMA, POS=32, 4-way K-split; om = om1 + om1B
    dcn_mfma_kernel<256, 64, 64, 32, 4, 4, false, true>
        <<<4 * (4096 / 32), 512, 48896, stream>>>(
        x, om1, om1B, w1hi, w1lo, b1, g1v, be1, m1, v1, y1);
    // up = depthwise transposed upsample (clobbers w1 split — now dead)
    upsample_kernel<<<8388608 / 256, 256, 0, stream>>>(y1, w_up, up);
    // prep: split w2 -> bf16 hi/lo in fragment order (y1 now dead)
    wsplit_perm_kernel<<<(147456 + 255) / 256, 256, 0, stream>>>(
        w2, w2hi, w2lo, 128, 147456);
    {   // om2 = conv3x3(up, w_off2) + b_off2 — column-tiled
        // CT=64, SPLIT=4, CC=8: 256 thr, grid 256x4=1024 -> 16 waves/CU
        dim3 grid(256, 4, 1);
        conv_off_kernel<128, 1, 128, 128, 64, 4, 8><<<grid, 256, 0, stream>>>(
            up, w_off2, b_off2, om2, om2);
    }
    // out = bn_relu(dcn2) — MFMA, POS=64, 1024 blocks x 4 waves, A-staged
    dcn_mfma_kernel<128, 128, 128, 64, 1, 3, true, false>
        <<<4 * (16384 / 64), 256, 51712, stream>>>(
        up, om2, om2, w2hi, w2lo, b2, g2v, be2, m2, v2, outf);
}

// Round 9
// 679.057 us; speedup vs baseline: 1.9788x; 1.0993x over previous
//
#include <hip/hip_runtime.h>
#include <hip/hip_bf16.h>
#include <cmath>

// ---------------------------------------------------------------------------
// Pipeline: y1 = bn_relu(dcn(x, w_off1, b_off1, w1, b1))        (4,128,64,64)
//           up = up_depthwise(y1, w_up, f=2)                    (4,128,128,128)
//           out = bn_relu(dcn(up, w_off2, b_off2, w2, b2))      (4,128,128,128)
// DCN GEMM on mfma_f32_16x16x32_bf16, split-bf16 (hi/lo, 3 products).
// Bilinear gathers PAIRED: one float2 per row (2 loads/sample, edge cases
// folded into precomputed slot weights; bitwise-identical math).
// dcn2 (ASTAGE): A staged in LDS; T14 split sampler: gathers for ch+1 are
// ISSUED before a raw s_barrier (lgkmcnt-only — no vmcnt drain) and consumed
// AFTER the MFMA section, hiding gather latency under MFMA.
// conv_off: column-tiled halo slabs, channel z-split. XCD-swizzled dcn grids.
// Workspace: om1 | y1 | up | om2 ; w1-split parked in `up`, w2-split in `y1`,
// om1B (conv1 z=1 partial) parked in om2.
// ---------------------------------------------------------------------------

#define EPSV 1e-5f

typedef __attribute__((ext_vector_type(8))) short short8;
typedef __attribute__((ext_vector_type(4))) float f32x4;

__device__ __forceinline__ ushort f2bf(float f) {
    union { float f; uint u; } v; v.f = f;
    const uint r = v.u + 0x7fffu + ((v.u >> 16) & 1u);   // RNE
    return (ushort)(r >> 16);
}
__device__ __forceinline__ float bf2f(ushort h) {
    union { uint u; float f; } v; v.u = ((uint)h) << 16;
    return v.f;
}
__device__ __forceinline__ float2 ld2u(const float* p) {
    float2 v; __builtin_memcpy(&v, p, sizeof(float2)); return v;
}

// ---------------- weight split: fp32 -> bf16 hi/lo (natural K layout) -------
__global__ __launch_bounds__(256) void wsplit_kernel(
    const float* __restrict__ w, ushort* __restrict__ hi,
    ushort* __restrict__ lo, int n)
{
    const int i = blockIdx.x * 256 + threadIdx.x;
    if (i >= n) return;
    const float f = w[i];
    const ushort h = f2bf(f);
    hi[i] = h;
    lo[i] = f2bf(f - bf2f(h));
}

// ------- weight split: fp32 -> bf16 hi/lo in per-chunk FRAGMENT order -------
__global__ __launch_bounds__(256) void wsplit_perm_kernel(
    const float* __restrict__ w, ushort* __restrict__ hi,
    ushort* __restrict__ lo, int cin, int n)
{
    const int i = blockIdx.x * 256 + threadIdx.x;
    if (i >= n) return;
    const int cin9 = cin * 9;
    const int co = i / cin9;
    const int k  = i - co * cin9;            // channel-major K index
    const int ch = k >> 5;
    const int kq = (k & 31) >> 3;
    const int j  = k & 7;
    const int mt = co >> 4;
    const int lane = (co & 15) | (kq << 4);
    const size_t dst = ((size_t)(ch * 8 + mt) * 64 + lane) * 8 + j;
    const float f = w[i];
    const ushort h = f2bf(f);
    hi[dst] = h;
    lo[dst] = f2bf(f - bf2f(h));
}

// ---------------- offset conv: 3x3, pad 1, 27 output channels ---------------
template <int CIN, int ZS, int HH, int WW, int CT, int SPLIT, int CC>
__global__ __launch_bounds__(CT * SPLIT) void conv_off_kernel(
    const float* __restrict__ in,    // (B, CIN, HH, WW)
    const float* __restrict__ wt,    // (27, CIN, 3, 3)
    const float* __restrict__ bias,  // (27)
    float* __restrict__ om,          // (B, 27, HH, WW)  z==0
    float* __restrict__ omB)         // (B, 27, HH, WW)  z==1 partial
{
    constexpr int NT   = CT * SPLIT;
    constexpr int CPB  = CIN / ZS;
    constexpr int CPG  = CPB / SPLIT;
    constexpr int NCH  = CPG / CC;
    constexpr int CTP  = CT + 2;
    constexpr int SLABN = SPLIT * CC * 3 * CTP;
    constexpr int REDN  = 27 * SPLIT * CT;
    constexpr int SMEMN = (SLABN > REDN) ? SLABN : REDN;
    constexpr int NCT  = WW / CT;

    __shared__ __align__(16) float smem[SMEMN];
    float* slab = smem;
    float* red  = smem;

    const int tid = threadIdx.x;
    const int pos = tid & (CT - 1);
    const int g   = tid / CT;                // wave-uniform (CT=64)
    const int row = blockIdx.x / NCT;
    const int c0  = (blockIdx.x - row * NCT) * CT;
    const int b   = blockIdx.y;
    const int z   = blockIdx.z;

    const float* ib = in + (size_t)b * CIN * HH * WW;
    const int cbs = __builtin_amdgcn_readfirstlane(z * CPB + g * CPG);

    float acc[27];
#pragma unroll
    for (int o = 0; o < 27; ++o) acc[o] = 0.f;

    for (int ch = 0; ch < NCH; ++ch) {
        const int c0ch = ch * CC;
        for (int i = tid; i < SLABN; i += NT) {
            const int gg = i / (CC * 3 * CTP);
            const int r1 = i - gg * (CC * 3 * CTP);
            const int cc = r1 / (3 * CTP);
            const int r2 = r1 - cc * 3 * CTP;
            const int rr = r2 / CTP;
            const int px = r2 - rr * CTP;
            const int c  = z * CPB + gg * CPG + c0ch + cc;
            const int iy = row + rr - 1;
            const int ix = c0 + px - 1;
            float v = 0.f;
            if (iy >= 0 && iy < HH && ix >= 0 && ix < WW)
                v = ib[((size_t)c * HH + iy) * WW + ix];
            slab[i] = v;
        }
        __syncthreads();

        const float* myslab = slab + g * (CC * 3 * CTP);
        for (int cc = 0; cc < CC; ++cc) {
            const float* sl = myslab + cc * 3 * CTP;
            float v[9];
#pragma unroll
            for (int r = 0; r < 3; ++r) {
                v[r * 3 + 0] = sl[r * CTP + pos];
                v[r * 3 + 1] = sl[r * CTP + pos + 1];
                v[r * 3 + 2] = sl[r * CTP + pos + 2];
            }
            const float* wp = wt + (size_t)(cbs + c0ch + cc) * 9;
#pragma unroll
            for (int o = 0; o < 27; ++o) {
                const float* w9 = wp + (size_t)o * CIN * 9;
#pragma unroll
                for (int k = 0; k < 9; ++k)
                    acc[o] = fmaf(w9[k], v[k], acc[o]);
            }
        }
        __syncthreads();
    }

#pragma unroll
    for (int o = 0; o < 27; ++o) red[(o * SPLIT + g) * CT + pos] = acc[o];
    __syncthreads();

    float* outp = (z == 0) ? om : omB;
    float* ob = outp + (size_t)b * 27 * HH * WW + (size_t)row * WW + c0;
    for (int i = tid; i < 27 * CT; i += NT) {
        const int o  = i / CT;
        const int px = i - o * CT;
        float s = (z == 0) ? bias[o] : 0.f;
#pragma unroll
        for (int gg = 0; gg < SPLIT; ++gg)
            s += red[(o * SPLIT + gg) * CT + px];
        ob[(size_t)o * HH * WW + px] = s;
    }
}

// ---------------- paired sampler: issue / finish ----------------------------
// Entry: uint (off_row0 | off_row1<<16, base col clamped to W-2) +
// float4 slot weights (validity/mask/edge-remap folded at precompute).
template <int CIN, int HH, int WW, int POS>
__device__ __forceinline__ void sample_issue(
    const float* __restrict__ xb, const uint* __restrict__ eoff2,
    float2* v0, float2* v1, int tt, int kbase)
{
    constexpr int HW = HH * WW;
    const int pp = tt & (POS - 1);
    const int j0 = (tt / POS) * 8;
#pragma unroll
    for (int j = 0; j < 8; ++j) {
        const int kg = kbase + j0 + j;
        const int c  = (kg * 7282) >> 16;       // /9 (exact for kg<2304)
        const int k9 = kg - c * 9;
        const uint e = eoff2[k9 * POS + pp];
        const float* chp = xb + (size_t)c * HW;
        v0[j] = ld2u(chp + (e & 0xffffu));
        v1[j] = ld2u(chp + (e >> 16));
    }
}

template <int CIN, int HH, int WW, int POS, int KS>
__device__ __forceinline__ void sample_finish(
    const float4* __restrict__ ewt, const float2* v0, const float2* v1,
    ushort* __restrict__ Shi, ushort* __restrict__ Slo, int tt, int kbase)
{
    const int pp = tt & (POS - 1);
    const int j0 = (tt / POS) * 8;
    float s[8];
#pragma unroll
    for (int j = 0; j < 8; ++j) {
        const int kg = kbase + j0 + j;
        const int c  = (kg * 7282) >> 16;
        const int k9 = kg - c * 9;
        const float4 wv = ewt[k9 * POS + pp];
        s[j] = v0[j].x * wv.x + v0[j].y * wv.y
             + v1[j].x * wv.z + v1[j].y * wv.w;
    }
    uint hw[4], lw[4];
#pragma unroll
    for (int q = 0; q < 4; ++q) {
        const ushort h0 = f2bf(s[2 * q]);
        const ushort h1 = f2bf(s[2 * q + 1]);
        const float  l0 = s[2 * q]     - bf2f(h0);
        const float  l1 = s[2 * q + 1] - bf2f(h1);
        hw[q] = (uint)h0 | ((uint)h1 << 16);
        lw[q] = (uint)f2bf(l0) | ((uint)f2bf(l1) << 16);
    }
    uint4 hv; hv.x = hw[0]; hv.y = hw[1]; hv.z = hw[2]; hv.w = hw[3];
    uint4 lv; lv.x = lw[0]; lv.y = lw[1]; lv.z = lw[2]; lv.w = lw[3];
    *(uint4*)&Shi[pp * KS + j0] = hv;
    *(uint4*)&Slo[pp * KS + j0] = lv;
}

template <int CIN, int HH, int WW, int POS, int KS>
__device__ __forceinline__ void sample_chunk(
    const float* __restrict__ xb, const uint* __restrict__ eoff2,
    const float4* __restrict__ ewt, ushort* __restrict__ Shi,
    ushort* __restrict__ Slo, int tt, int kbase)
{
    float2 v0[8], v1[8];
    sample_issue<CIN, HH, WW, POS>(xb, eoff2, v0, v1, tt, kbase);
    sample_finish<CIN, HH, WW, POS, KS>(ewt, v0, v1, Shi, Slo, tt, kbase);
}

// ---------------- fused DCN on MFMA: sample + GEMM + bias + BN + ReLU -------
template <int CIN, int HH, int WW, int POS, int KWAVES, int MINW,
          bool ASTAGE, bool OMS>
__global__ __launch_bounds__((POS / 16) * KWAVES * 64, MINW) void dcn_mfma_kernel(
    const float* __restrict__ xin,   // (B, CIN, HH, WW)
    const float* __restrict__ om,    // (B, 27, HH, WW)
    const float* __restrict__ omB,   // partial (OMS only)
    const ushort* __restrict__ whi,  // (128, K) bf16 hi (ASTAGE: fragment order)
    const ushort* __restrict__ wlo,  // (128, K) bf16 lo
    const float* __restrict__ bias,
    const float* __restrict__ gam, const float* __restrict__ bet,
    const float* __restrict__ mu,  const float* __restrict__ var,
    float* __restrict__ out)         // (B, 128, HH*WW)
{
    constexpr int HW   = HH * WW;
    constexpr int K    = CIN * 9;
    constexpr int NPQ  = POS / 16;
    constexpr int NT   = NPQ * KWAVES * 64;
    constexpr int KC   = 32;
    constexpr int KS   = 40;                  // S row stride (ushort), pad 8
    constexpr int NCHT = K / KC;
    constexpr int NCH  = NCHT / KWAVES;
    constexpr int SBUF = POS * KS;            // ushorts per (buf, hi|lo)
    constexpr int ABN  = ASTAGE ? 8192 : 0;   // A-stage ushorts (16KB)

    extern __shared__ __align__(16) char smem[];
    uint*    eoff2 = (uint*)smem;                 // 9*POS * 4B
    float4*  ewt   = (float4*)(eoff2 + 9 * POS);  // 9*POS * 16B
    float*   invp  = (float*)(ewt + 9 * POS);     // 128
    float*   shp   = invp + 128;                  // 128
    ushort*  Abuf  = (ushort*)(shp + 128);        // ABN ushorts
    ushort*  Sbase = Abuf + ABN;

    const int tid = threadIdx.x;
    const int nt  = HW / POS;
    // bijective XCD swizzle (gridDim.x % 8 == 0)
    const int cpx = gridDim.x >> 3;
    const int bid = (blockIdx.x & 7) * cpx + (blockIdx.x >> 3);
    const int b   = bid / nt;
    const int p0  = (bid - b * nt) * POS;

    // ---- precompute paired bilinear entries ----
    const float* omb  = om + (size_t)b * 27 * HW;
    const float* ombB = OMS ? (omB + (size_t)b * 27 * HW) : nullptr;
    for (int i = tid; i < 9 * POS; i += NT) {
        const int k9 = i / POS, pp = i - k9 * POS;
        const int p  = p0 + pp;
        const int yy = p / WW;
        const int xx = p - yy * WW;
        float oy = omb[(size_t)k9 * HW + p];
        float ox = omb[(size_t)(9 + k9) * HW + p];
        float mv = omb[(size_t)(18 + k9) * HW + p];
        if constexpr (OMS) {
            oy += ombB[(size_t)k9 * HW + p];
            ox += ombB[(size_t)(9 + k9) * HW + p];
            mv += ombB[(size_t)(18 + k9) * HW + p];
        }
        const float m  = 1.0f / (1.0f + expf(-mv));
        const int ky = (k9 * 11) >> 5;        // /3 for 0..8
        const int kx = k9 - ky * 3;
        const float py = (float)(yy + ky - 1) + oy;
        const float px = (float)(xx + kx - 1) + ox;
        const float y0f = floorf(py), x0f = floorf(px);
        const int   y0  = (int)y0f,  x0 = (int)x0f;
        const int by0 = min(max(y0, 0), HH - 1);
        const int by1 = min(max(y0 + 1, 0), HH - 1);
        const int bx  = min(max(x0, 0), WW - 2);
        const float wy1 = py - y0f, wx1 = px - x0f;
        const float fy0 = (y0 >= 0  && y0 < HH)     ? (1.f - wy1) * m : 0.f;
        const float fy1 = (y0 >= -1 && y0 < HH - 1) ? wy1 * m         : 0.f;
        const float fx0v = 1.f - wx1, fx1v = wx1;
        // remap x-weights onto slots [bx], [bx+1] (validity + clamp folded)
        float gx0 = 0.f, gx1 = 0.f;
        if (x0 >= 0 && x0 < WW)         { if (x0 == bx)     gx0 += fx0v; else gx1 += fx0v; }
        if (x0 + 1 >= 0 && x0 + 1 < WW) { if (x0 + 1 == bx) gx0 += fx1v; else gx1 += fx1v; }
        eoff2[i] = (uint)(by0 * WW + bx) | ((uint)(by1 * WW + bx) << 16);
        float4 wv; wv.x = fy0 * gx0; wv.y = fy0 * gx1;
                   wv.z = fy1 * gx0; wv.w = fy1 * gx1;
        ewt[i] = wv;
    }
    for (int i = tid; i < 128; i += NT) {
        const float iv = gam[i] * rsqrtf(var[i] + EPSV);
        invp[i] = iv;
        shp[i]  = bet[i] - mu[i] * iv + bias[i] * iv;
    }
    __syncthreads();

    const float* xb   = xin + (size_t)b * CIN * HW;
    const int lane = tid & 63;
    const int w    = tid >> 6;
    const int wq   = w & (NPQ - 1);
    const int kgid = w / NPQ;
    const int tt   = tid & (NPQ * 64 - 1);

    ushort* S00 = Sbase + kgid * (4 * SBUF);

    f32x4 acc[8];
#pragma unroll
    for (int mt = 0; mt < 8; ++mt) acc[mt] = (f32x4){0.f, 0.f, 0.f, 0.f};

    const int mrow = lane & 15;
    const int kq   = lane >> 4;

    sample_chunk<CIN, HH, WW, POS, KS>(xb, eoff2, ewt, S00, S00 + SBUF,
                                       tt, kgid * NCH * KC);
    __syncthreads();

    for (int ch = 0; ch < NCH; ++ch) {
        const int cur = ch & 1;
        ushort* Sc = S00 + (cur * 2) * SBUF;
        if constexpr (ASTAGE) {
            // ---- stage A(ch): self-contained (loads consumed by ds_writes) --
            const size_t wb = (size_t)ch * 4096;
#pragma unroll
            for (int t = 0; t < 1024 / NT; ++t) {
                const int u = tid + t * NT;
                const ushort* srcp = (u < 512)
                    ? (whi + wb + (size_t)u * 8)
                    : (wlo + wb + (size_t)(u - 512) * 8);
                *(short8*)&Abuf[(size_t)u * 8] = *(const short8*)srcp;
            }
            // ---- issue gathers for ch+1 (stay in flight across barrier) ----
            float2 v0[8], v1[8];
            if (ch + 1 < NCH)
                sample_issue<CIN, HH, WW, POS>(xb, eoff2, v0, v1, tt,
                                               (ch + 1) * KC);
            // raw barrier: LDS writes visible, gathers NOT drained
            asm volatile("s_waitcnt lgkmcnt(0)" ::: "memory");
            __builtin_amdgcn_s_barrier();
            __builtin_amdgcn_sched_barrier(0);
            // ---- MFMA section (all operands from LDS; no VMEM) ----
            const int boff = (wq * 16 + mrow) * KS + kq * 8;
            const short8 bh = *(const short8*)&Sc[boff];
            const short8 bl = *(const short8*)&Sc[SBUF + boff];
#pragma unroll
            for (int mt = 0; mt < 8; ++mt) {
                const int au = (mt * 64 + lane) * 8;
                const short8 ah = *(const short8*)&Abuf[au];
                const short8 al = *(const short8*)&Abuf[4096 + au];
                acc[mt] = __builtin_amdgcn_mfma_f32_16x16x32_bf16(al, bh, acc[mt], 0, 0, 0);
                acc[mt] = __builtin_amdgcn_mfma_f32_16x16x32_bf16(ah, bl, acc[mt], 0, 0, 0);
                acc[mt] = __builtin_amdgcn_mfma_f32_16x16x32_bf16(ah, bh, acc[mt], 0, 0, 0);
            }
            // ---- finish: consume gathers (counted vmcnt), write S^1 ----
            if (ch + 1 < NCH) {
                ushort* Sn = S00 + ((cur ^ 1) * 2) * SBUF;
                sample_finish<CIN, HH, WW, POS, KS>(ewt, v0, v1,
                                                    Sn, Sn + SBUF, tt,
                                                    (ch + 1) * KC);
            }
            // raw barrier: protect Abuf (next stage) + S writes
            asm volatile("s_waitcnt lgkmcnt(0)" ::: "memory");
            __builtin_amdgcn_s_barrier();
            __builtin_amdgcn_sched_barrier(0);
        } else {
            const int boff = (wq * 16 + mrow) * KS + kq * 8;
            const short8 bh = *(const short8*)&Sc[boff];
            const short8 bl = *(const short8*)&Sc[SBUF + boff];
            if (ch + 1 < NCH) {
                ushort* Sn = S00 + ((cur ^ 1) * 2) * SBUF;
                sample_chunk<CIN, HH, WW, POS, KS>(xb, eoff2, ewt,
                                                   Sn, Sn + SBUF, tt,
                                                   (kgid * NCH + ch + 1) * KC);
            }
            const size_t abase = (size_t)mrow * K
                               + (size_t)(kgid * NCH + ch) * KC + (size_t)(kq * 8);
#pragma unroll
            for (int mt = 0; mt < 8; ++mt) {
                const size_t ao = abase + (size_t)(mt * 16) * K;
                const short8 ah = *(const short8*)(whi + ao);
                const short8 al = *(const short8*)(wlo + ao);
                acc[mt] = __builtin_amdgcn_mfma_f32_16x16x32_bf16(al, bh, acc[mt], 0, 0, 0);
                acc[mt] = __builtin_amdgcn_mfma_f32_16x16x32_bf16(ah, bl, acc[mt], 0, 0, 0);
                acc[mt] = __builtin_amdgcn_mfma_f32_16x16x32_bf16(ah, bh, acc[mt], 0, 0, 0);
            }
            __syncthreads();
        }
    }

    const int pcolb = wq * 16 + mrow;
    constexpr int RS = POS + 1;
    constexpr int SL = 128 * RS;
    float* red = (float*)Sbase;

    if constexpr (KWAVES == 4) {
        if (kgid >= 2) {
#pragma unroll
            for (int mt = 0; mt < 8; ++mt)
#pragma unroll
                for (int r = 0; r < 4; ++r) {
                    const int co = mt * 16 + kq * 4 + r;
                    red[(kgid - 2) * SL + co * RS + pcolb] = acc[mt][r];
                }
        }
        __syncthreads();
        if (kgid < 2) {
#pragma unroll
            for (int mt = 0; mt < 8; ++mt)
#pragma unroll
                for (int r = 0; r < 4; ++r) {
                    const int co = mt * 16 + kq * 4 + r;
                    acc[mt][r] += red[kgid * SL + co * RS + pcolb];
                }
        }
        __syncthreads();
        if (kgid == 1) {
#pragma unroll
            for (int mt = 0; mt < 8; ++mt)
#pragma unroll
                for (int r = 0; r < 4; ++r) {
                    const int co = mt * 16 + kq * 4 + r;
                    red[co * RS + pcolb] = acc[mt][r];
                }
        }
        __syncthreads();
        if (kgid == 0) {
#pragma unroll
            for (int mt = 0; mt < 8; ++mt)
#pragma unroll
                for (int r = 0; r < 4; ++r) {
                    const int co = mt * 16 + kq * 4 + r;
                    acc[mt][r] += red[co * RS + pcolb];
                }
        }
    } else if constexpr (KWAVES == 2) {
        if (kgid == 1) {
#pragma unroll
            for (int mt = 0; mt < 8; ++mt)
#pragma unroll
                for (int r = 0; r < 4; ++r) {
                    const int co = mt * 16 + kq * 4 + r;
                    red[co * RS + pcolb] = acc[mt][r];
                }
        }
        __syncthreads();
        if (kgid == 0) {
#pragma unroll
            for (int mt = 0; mt < 8; ++mt)
#pragma unroll
                for (int r = 0; r < 4; ++r) {
                    const int co = mt * 16 + kq * 4 + r;
                    acc[mt][r] += red[co * RS + pcolb];
                }
        }
    }

    if (kgid == 0) {
        float* outb = out + (size_t)b * 128 * HW + p0 + pcolb;
#pragma unroll
        for (int mt = 0; mt < 8; ++mt)
#pragma unroll
            for (int r = 0; r < 4; ++r) {
                const int co = mt * 16 + kq * 4 + r;
                outb[(size_t)co * HW] = fmaxf(acc[mt][r] * invp[co] + shp[co], 0.f);
            }
    }
}

// ---------------- depthwise transposed-conv upsample x2 (k=4, pad 2) --------
__global__ __launch_bounds__(256) void upsample_kernel(
    const float* __restrict__ y,    // (4,128,64,64)
    const float* __restrict__ wup,  // (128,1,4,4)
    float* __restrict__ out)        // (4,128,128,128)
{
    const int idx = blockIdx.x * 256 + threadIdx.x;
    const int ox = idx & 127;
    const int oy = (idx >> 7) & 127;
    const int c  = (idx >> 14) & 127;
    const int b  = idx >> 21;

    const float* yc = y + (size_t)(b * 128 + c) * 4096;
    const float* wc = wup + c * 16;

    float acc = 0.f;
#pragma unroll
    for (int ky = 0; ky < 4; ++ky) {
        const int qy = oy + ky - 2;
        if (qy & 1) continue;
        const int iy = qy >> 1;
        if (iy < 0 || iy >= 64) continue;
#pragma unroll
        for (int kx = 0; kx < 4; ++kx) {
            const int qx = ox + kx - 2;
            if (qx & 1) continue;
            const int ix = qx >> 1;
            if (ix < 0 || ix >= 64) continue;
            acc += yc[iy * 64 + ix] * wc[(3 - ky) * 4 + (3 - kx)];
        }
    }
    out[idx] = acc;
}

// ---------------------------------------------------------------------------
extern "C" void kernel_launch(void* const* d_in, const int* in_sizes, int n_in,
                              void* d_out, int out_size, void* d_ws, size_t ws_size,
                              hipStream_t stream) {
    const float* x      = (const float*)d_in[0];
    const float* w_off1 = (const float*)d_in[1];
    const float* b_off1 = (const float*)d_in[2];
    const float* w1     = (const float*)d_in[3];
    const float* b1     = (const float*)d_in[4];
    const float* g1v    = (const float*)d_in[5];
    const float* be1    = (const float*)d_in[6];
    const float* m1     = (const float*)d_in[7];
    const float* v1     = (const float*)d_in[8];
    const float* w_up   = (const float*)d_in[9];
    const float* w_off2 = (const float*)d_in[10];
    const float* b_off2 = (const float*)d_in[11];
    const float* w2     = (const float*)d_in[12];
    const float* b2     = (const float*)d_in[13];
    const float* g2v    = (const float*)d_in[14];
    const float* be2    = (const float*)d_in[15];
    const float* m2     = (const float*)d_in[16];
    const float* v2     = (const float*)d_in[17];

    float* ws  = (float*)d_ws;
    float* om1 = ws;                     // 4*27*4096   =   442368 f
    float* y1  = om1 + 442368;           // 4*128*4096  =  2097152 f
    float* up  = y1 + 2097152;           // 4*128*16384 =  8388608 f
    float* om2 = up + 8388608;           // 4*27*16384  =  1769472 f
    float* outf = (float*)d_out;

    // w1 split parked in `up` (dead until upsample overwrites it)
    ushort* w1hi = (ushort*)up;          // 294912 ushort
    ushort* w1lo = w1hi + 294912;
    // w2 split parked in `y1` (dead after upsample reads it)
    ushort* w2hi = (ushort*)y1;          // 147456 ushort
    ushort* w2lo = w2hi + 147456;
    // conv1 z=1 partial parked in om2 (dead until conv2 writes it)
    float* om1B = om2;                   // 442368 f <= 1769472 f

    // prep: split w1 -> bf16 hi/lo (natural channel-major K layout)
    wsplit_kernel<<<(294912 + 255) / 256, 256, 0, stream>>>(w1, w1hi, w1lo, 294912);

    {   // om1/om1B = conv3x3(x, w_off1) + b_off1 — 2-way channel z-split
        dim3 grid(64, 4, 2);
        conv_off_kernel<256, 2, 64, 64, 64, 8, 4><<<grid, 512, 0, stream>>>(
            x, w_off1, b_off1, om1, om1B);
    }
    // y1 = bn_relu(dcn1) — MFMA, POS=32, 4-way K-split; om = om1 + om1B
    // LDS: 1152 + 4608 + 1024 + 40960 = 47744
    dcn_mfma_kernel<256, 64, 64, 32, 4, 4, false, true>
        <<<4 * (4096 / 32), 512, 47744, stream>>>(
        x, om1, om1B, w1hi, w1lo, b1, g1v, be1, m1, v1, y1);
    // up = depthwise transposed upsample (clobbers w1 split — now dead)
    upsample_kernel<<<8388608 / 256, 256, 0, stream>>>(y1, w_up, up);
    // prep: split w2 -> bf16 hi/lo in fragment order (y1 now dead)
    wsplit_perm_kernel<<<(147456 + 255) / 256, 256, 0, stream>>>(
        w2, w2hi, w2lo, 128, 147456);
    {   // om2 = conv3x3(up, w_off2) + b_off2 — column-tiled
        dim3 grid(256, 4, 1);
        conv_off_kernel<128, 1, 128, 128, 64, 4, 8><<<grid, 256, 0, stream>>>(
            up, w_off2, b_off2, om2, om2);
    }
    // out = bn_relu(dcn2) — MFMA, POS=64, A-staged, T14 split sampler
    // LDS: 2304 + 9216 + 1024 + 16384 + 20480 = 49408
    dcn_mfma_kernel<128, 128, 128, 64, 1, 3, true, false>
        <<<4 * (16384 / 64), 256, 49408, stream>>>(
        up, om2, om2, w2hi, w2lo, b2, g2v, be2, m2, v2, outf);
}

// Round 10
// 593.365 us; speedup vs baseline: 2.2646x; 1.1444x over previous
//
#include <hip/hip_runtime.h>
#include <hip/hip_bf16.h>
#include <cmath>

// ---------------------------------------------------------------------------
// Pipeline: y1 = bn_relu(dcn(x, w_off1, b_off1, w1, b1))        (4,128,64,64)
//           up = up_depthwise(y1, w_up, f=2)                    (4,128,128,128)
//           out = bn_relu(dcn(up, w_off2, b_off2, w2, b2))      (4,128,128,128)
// DCN GEMM on mfma_f32_16x16x32_bf16, split-bf16 (hi/lo, 3 products).
// BOTH dcn weight matrices pre-permuted into per-chunk fragment order ->
// every A-fragment load is a coalesced 16B/lane (1KB/instr) L2 read.
// Bilinear gathers PAIRED (one float2 per row, edges folded into weights).
// dcn2 (ASTAGE): A staged in LDS; T14 split sampler (gathers in flight
// across a raw lgkmcnt-only s_barrier, consumed after the MFMA section).
// conv_off: column-tiled halo slabs, channel z-split. XCD-swizzled dcn grids.
// Workspace: om1 | y1 | up | om2 ; w1-split parked in `up`, w2-split in `y1`,
// om1B (conv1 z=1 partial) parked in om2.
// ---------------------------------------------------------------------------

#define EPSV 1e-5f

typedef __attribute__((ext_vector_type(8))) short short8;
typedef __attribute__((ext_vector_type(4))) float f32x4;

__device__ __forceinline__ ushort f2bf(float f) {
    union { float f; uint u; } v; v.f = f;
    const uint r = v.u + 0x7fffu + ((v.u >> 16) & 1u);   // RNE
    return (ushort)(r >> 16);
}
__device__ __forceinline__ float bf2f(ushort h) {
    union { uint u; float f; } v; v.u = ((uint)h) << 16;
    return v.f;
}
__device__ __forceinline__ float2 ld2u(const float* p) {
    float2 v; __builtin_memcpy(&v, p, sizeof(float2)); return v;
}

// ------- weight split: fp32 -> bf16 hi/lo in per-chunk FRAGMENT order -------
// dst[((ch*8 + mt)*64 + lane)*8 + j] = w[co][k], k = c*9+k9 (channel-major),
// ch = k>>5, kq = (k&31)>>3, j = k&7, mt = co>>4, lane = (co&15) | (kq<<4).
__global__ __launch_bounds__(256) void wsplit_perm_kernel(
    const float* __restrict__ w, ushort* __restrict__ hi,
    ushort* __restrict__ lo, int cin, int n)
{
    const int i = blockIdx.x * 256 + threadIdx.x;
    if (i >= n) return;
    const int cin9 = cin * 9;
    const int co = i / cin9;
    const int k  = i - co * cin9;            // channel-major K index
    const int ch = k >> 5;
    const int kq = (k & 31) >> 3;
    const int j  = k & 7;
    const int mt = co >> 4;
    const int lane = (co & 15) | (kq << 4);
    const size_t dst = ((size_t)(ch * 8 + mt) * 64 + lane) * 8 + j;
    const float f = w[i];
    const ushort h = f2bf(f);
    hi[dst] = h;
    lo[dst] = f2bf(f - bf2f(h));
}

// ---------------- offset conv: 3x3, pad 1, 27 output channels ---------------
template <int CIN, int ZS, int HH, int WW, int CT, int SPLIT, int CC>
__global__ __launch_bounds__(CT * SPLIT) void conv_off_kernel(
    const float* __restrict__ in,    // (B, CIN, HH, WW)
    const float* __restrict__ wt,    // (27, CIN, 3, 3)
    const float* __restrict__ bias,  // (27)
    float* __restrict__ om,          // (B, 27, HH, WW)  z==0
    float* __restrict__ omB)         // (B, 27, HH, WW)  z==1 partial
{
    constexpr int NT   = CT * SPLIT;
    constexpr int CPB  = CIN / ZS;
    constexpr int CPG  = CPB / SPLIT;
    constexpr int NCH  = CPG / CC;
    constexpr int CTP  = CT + 2;
    constexpr int SLABN = SPLIT * CC * 3 * CTP;
    constexpr int REDN  = 27 * SPLIT * CT;
    constexpr int SMEMN = (SLABN > REDN) ? SLABN : REDN;
    constexpr int NCT  = WW / CT;

    __shared__ __align__(16) float smem[SMEMN];
    float* slab = smem;
    float* red  = smem;

    const int tid = threadIdx.x;
    const int pos = tid & (CT - 1);
    const int g   = tid / CT;                // wave-uniform (CT=64)
    const int row = blockIdx.x / NCT;
    const int c0  = (blockIdx.x - row * NCT) * CT;
    const int b   = blockIdx.y;
    const int z   = blockIdx.z;

    const float* ib = in + (size_t)b * CIN * HH * WW;
    const int cbs = __builtin_amdgcn_readfirstlane(z * CPB + g * CPG);

    float acc[27];
#pragma unroll
    for (int o = 0; o < 27; ++o) acc[o] = 0.f;

    for (int ch = 0; ch < NCH; ++ch) {
        const int c0ch = ch * CC;
        for (int i = tid; i < SLABN; i += NT) {
            const int gg = i / (CC * 3 * CTP);
            const int r1 = i - gg * (CC * 3 * CTP);
            const int cc = r1 / (3 * CTP);
            const int r2 = r1 - cc * 3 * CTP;
            const int rr = r2 / CTP;
            const int px = r2 - rr * CTP;
            const int c  = z * CPB + gg * CPG + c0ch + cc;
            const int iy = row + rr - 1;
            const int ix = c0 + px - 1;
            float v = 0.f;
            if (iy >= 0 && iy < HH && ix >= 0 && ix < WW)
                v = ib[((size_t)c * HH + iy) * WW + ix];
            slab[i] = v;
        }
        __syncthreads();

        const float* myslab = slab + g * (CC * 3 * CTP);
        for (int cc = 0; cc < CC; ++cc) {
            const float* sl = myslab + cc * 3 * CTP;
            float v[9];
#pragma unroll
            for (int r = 0; r < 3; ++r) {
                v[r * 3 + 0] = sl[r * CTP + pos];
                v[r * 3 + 1] = sl[r * CTP + pos + 1];
                v[r * 3 + 2] = sl[r * CTP + pos + 2];
            }
            const float* wp = wt + (size_t)(cbs + c0ch + cc) * 9;
#pragma unroll
            for (int o = 0; o < 27; ++o) {
                const float* w9 = wp + (size_t)o * CIN * 9;
#pragma unroll
                for (int k = 0; k < 9; ++k)
                    acc[o] = fmaf(w9[k], v[k], acc[o]);
            }
        }
        __syncthreads();
    }

#pragma unroll
    for (int o = 0; o < 27; ++o) red[(o * SPLIT + g) * CT + pos] = acc[o];
    __syncthreads();

    float* outp = (z == 0) ? om : omB;
    float* ob = outp + (size_t)b * 27 * HH * WW + (size_t)row * WW + c0;
    for (int i = tid; i < 27 * CT; i += NT) {
        const int o  = i / CT;
        const int px = i - o * CT;
        float s = (z == 0) ? bias[o] : 0.f;
#pragma unroll
        for (int gg = 0; gg < SPLIT; ++gg)
            s += red[(o * SPLIT + gg) * CT + px];
        ob[(size_t)o * HH * WW + px] = s;
    }
}

// ---------------- paired sampler: issue / finish ----------------------------
template <int CIN, int HH, int WW, int POS>
__device__ __forceinline__ void sample_issue(
    const float* __restrict__ xb, const uint* __restrict__ eoff2,
    float2* v0, float2* v1, int tt, int kbase)
{
    constexpr int HW = HH * WW;
    const int pp = tt & (POS - 1);
    const int j0 = (tt / POS) * 8;
#pragma unroll
    for (int j = 0; j < 8; ++j) {
        const int kg = kbase + j0 + j;
        const int c  = (kg * 7282) >> 16;       // /9 (exact for kg<2304)
        const int k9 = kg - c * 9;
        const uint e = eoff2[k9 * POS + pp];
        const float* chp = xb + (size_t)c * HW;
        v0[j] = ld2u(chp + (e & 0xffffu));
        v1[j] = ld2u(chp + (e >> 16));
    }
}

template <int CIN, int HH, int WW, int POS, int KS>
__device__ __forceinline__ void sample_finish(
    const float4* __restrict__ ewt, const float2* v0, const float2* v1,
    ushort* __restrict__ Shi, ushort* __restrict__ Slo, int tt, int kbase)
{
    const int pp = tt & (POS - 1);
    const int j0 = (tt / POS) * 8;
    float s[8];
#pragma unroll
    for (int j = 0; j < 8; ++j) {
        const int kg = kbase + j0 + j;
        const int c  = (kg * 7282) >> 16;
        const int k9 = kg - c * 9;
        const float4 wv = ewt[k9 * POS + pp];
        s[j] = v0[j].x * wv.x + v0[j].y * wv.y
             + v1[j].x * wv.z + v1[j].y * wv.w;
    }
    uint hw[4], lw[4];
#pragma unroll
    for (int q = 0; q < 4; ++q) {
        const ushort h0 = f2bf(s[2 * q]);
        const ushort h1 = f2bf(s[2 * q + 1]);
        const float  l0 = s[2 * q]     - bf2f(h0);
        const float  l1 = s[2 * q + 1] - bf2f(h1);
        hw[q] = (uint)h0 | ((uint)h1 << 16);
        lw[q] = (uint)f2bf(l0) | ((uint)f2bf(l1) << 16);
    }
    uint4 hv; hv.x = hw[0]; hv.y = hw[1]; hv.z = hw[2]; hv.w = hw[3];
    uint4 lv; lv.x = lw[0]; lv.y = lw[1]; lv.z = lw[2]; lv.w = lw[3];
    *(uint4*)&Shi[pp * KS + j0] = hv;
    *(uint4*)&Slo[pp * KS + j0] = lv;
}

template <int CIN, int HH, int WW, int POS, int KS>
__device__ __forceinline__ void sample_chunk(
    const float* __restrict__ xb, const uint* __restrict__ eoff2,
    const float4* __restrict__ ewt, ushort* __restrict__ Shi,
    ushort* __restrict__ Slo, int tt, int kbase)
{
    float2 v0[8], v1[8];
    sample_issue<CIN, HH, WW, POS>(xb, eoff2, v0, v1, tt, kbase);
    sample_finish<CIN, HH, WW, POS, KS>(ewt, v0, v1, Shi, Slo, tt, kbase);
}

// ---------------- fused DCN on MFMA: sample + GEMM + bias + BN + ReLU -------
// Both paths use fragment-ordered weights (coalesced A loads).
template <int CIN, int HH, int WW, int POS, int KWAVES, int MINW,
          bool ASTAGE, bool OMS>
__global__ __launch_bounds__((POS / 16) * KWAVES * 64, MINW) void dcn_mfma_kernel(
    const float* __restrict__ xin,   // (B, CIN, HH, WW)
    const float* __restrict__ om,    // (B, 27, HH, WW)
    const float* __restrict__ omB,   // partial (OMS only)
    const ushort* __restrict__ whi,  // (128, K) bf16 hi, fragment order
    const ushort* __restrict__ wlo,  // (128, K) bf16 lo, fragment order
    const float* __restrict__ bias,
    const float* __restrict__ gam, const float* __restrict__ bet,
    const float* __restrict__ mu,  const float* __restrict__ var,
    float* __restrict__ out)         // (B, 128, HH*WW)
{
    constexpr int HW   = HH * WW;
    constexpr int K    = CIN * 9;
    constexpr int NPQ  = POS / 16;
    constexpr int NT   = NPQ * KWAVES * 64;
    constexpr int KC   = 32;
    constexpr int KS   = 40;                  // S row stride (ushort), pad 8
    constexpr int NCHT = K / KC;
    constexpr int NCH  = NCHT / KWAVES;
    constexpr int SBUF = POS * KS;            // ushorts per (buf, hi|lo)
    constexpr int ABN  = ASTAGE ? 8192 : 0;   // A-stage ushorts (16KB)

    extern __shared__ __align__(16) char smem[];
    uint*    eoff2 = (uint*)smem;                 // 9*POS * 4B
    float4*  ewt   = (float4*)(eoff2 + 9 * POS);  // 9*POS * 16B
    float*   invp  = (float*)(ewt + 9 * POS);     // 128
    float*   shp   = invp + 128;                  // 128
    ushort*  Abuf  = (ushort*)(shp + 128);        // ABN ushorts
    ushort*  Sbase = Abuf + ABN;

    const int tid = threadIdx.x;
    const int nt  = HW / POS;
    // bijective XCD swizzle (gridDim.x % 8 == 0)
    const int cpx = gridDim.x >> 3;
    const int bid = (blockIdx.x & 7) * cpx + (blockIdx.x >> 3);
    const int b   = bid / nt;
    const int p0  = (bid - b * nt) * POS;

    // ---- precompute paired bilinear entries ----
    const float* omb  = om + (size_t)b * 27 * HW;
    const float* ombB = OMS ? (omB + (size_t)b * 27 * HW) : nullptr;
    for (int i = tid; i < 9 * POS; i += NT) {
        const int k9 = i / POS, pp = i - k9 * POS;
        const int p  = p0 + pp;
        const int yy = p / WW;
        const int xx = p - yy * WW;
        float oy = omb[(size_t)k9 * HW + p];
        float ox = omb[(size_t)(9 + k9) * HW + p];
        float mv = omb[(size_t)(18 + k9) * HW + p];
        if constexpr (OMS) {
            oy += ombB[(size_t)k9 * HW + p];
            ox += ombB[(size_t)(9 + k9) * HW + p];
            mv += ombB[(size_t)(18 + k9) * HW + p];
        }
        const float m  = 1.0f / (1.0f + expf(-mv));
        const int ky = (k9 * 11) >> 5;        // /3 for 0..8
        const int kx = k9 - ky * 3;
        const float py = (float)(yy + ky - 1) + oy;
        const float px = (float)(xx + kx - 1) + ox;
        const float y0f = floorf(py), x0f = floorf(px);
        const int   y0  = (int)y0f,  x0 = (int)x0f;
        const int by0 = min(max(y0, 0), HH - 1);
        const int by1 = min(max(y0 + 1, 0), HH - 1);
        const int bx  = min(max(x0, 0), WW - 2);
        const float wy1 = py - y0f, wx1 = px - x0f;
        const float fy0 = (y0 >= 0  && y0 < HH)     ? (1.f - wy1) * m : 0.f;
        const float fy1 = (y0 >= -1 && y0 < HH - 1) ? wy1 * m         : 0.f;
        const float fx0v = 1.f - wx1, fx1v = wx1;
        float gx0 = 0.f, gx1 = 0.f;
        if (x0 >= 0 && x0 < WW)         { if (x0 == bx)     gx0 += fx0v; else gx1 += fx0v; }
        if (x0 + 1 >= 0 && x0 + 1 < WW) { if (x0 + 1 == bx) gx0 += fx1v; else gx1 += fx1v; }
        eoff2[i] = (uint)(by0 * WW + bx) | ((uint)(by1 * WW + bx) << 16);
        float4 wv; wv.x = fy0 * gx0; wv.y = fy0 * gx1;
                   wv.z = fy1 * gx0; wv.w = fy1 * gx1;
        ewt[i] = wv;
    }
    for (int i = tid; i < 128; i += NT) {
        const float iv = gam[i] * rsqrtf(var[i] + EPSV);
        invp[i] = iv;
        shp[i]  = bet[i] - mu[i] * iv + bias[i] * iv;
    }
    __syncthreads();

    const float* xb   = xin + (size_t)b * CIN * HW;
    const int lane = tid & 63;
    const int w    = tid >> 6;
    const int wq   = w & (NPQ - 1);
    const int kgid = w / NPQ;
    const int tt   = tid & (NPQ * 64 - 1);

    ushort* S00 = Sbase + kgid * (4 * SBUF);

    f32x4 acc[8];
#pragma unroll
    for (int mt = 0; mt < 8; ++mt) acc[mt] = (f32x4){0.f, 0.f, 0.f, 0.f};

    const int mrow = lane & 15;
    const int kq   = lane >> 4;

    sample_chunk<CIN, HH, WW, POS, KS>(xb, eoff2, ewt, S00, S00 + SBUF,
                                       tt, kgid * NCH * KC);
    __syncthreads();

    for (int ch = 0; ch < NCH; ++ch) {
        const int cur = ch & 1;
        ushort* Sc = S00 + (cur * 2) * SBUF;
        if constexpr (ASTAGE) {
            // ---- stage A(ch): self-contained (loads consumed by ds_writes) --
            const size_t wb = (size_t)ch * 4096;
#pragma unroll
            for (int t = 0; t < 1024 / NT; ++t) {
                const int u = tid + t * NT;
                const ushort* srcp = (u < 512)
                    ? (whi + wb + (size_t)u * 8)
                    : (wlo + wb + (size_t)(u - 512) * 8);
                *(short8*)&Abuf[(size_t)u * 8] = *(const short8*)srcp;
            }
            // ---- issue gathers for ch+1 (stay in flight across barrier) ----
            float2 v0[8], v1[8];
            if (ch + 1 < NCH)
                sample_issue<CIN, HH, WW, POS>(xb, eoff2, v0, v1, tt,
                                               (ch + 1) * KC);
            // raw barrier: LDS writes visible, gathers NOT drained
            asm volatile("s_waitcnt lgkmcnt(0)" ::: "memory");
            __builtin_amdgcn_s_barrier();
            __builtin_amdgcn_sched_barrier(0);
            // ---- MFMA section (all operands from LDS; no VMEM) ----
            const int boff = (wq * 16 + mrow) * KS + kq * 8;
            const short8 bh = *(const short8*)&Sc[boff];
            const short8 bl = *(const short8*)&Sc[SBUF + boff];
#pragma unroll
            for (int mt = 0; mt < 8; ++mt) {
                const int au = (mt * 64 + lane) * 8;
                const short8 ah = *(const short8*)&Abuf[au];
                const short8 al = *(const short8*)&Abuf[4096 + au];
                acc[mt] = __builtin_amdgcn_mfma_f32_16x16x32_bf16(al, bh, acc[mt], 0, 0, 0);
                acc[mt] = __builtin_amdgcn_mfma_f32_16x16x32_bf16(ah, bl, acc[mt], 0, 0, 0);
                acc[mt] = __builtin_amdgcn_mfma_f32_16x16x32_bf16(ah, bh, acc[mt], 0, 0, 0);
            }
            // ---- finish: consume gathers (counted vmcnt), write S^1 ----
            if (ch + 1 < NCH) {
                ushort* Sn = S00 + ((cur ^ 1) * 2) * SBUF;
                sample_finish<CIN, HH, WW, POS, KS>(ewt, v0, v1,
                                                    Sn, Sn + SBUF, tt,
                                                    (ch + 1) * KC);
            }
            // raw barrier: protect Abuf (next stage) + S writes
            asm volatile("s_waitcnt lgkmcnt(0)" ::: "memory");
            __builtin_amdgcn_s_barrier();
            __builtin_amdgcn_sched_barrier(0);
        } else {
            const int boff = (wq * 16 + mrow) * KS + kq * 8;
            const short8 bh = *(const short8*)&Sc[boff];
            const short8 bl = *(const short8*)&Sc[SBUF + boff];
            if (ch + 1 < NCH) {
                ushort* Sn = S00 + ((cur ^ 1) * 2) * SBUF;
                sample_chunk<CIN, HH, WW, POS, KS>(xb, eoff2, ewt,
                                                   Sn, Sn + SBUF, tt,
                                                   (kgid * NCH + ch + 1) * KC);
            }
            // A fragments: fragment-ordered -> coalesced 16B/lane L2 reads
            const size_t abase = (size_t)((kgid * NCH + ch) * 8) * 512;
#pragma unroll
            for (int mt = 0; mt < 8; ++mt) {
                const size_t ao = abase + (size_t)((mt * 64 + lane) * 8);
                const short8 ah = *(const short8*)(whi + ao);
                const short8 al = *(const short8*)(wlo + ao);
                acc[mt] = __builtin_amdgcn_mfma_f32_16x16x32_bf16(al, bh, acc[mt], 0, 0, 0);
                acc[mt] = __builtin_amdgcn_mfma_f32_16x16x32_bf16(ah, bl, acc[mt], 0, 0, 0);
                acc[mt] = __builtin_amdgcn_mfma_f32_16x16x32_bf16(ah, bh, acc[mt], 0, 0, 0);
            }
            __syncthreads();
        }
    }

    const int pcolb = wq * 16 + mrow;
    constexpr int RS = POS + 1;
    constexpr int SL = 128 * RS;
    float* red = (float*)Sbase;

    if constexpr (KWAVES == 4) {
        if (kgid >= 2) {
#pragma unroll
            for (int mt = 0; mt < 8; ++mt)
#pragma unroll
                for (int r = 0; r < 4; ++r) {
                    const int co = mt * 16 + kq * 4 + r;
                    red[(kgid - 2) * SL + co * RS + pcolb] = acc[mt][r];
                }
        }
        __syncthreads();
        if (kgid < 2) {
#pragma unroll
            for (int mt = 0; mt < 8; ++mt)
#pragma unroll
                for (int r = 0; r < 4; ++r) {
                    const int co = mt * 16 + kq * 4 + r;
                    acc[mt][r] += red[kgid * SL + co * RS + pcolb];
                }
        }
        __syncthreads();
        if (kgid == 1) {
#pragma unroll
            for (int mt = 0; mt < 8; ++mt)
#pragma unroll
                for (int r = 0; r < 4; ++r) {
                    const int co = mt * 16 + kq * 4 + r;
                    red[co * RS + pcolb] = acc[mt][r];
                }
        }
        __syncthreads();
        if (kgid == 0) {
#pragma unroll
            for (int mt = 0; mt < 8; ++mt)
#pragma unroll
                for (int r = 0; r < 4; ++r) {
                    const int co = mt * 16 + kq * 4 + r;
                    acc[mt][r] += red[co * RS + pcolb];
                }
        }
    } else if constexpr (KWAVES == 2) {
        if (kgid == 1) {
#pragma unroll
            for (int mt = 0; mt < 8; ++mt)
#pragma unroll
                for (int r = 0; r < 4; ++r) {
                    const int co = mt * 16 + kq * 4 + r;
                    red[co * RS + pcolb] = acc[mt][r];
                }
        }
        __syncthreads();
        if (kgid == 0) {
#pragma unroll
            for (int mt = 0; mt < 8; ++mt)
#pragma unroll
                for (int r = 0; r < 4; ++r) {
                    const int co = mt * 16 + kq * 4 + r;
                    acc[mt][r] += red[co * RS + pcolb];
                }
        }
    }

    if (kgid == 0) {
        float* outb = out + (size_t)b * 128 * HW + p0 + pcolb;
#pragma unroll
        for (int mt = 0; mt < 8; ++mt)
#pragma unroll
            for (int r = 0; r < 4; ++r) {
                const int co = mt * 16 + kq * 4 + r;
                outb[(size_t)co * HW] = fmaxf(acc[mt][r] * invp[co] + shp[co], 0.f);
            }
    }
}

// ---------------- depthwise transposed-conv upsample x2 (k=4, pad 2) --------
__global__ __launch_bounds__(256) void upsample_kernel(
    const float* __restrict__ y,    // (4,128,64,64)
    const float* __restrict__ wup,  // (128,1,4,4)
    float* __restrict__ out)        // (4,128,128,128)
{
    const int idx = blockIdx.x * 256 + threadIdx.x;
    const int ox = idx & 127;
    const int oy = (idx >> 7) & 127;
    const int c  = (idx >> 14) & 127;
    const int b  = idx >> 21;

    const float* yc = y + (size_t)(b * 128 + c) * 4096;
    const float* wc = wup + c * 16;

    float acc = 0.f;
#pragma unroll
    for (int ky = 0; ky < 4; ++ky) {
        const int qy = oy + ky - 2;
        if (qy & 1) continue;
        const int iy = qy >> 1;
        if (iy < 0 || iy >= 64) continue;
#pragma unroll
        for (int kx = 0; kx < 4; ++kx) {
            const int qx = ox + kx - 2;
            if (qx & 1) continue;
            const int ix = qx >> 1;
            if (ix < 0 || ix >= 64) continue;
            acc += yc[iy * 64 + ix] * wc[(3 - ky) * 4 + (3 - kx)];
        }
    }
    out[idx] = acc;
}

// ---------------------------------------------------------------------------
extern "C" void kernel_launch(void* const* d_in, const int* in_sizes, int n_in,
                              void* d_out, int out_size, void* d_ws, size_t ws_size,
                              hipStream_t stream) {
    const float* x      = (const float*)d_in[0];
    const float* w_off1 = (const float*)d_in[1];
    const float* b_off1 = (const float*)d_in[2];
    const float* w1     = (const float*)d_in[3];
    const float* b1     = (const float*)d_in[4];
    const float* g1v    = (const float*)d_in[5];
    const float* be1    = (const float*)d_in[6];
    const float* m1     = (const float*)d_in[7];
    const float* v1     = (const float*)d_in[8];
    const float* w_up   = (const float*)d_in[9];
    const float* w_off2 = (const float*)d_in[10];
    const float* b_off2 = (const float*)d_in[11];
    const float* w2     = (const float*)d_in[12];
    const float* b2     = (const float*)d_in[13];
    const float* g2v    = (const float*)d_in[14];
    const float* be2    = (const float*)d_in[15];
    const float* m2     = (const float*)d_in[16];
    const float* v2     = (const float*)d_in[17];

    float* ws  = (float*)d_ws;
    float* om1 = ws;                     // 4*27*4096   =   442368 f
    float* y1  = om1 + 442368;           // 4*128*4096  =  2097152 f
    float* up  = y1 + 2097152;           // 4*128*16384 =  8388608 f
    float* om2 = up + 8388608;           // 4*27*16384  =  1769472 f
    float* outf = (float*)d_out;

    // w1 split parked in `up` (dead until upsample overwrites it)
    ushort* w1hi = (ushort*)up;          // 294912 ushort
    ushort* w1lo = w1hi + 294912;
    // w2 split parked in `y1` (dead after upsample reads it)
    ushort* w2hi = (ushort*)y1;          // 147456 ushort
    ushort* w2lo = w2hi + 147456;
    // conv1 z=1 partial parked in om2 (dead until conv2 writes it)
    float* om1B = om2;                   // 442368 f <= 1769472 f

    // prep: split w1 -> bf16 hi/lo in fragment order (coalesced A loads)
    wsplit_perm_kernel<<<(294912 + 255) / 256, 256, 0, stream>>>(
        w1, w1hi, w1lo, 256, 294912);

    {   // om1/om1B = conv3x3(x, w_off1) + b_off1 — 2-way channel z-split
        dim3 grid(64, 4, 2);
        conv_off_kernel<256, 2, 64, 64, 64, 8, 4><<<grid, 512, 0, stream>>>(
            x, w_off1, b_off1, om1, om1B);
    }
    // y1 = bn_relu(dcn1) — MFMA, POS=32, 4-way K-split; om = om1 + om1B
    // LDS: 1152 + 4608 + 1024 + 40960 = 47744
    dcn_mfma_kernel<256, 64, 64, 32, 4, 4, false, true>
        <<<4 * (4096 / 32), 512, 47744, stream>>>(
        x, om1, om1B, w1hi, w1lo, b1, g1v, be1, m1, v1, y1);
    // up = depthwise transposed upsample (clobbers w1 split — now dead)
    upsample_kernel<<<8388608 / 256, 256, 0, stream>>>(y1, w_up, up);
    // prep: split w2 -> bf16 hi/lo in fragment order (y1 now dead)
    wsplit_perm_kernel<<<(147456 + 255) / 256, 256, 0, stream>>>(
        w2, w2hi, w2lo, 128, 147456);
    {   // om2 = conv3x3(up, w_off2) + b_off2 — column-tiled
        dim3 grid(256, 4, 1);
        conv_off_kernel<128, 1, 128, 128, 64, 4, 8><<<grid, 256, 0, stream>>>(
            up, w_off2, b_off2, om2, om2);
    }
    // out = bn_relu(dcn2) — MFMA, POS=64, A-staged, T14 split sampler
    // LDS: 2304 + 9216 + 1024 + 16384 + 20480 = 49408
    dcn_mfma_kernel<128, 128, 128, 64, 1, 3, true, false>
        <<<4 * (16384 / 64), 256, 49408, stream>>>(
        up, om2, om2, w2hi, w2lo, b2, g2v, be2, m2, v2, outf);
}

// Round 11
// 562.886 us; speedup vs baseline: 2.3872x; 1.0541x over previous
//
#include <hip/hip_runtime.h>
#include <hip/hip_bf16.h>
#include <cmath>

// ---------------------------------------------------------------------------
// Pipeline: y1 = bn_relu(dcn(x, w_off1, b_off1, w1, b1))        (4,128,64,64)
//           up = up_depthwise(y1, w_up, f=2)                    (4,128,128,128)
//           out = bn_relu(dcn(up, w_off2, b_off2, w2, b2))      (4,128,128,128)
// DCN GEMM on mfma_f32_16x16x32_bf16, split-bf16 (hi/lo, 3 products).
// Weights pre-permuted into per-chunk fragment order (coalesced A loads).
// Bilinear gathers PAIRED (one float2 per row, edges folded into weights).
// dcn2 (ASTAGE): SINGLE S buffer, alternating phases per chunk:
//   {MFMA reads S+Abuf} -> barrier -> {stage A(ch+1) | finish->S | issue(ch+2)}
//   -> lgkmcnt-only barrier.  Gathers stay in flight across a full MFMA
//   phase; LDS 39.2KB -> 4 blocks/CU (16 waves).
// conv_off: column-tiled halo slabs, channel z-split. XCD-swizzled dcn grids.
// Workspace: om1 | y1 | up | om2 ; w1-split parked in `up`, w2-split in `y1`,
// om1B (conv1 z=1 partial) parked in om2.
// ---------------------------------------------------------------------------

#define EPSV 1e-5f

typedef __attribute__((ext_vector_type(8))) short short8;
typedef __attribute__((ext_vector_type(4))) float f32x4;

__device__ __forceinline__ ushort f2bf(float f) {
    union { float f; uint u; } v; v.f = f;
    const uint r = v.u + 0x7fffu + ((v.u >> 16) & 1u);   // RNE
    return (ushort)(r >> 16);
}
__device__ __forceinline__ float bf2f(ushort h) {
    union { uint u; float f; } v; v.u = ((uint)h) << 16;
    return v.f;
}
__device__ __forceinline__ float2 ld2u(const float* p) {
    float2 v; __builtin_memcpy(&v, p, sizeof(float2)); return v;
}

// ------- weight split: fp32 -> bf16 hi/lo in per-chunk FRAGMENT order -------
// dst[((ch*8 + mt)*64 + lane)*8 + j] = w[co][k], k = c*9+k9 (channel-major),
// ch = k>>5, kq = (k&31)>>3, j = k&7, mt = co>>4, lane = (co&15) | (kq<<4).
__global__ __launch_bounds__(256) void wsplit_perm_kernel(
    const float* __restrict__ w, ushort* __restrict__ hi,
    ushort* __restrict__ lo, int cin, int n)
{
    const int i = blockIdx.x * 256 + threadIdx.x;
    if (i >= n) return;
    const int cin9 = cin * 9;
    const int co = i / cin9;
    const int k  = i - co * cin9;            // channel-major K index
    const int ch = k >> 5;
    const int kq = (k & 31) >> 3;
    const int j  = k & 7;
    const int mt = co >> 4;
    const int lane = (co & 15) | (kq << 4);
    const size_t dst = ((size_t)(ch * 8 + mt) * 64 + lane) * 8 + j;
    const float f = w[i];
    const ushort h = f2bf(f);
    hi[dst] = h;
    lo[dst] = f2bf(f - bf2f(h));
}

// ---------------- offset conv: 3x3, pad 1, 27 output channels ---------------
template <int CIN, int ZS, int HH, int WW, int CT, int SPLIT, int CC>
__global__ __launch_bounds__(CT * SPLIT) void conv_off_kernel(
    const float* __restrict__ in,    // (B, CIN, HH, WW)
    const float* __restrict__ wt,    // (27, CIN, 3, 3)
    const float* __restrict__ bias,  // (27)
    float* __restrict__ om,          // (B, 27, HH, WW)  z==0
    float* __restrict__ omB)         // (B, 27, HH, WW)  z==1 partial
{
    constexpr int NT   = CT * SPLIT;
    constexpr int CPB  = CIN / ZS;
    constexpr int CPG  = CPB / SPLIT;
    constexpr int NCH  = CPG / CC;
    constexpr int CTP  = CT + 2;
    constexpr int SLABN = SPLIT * CC * 3 * CTP;
    constexpr int REDN  = 27 * SPLIT * CT;
    constexpr int SMEMN = (SLABN > REDN) ? SLABN : REDN;
    constexpr int NCT  = WW / CT;

    __shared__ __align__(16) float smem[SMEMN];
    float* slab = smem;
    float* red  = smem;

    const int tid = threadIdx.x;
    const int pos = tid & (CT - 1);
    const int g   = tid / CT;                // wave-uniform (CT=64)
    const int row = blockIdx.x / NCT;
    const int c0  = (blockIdx.x - row * NCT) * CT;
    const int b   = blockIdx.y;
    const int z   = blockIdx.z;

    const float* ib = in + (size_t)b * CIN * HH * WW;
    const int cbs = __builtin_amdgcn_readfirstlane(z * CPB + g * CPG);

    float acc[27];
#pragma unroll
    for (int o = 0; o < 27; ++o) acc[o] = 0.f;

    for (int ch = 0; ch < NCH; ++ch) {
        const int c0ch = ch * CC;
        for (int i = tid; i < SLABN; i += NT) {
            const int gg = i / (CC * 3 * CTP);
            const int r1 = i - gg * (CC * 3 * CTP);
            const int cc = r1 / (3 * CTP);
            const int r2 = r1 - cc * 3 * CTP;
            const int rr = r2 / CTP;
            const int px = r2 - rr * CTP;
            const int c  = z * CPB + gg * CPG + c0ch + cc;
            const int iy = row + rr - 1;
            const int ix = c0 + px - 1;
            float v = 0.f;
            if (iy >= 0 && iy < HH && ix >= 0 && ix < WW)
                v = ib[((size_t)c * HH + iy) * WW + ix];
            slab[i] = v;
        }
        __syncthreads();

        const float* myslab = slab + g * (CC * 3 * CTP);
        for (int cc = 0; cc < CC; ++cc) {
            const float* sl = myslab + cc * 3 * CTP;
            float v[9];
#pragma unroll
            for (int r = 0; r < 3; ++r) {
                v[r * 3 + 0] = sl[r * CTP + pos];
                v[r * 3 + 1] = sl[r * CTP + pos + 1];
                v[r * 3 + 2] = sl[r * CTP + pos + 2];
            }
            const float* wp = wt + (size_t)(cbs + c0ch + cc) * 9;
#pragma unroll
            for (int o = 0; o < 27; ++o) {
                const float* w9 = wp + (size_t)o * CIN * 9;
#pragma unroll
                for (int k = 0; k < 9; ++k)
                    acc[o] = fmaf(w9[k], v[k], acc[o]);
            }
        }
        __syncthreads();
    }

#pragma unroll
    for (int o = 0; o < 27; ++o) red[(o * SPLIT + g) * CT + pos] = acc[o];
    __syncthreads();

    float* outp = (z == 0) ? om : omB;
    float* ob = outp + (size_t)b * 27 * HH * WW + (size_t)row * WW + c0;
    for (int i = tid; i < 27 * CT; i += NT) {
        const int o  = i / CT;
        const int px = i - o * CT;
        float s = (z == 0) ? bias[o] : 0.f;
#pragma unroll
        for (int gg = 0; gg < SPLIT; ++gg)
            s += red[(o * SPLIT + gg) * CT + px];
        ob[(size_t)o * HH * WW + px] = s;
    }
}

// ---------------- paired sampler: issue / finish ----------------------------
template <int CIN, int HH, int WW, int POS>
__device__ __forceinline__ void sample_issue(
    const float* __restrict__ xb, const uint* __restrict__ eoff2,
    float2* v0, float2* v1, int tt, int kbase)
{
    constexpr int HW = HH * WW;
    const int pp = tt & (POS - 1);
    const int j0 = (tt / POS) * 8;
#pragma unroll
    for (int j = 0; j < 8; ++j) {
        const int kg = kbase + j0 + j;
        const int c  = (kg * 7282) >> 16;       // /9 (exact for kg<2304)
        const int k9 = kg - c * 9;
        const uint e = eoff2[k9 * POS + pp];
        const float* chp = xb + (size_t)c * HW;
        v0[j] = ld2u(chp + (e & 0xffffu));
        v1[j] = ld2u(chp + (e >> 16));
    }
}

template <int CIN, int HH, int WW, int POS, int KS>
__device__ __forceinline__ void sample_finish(
    const float4* __restrict__ ewt, const float2* v0, const float2* v1,
    ushort* __restrict__ Shi, ushort* __restrict__ Slo, int tt, int kbase)
{
    const int pp = tt & (POS - 1);
    const int j0 = (tt / POS) * 8;
    float s[8];
#pragma unroll
    for (int j = 0; j < 8; ++j) {
        const int kg = kbase + j0 + j;
        const int c  = (kg * 7282) >> 16;
        const int k9 = kg - c * 9;
        const float4 wv = ewt[k9 * POS + pp];
        s[j] = v0[j].x * wv.x + v0[j].y * wv.y
             + v1[j].x * wv.z + v1[j].y * wv.w;
    }
    uint hw[4], lw[4];
#pragma unroll
    for (int q = 0; q < 4; ++q) {
        const ushort h0 = f2bf(s[2 * q]);
        const ushort h1 = f2bf(s[2 * q + 1]);
        const float  l0 = s[2 * q]     - bf2f(h0);
        const float  l1 = s[2 * q + 1] - bf2f(h1);
        hw[q] = (uint)h0 | ((uint)h1 << 16);
        lw[q] = (uint)f2bf(l0) | ((uint)f2bf(l1) << 16);
    }
    uint4 hv; hv.x = hw[0]; hv.y = hw[1]; hv.z = hw[2]; hv.w = hw[3];
    uint4 lv; lv.x = lw[0]; lv.y = lw[1]; lv.z = lw[2]; lv.w = lw[3];
    *(uint4*)&Shi[pp * KS + j0] = hv;
    *(uint4*)&Slo[pp * KS + j0] = lv;
}

template <int CIN, int HH, int WW, int POS, int KS>
__device__ __forceinline__ void sample_chunk(
    const float* __restrict__ xb, const uint* __restrict__ eoff2,
    const float4* __restrict__ ewt, ushort* __restrict__ Shi,
    ushort* __restrict__ Slo, int tt, int kbase)
{
    float2 v0[8], v1[8];
    sample_issue<CIN, HH, WW, POS>(xb, eoff2, v0, v1, tt, kbase);
    sample_finish<CIN, HH, WW, POS, KS>(ewt, v0, v1, Shi, Slo, tt, kbase);
}

// ---------------- fused DCN on MFMA: sample + GEMM + bias + BN + ReLU -------
// Both paths use fragment-ordered weights (coalesced A loads).
template <int CIN, int HH, int WW, int POS, int KWAVES, int MINW,
          bool ASTAGE, bool OMS>
__global__ __launch_bounds__((POS / 16) * KWAVES * 64, MINW) void dcn_mfma_kernel(
    const float* __restrict__ xin,   // (B, CIN, HH, WW)
    const float* __restrict__ om,    // (B, 27, HH, WW)
    const float* __restrict__ omB,   // partial (OMS only)
    const ushort* __restrict__ whi,  // (128, K) bf16 hi, fragment order
    const ushort* __restrict__ wlo,  // (128, K) bf16 lo, fragment order
    const float* __restrict__ bias,
    const float* __restrict__ gam, const float* __restrict__ bet,
    const float* __restrict__ mu,  const float* __restrict__ var,
    float* __restrict__ out)         // (B, 128, HH*WW)
{
    constexpr int HW   = HH * WW;
    constexpr int K    = CIN * 9;
    constexpr int NPQ  = POS / 16;
    constexpr int NT   = NPQ * KWAVES * 64;
    constexpr int KC   = 32;
    constexpr int KS   = 40;                  // S row stride (ushort), pad 8
    constexpr int NCHT = K / KC;
    constexpr int NCH  = NCHT / KWAVES;
    constexpr int SBUF = POS * KS;            // ushorts per (hi|lo) buffer
    constexpr int ABN  = ASTAGE ? 8192 : 0;   // A-stage ushorts (16KB)
    // ASTAGE: single S buffer (2*SBUF). else: double-buffered (4*SBUF/kgid).
    constexpr int SN   = ASTAGE ? 2 * SBUF : KWAVES * 4 * SBUF;

    extern __shared__ __align__(16) char smem[];
    uint*    eoff2 = (uint*)smem;                 // 9*POS * 4B
    float4*  ewt   = (float4*)(eoff2 + 9 * POS);  // 9*POS * 16B
    float*   invp  = (float*)(ewt + 9 * POS);     // 128
    float*   shp   = invp + 128;                  // 128
    ushort*  Abuf  = (ushort*)(shp + 128);        // ABN ushorts
    ushort*  Sbase = Abuf + ABN;                  // SN ushorts

    const int tid = threadIdx.x;
    const int nt  = HW / POS;
    // bijective XCD swizzle (gridDim.x % 8 == 0)
    const int cpx = gridDim.x >> 3;
    const int bid = (blockIdx.x & 7) * cpx + (blockIdx.x >> 3);
    const int b   = bid / nt;
    const int p0  = (bid - b * nt) * POS;

    // ---- precompute paired bilinear entries ----
    const float* omb  = om + (size_t)b * 27 * HW;
    const float* ombB = OMS ? (omB + (size_t)b * 27 * HW) : nullptr;
    for (int i = tid; i < 9 * POS; i += NT) {
        const int k9 = i / POS, pp = i - k9 * POS;
        const int p  = p0 + pp;
        const int yy = p / WW;
        const int xx = p - yy * WW;
        float oy = omb[(size_t)k9 * HW + p];
        float ox = omb[(size_t)(9 + k9) * HW + p];
        float mv = omb[(size_t)(18 + k9) * HW + p];
        if constexpr (OMS) {
            oy += ombB[(size_t)k9 * HW + p];
            ox += ombB[(size_t)(9 + k9) * HW + p];
            mv += ombB[(size_t)(18 + k9) * HW + p];
        }
        const float m  = 1.0f / (1.0f + expf(-mv));
        const int ky = (k9 * 11) >> 5;        // /3 for 0..8
        const int kx = k9 - ky * 3;
        const float py = (float)(yy + ky - 1) + oy;
        const float px = (float)(xx + kx - 1) + ox;
        const float y0f = floorf(py), x0f = floorf(px);
        const int   y0  = (int)y0f,  x0 = (int)x0f;
        const int by0 = min(max(y0, 0), HH - 1);
        const int by1 = min(max(y0 + 1, 0), HH - 1);
        const int bx  = min(max(x0, 0), WW - 2);
        const float wy1 = py - y0f, wx1 = px - x0f;
        const float fy0 = (y0 >= 0  && y0 < HH)     ? (1.f - wy1) * m : 0.f;
        const float fy1 = (y0 >= -1 && y0 < HH - 1) ? wy1 * m         : 0.f;
        const float fx0v = 1.f - wx1, fx1v = wx1;
        float gx0 = 0.f, gx1 = 0.f;
        if (x0 >= 0 && x0 < WW)         { if (x0 == bx)     gx0 += fx0v; else gx1 += fx0v; }
        if (x0 + 1 >= 0 && x0 + 1 < WW) { if (x0 + 1 == bx) gx0 += fx1v; else gx1 += fx1v; }
        eoff2[i] = (uint)(by0 * WW + bx) | ((uint)(by1 * WW + bx) << 16);
        float4 wv; wv.x = fy0 * gx0; wv.y = fy0 * gx1;
                   wv.z = fy1 * gx0; wv.w = fy1 * gx1;
        ewt[i] = wv;
    }
    for (int i = tid; i < 128; i += NT) {
        const float iv = gam[i] * rsqrtf(var[i] + EPSV);
        invp[i] = iv;
        shp[i]  = bet[i] - mu[i] * iv + bias[i] * iv;
    }
    __syncthreads();

    const float* xb   = xin + (size_t)b * CIN * HW;
    const int lane = tid & 63;
    const int w    = tid >> 6;
    const int wq   = w & (NPQ - 1);
    const int kgid = w / NPQ;
    const int tt   = tid & (NPQ * 64 - 1);

    f32x4 acc[8];
#pragma unroll
    for (int mt = 0; mt < 8; ++mt) acc[mt] = (f32x4){0.f, 0.f, 0.f, 0.f};

    const int mrow = lane & 15;
    const int kq   = lane >> 4;

    if constexpr (ASTAGE) {
        // ===== single-S-buffer alternating-phase pipeline =====
        ushort* Shi = Sbase;
        ushort* Slo = Sbase + SBUF;
        float2 v0[8], v1[8];
        // prologue: S(0), A(0), issue gathers for chunk 1
        sample_chunk<CIN, HH, WW, POS, KS>(xb, eoff2, ewt, Shi, Slo, tt, 0);
        {
#pragma unroll
            for (int t = 0; t < 1024 / NT; ++t) {
                const int u = tid + t * NT;
                const ushort* srcp = (u < 512)
                    ? (whi + (size_t)u * 8)
                    : (wlo + (size_t)(u - 512) * 8);
                *(short8*)&Abuf[(size_t)u * 8] = *(const short8*)srcp;
            }
        }
        if (NCH > 1)
            sample_issue<CIN, HH, WW, POS>(xb, eoff2, v0, v1, tt, KC);
        asm volatile("s_waitcnt lgkmcnt(0)" ::: "memory");
        __builtin_amdgcn_s_barrier();
        __builtin_amdgcn_sched_barrier(0);

        for (int ch = 0; ch < NCH; ++ch) {
            // ---- MFMA phase (reads S + Abuf; no VMEM) ----
            const int boff = (wq * 16 + mrow) * KS + kq * 8;
            const short8 bh = *(const short8*)&Shi[boff];
            const short8 bl = *(const short8*)&Slo[boff];
#pragma unroll
            for (int mt = 0; mt < 8; ++mt) {
                const int au = (mt * 64 + lane) * 8;
                const short8 ah = *(const short8*)&Abuf[au];
                const short8 al = *(const short8*)&Abuf[4096 + au];
                acc[mt] = __builtin_amdgcn_mfma_f32_16x16x32_bf16(al, bh, acc[mt], 0, 0, 0);
                acc[mt] = __builtin_amdgcn_mfma_f32_16x16x32_bf16(ah, bl, acc[mt], 0, 0, 0);
                acc[mt] = __builtin_amdgcn_mfma_f32_16x16x32_bf16(ah, bh, acc[mt], 0, 0, 0);
            }
            if (ch + 1 < NCH) {
                // reads of S/Abuf complete -> safe to overwrite after barrier
                asm volatile("s_waitcnt lgkmcnt(0)" ::: "memory");
                __builtin_amdgcn_s_barrier();
                __builtin_amdgcn_sched_barrier(0);
                // ---- write phase: stage A(ch+1) | finish->S | issue(ch+2) --
                const size_t wb = (size_t)(ch + 1) * 4096;
#pragma unroll
                for (int t = 0; t < 1024 / NT; ++t) {
                    const int u = tid + t * NT;
                    const ushort* srcp = (u < 512)
                        ? (whi + wb + (size_t)u * 8)
                        : (wlo + wb + (size_t)(u - 512) * 8);
                    *(short8*)&Abuf[(size_t)u * 8] = *(const short8*)srcp;
                }
                sample_finish<CIN, HH, WW, POS, KS>(ewt, v0, v1, Shi, Slo,
                                                    tt, (ch + 1) * KC);
                if (ch + 2 < NCH)
                    sample_issue<CIN, HH, WW, POS>(xb, eoff2, v0, v1, tt,
                                                   (ch + 2) * KC);
                asm volatile("s_waitcnt lgkmcnt(0)" ::: "memory");
                __builtin_amdgcn_s_barrier();
                __builtin_amdgcn_sched_barrier(0);
            }
        }
    } else {
        ushort* S00 = Sbase + kgid * (4 * SBUF);
        sample_chunk<CIN, HH, WW, POS, KS>(xb, eoff2, ewt, S00, S00 + SBUF,
                                           tt, kgid * NCH * KC);
        __syncthreads();

        for (int ch = 0; ch < NCH; ++ch) {
            const int cur = ch & 1;
            ushort* Sc = S00 + (cur * 2) * SBUF;
            const int boff = (wq * 16 + mrow) * KS + kq * 8;
            const short8 bh = *(const short8*)&Sc[boff];
            const short8 bl = *(const short8*)&Sc[SBUF + boff];
            if (ch + 1 < NCH) {
                ushort* Sn = S00 + ((cur ^ 1) * 2) * SBUF;
                sample_chunk<CIN, HH, WW, POS, KS>(xb, eoff2, ewt,
                                                   Sn, Sn + SBUF, tt,
                                                   (kgid * NCH + ch + 1) * KC);
            }
            // A fragments: fragment-ordered -> coalesced 16B/lane L2 reads
            const size_t abase = (size_t)((kgid * NCH + ch) * 8) * 512;
#pragma unroll
            for (int mt = 0; mt < 8; ++mt) {
                const size_t ao = abase + (size_t)((mt * 64 + lane) * 8);
                const short8 ah = *(const short8*)(whi + ao);
                const short8 al = *(const short8*)(wlo + ao);
                acc[mt] = __builtin_amdgcn_mfma_f32_16x16x32_bf16(al, bh, acc[mt], 0, 0, 0);
                acc[mt] = __builtin_amdgcn_mfma_f32_16x16x32_bf16(ah, bl, acc[mt], 0, 0, 0);
                acc[mt] = __builtin_amdgcn_mfma_f32_16x16x32_bf16(ah, bh, acc[mt], 0, 0, 0);
            }
            __syncthreads();
        }
    }

    const int pcolb = wq * 16 + mrow;
    constexpr int RS = POS + 1;
    constexpr int SL = 128 * RS;
    float* red = (float*)Sbase;

    if constexpr (KWAVES == 4) {
        if (kgid >= 2) {
#pragma unroll
            for (int mt = 0; mt < 8; ++mt)
#pragma unroll
                for (int r = 0; r < 4; ++r) {
                    const int co = mt * 16 + kq * 4 + r;
                    red[(kgid - 2) * SL + co * RS + pcolb] = acc[mt][r];
                }
        }
        __syncthreads();
        if (kgid < 2) {
#pragma unroll
            for (int mt = 0; mt < 8; ++mt)
#pragma unroll
                for (int r = 0; r < 4; ++r) {
                    const int co = mt * 16 + kq * 4 + r;
                    acc[mt][r] += red[kgid * SL + co * RS + pcolb];
                }
        }
        __syncthreads();
        if (kgid == 1) {
#pragma unroll
            for (int mt = 0; mt < 8; ++mt)
#pragma unroll
                for (int r = 0; r < 4; ++r) {
                    const int co = mt * 16 + kq * 4 + r;
                    red[co * RS + pcolb] = acc[mt][r];
                }
        }
        __syncthreads();
        if (kgid == 0) {
#pragma unroll
            for (int mt = 0; mt < 8; ++mt)
#pragma unroll
                for (int r = 0; r < 4; ++r) {
                    const int co = mt * 16 + kq * 4 + r;
                    acc[mt][r] += red[co * RS + pcolb];
                }
        }
    } else if constexpr (KWAVES == 2) {
        if (kgid == 1) {
#pragma unroll
            for (int mt = 0; mt < 8; ++mt)
#pragma unroll
                for (int r = 0; r < 4; ++r) {
                    const int co = mt * 16 + kq * 4 + r;
                    red[co * RS + pcolb] = acc[mt][r];
                }
        }
        __syncthreads();
        if (kgid == 0) {
#pragma unroll
            for (int mt = 0; mt < 8; ++mt)
#pragma unroll
                for (int r = 0; r < 4; ++r) {
                    const int co = mt * 16 + kq * 4 + r;
                    acc[mt][r] += red[co * RS + pcolb];
                }
        }
    }

    if (kgid == 0) {
        float* outb = out + (size_t)b * 128 * HW + p0 + pcolb;
#pragma unroll
        for (int mt = 0; mt < 8; ++mt)
#pragma unroll
            for (int r = 0; r < 4; ++r) {
                const int co = mt * 16 + kq * 4 + r;
                outb[(size_t)co * HW] = fmaxf(acc[mt][r] * invp[co] + shp[co], 0.f);
            }
    }
}

// ---------------- depthwise transposed-conv upsample x2 (k=4, pad 2) --------
__global__ __launch_bounds__(256) void upsample_kernel(
    const float* __restrict__ y,    // (4,128,64,64)
    const float* __restrict__ wup,  // (128,1,4,4)
    float* __restrict__ out)        // (4,128,128,128)
{
    const int idx = blockIdx.x * 256 + threadIdx.x;
    const int ox = idx & 127;
    const int oy = (idx >> 7) & 127;
    const int c  = (idx >> 14) & 127;
    const int b  = idx >> 21;

    const float* yc = y + (size_t)(b * 128 + c) * 4096;
    const float* wc = wup + c * 16;

    float acc = 0.f;
#pragma unroll
    for (int ky = 0; ky < 4; ++ky) {
        const int qy = oy + ky - 2;
        if (qy & 1) continue;
        const int iy = qy >> 1;
        if (iy < 0 || iy >= 64) continue;
#pragma unroll
        for (int kx = 0; kx < 4; ++kx) {
            const int qx = ox + kx - 2;
            if (qx & 1) continue;
            const int ix = qx >> 1;
            if (ix < 0 || ix >= 64) continue;
            acc += yc[iy * 64 + ix] * wc[(3 - ky) * 4 + (3 - kx)];
        }
    }
    out[idx] = acc;
}

// ---------------------------------------------------------------------------
extern "C" void kernel_launch(void* const* d_in, const int* in_sizes, int n_in,
                              void* d_out, int out_size, void* d_ws, size_t ws_size,
                              hipStream_t stream) {
    const float* x      = (const float*)d_in[0];
    const float* w_off1 = (const float*)d_in[1];
    const float* b_off1 = (const float*)d_in[2];
    const float* w1     = (const float*)d_in[3];
    const float* b1     = (const float*)d_in[4];
    const float* g1v    = (const float*)d_in[5];
    const float* be1    = (const float*)d_in[6];
    const float* m1     = (const float*)d_in[7];
    const float* v1     = (const float*)d_in[8];
    const float* w_up   = (const float*)d_in[9];
    const float* w_off2 = (const float*)d_in[10];
    const float* b_off2 = (const float*)d_in[11];
    const float* w2     = (const float*)d_in[12];
    const float* b2     = (const float*)d_in[13];
    const float* g2v    = (const float*)d_in[14];
    const float* be2    = (const float*)d_in[15];
    const float* m2     = (const float*)d_in[16];
    const float* v2     = (const float*)d_in[17];

    float* ws  = (float*)d_ws;
    float* om1 = ws;                     // 4*27*4096   =   442368 f
    float* y1  = om1 + 442368;           // 4*128*4096  =  2097152 f
    float* up  = y1 + 2097152;           // 4*128*16384 =  8388608 f
    float* om2 = up + 8388608;           // 4*27*16384  =  1769472 f
    float* outf = (float*)d_out;

    // w1 split parked in `up` (dead until upsample overwrites it)
    ushort* w1hi = (ushort*)up;          // 294912 ushort
    ushort* w1lo = w1hi + 294912;
    // w2 split parked in `y1` (dead after upsample reads it)
    ushort* w2hi = (ushort*)y1;          // 147456 ushort
    ushort* w2lo = w2hi + 147456;
    // conv1 z=1 partial parked in om2 (dead until conv2 writes it)
    float* om1B = om2;                   // 442368 f <= 1769472 f

    // prep: split w1 -> bf16 hi/lo in fragment order (coalesced A loads)
    wsplit_perm_kernel<<<(294912 + 255) / 256, 256, 0, stream>>>(
        w1, w1hi, w1lo, 256, 294912);

    {   // om1/om1B = conv3x3(x, w_off1) + b_off1 — 2-way channel z-split
        dim3 grid(64, 4, 2);
        conv_off_kernel<256, 2, 64, 64, 64, 8, 4><<<grid, 512, 0, stream>>>(
            x, w_off1, b_off1, om1, om1B);
    }
    // y1 = bn_relu(dcn1) — MFMA, POS=32, 4-way K-split; om = om1 + om1B
    // LDS: 1152 + 4608 + 1024 + 40960 = 47744
    dcn_mfma_kernel<256, 64, 64, 32, 4, 4, false, true>
        <<<4 * (4096 / 32), 512, 47744, stream>>>(
        x, om1, om1B, w1hi, w1lo, b1, g1v, be1, m1, v1, y1);
    // up = depthwise transposed upsample (clobbers w1 split — now dead)
    upsample_kernel<<<8388608 / 256, 256, 0, stream>>>(y1, w_up, up);
    // prep: split w2 -> bf16 hi/lo in fragment order (y1 now dead)
    wsplit_perm_kernel<<<(147456 + 255) / 256, 256, 0, stream>>>(
        w2, w2hi, w2lo, 128, 147456);
    {   // om2 = conv3x3(up, w_off2) + b_off2 — column-tiled
        dim3 grid(256, 4, 1);
        conv_off_kernel<128, 1, 128, 128, 64, 4, 8><<<grid, 256, 0, stream>>>(
            up, w_off2, b_off2, om2, om2);
    }
    // out = bn_relu(dcn2) — MFMA, POS=64, A-staged, single-S pipeline
    // LDS: 2304 + 9216 + 1024 + 16384 + 10240 = 39168 -> 4 blocks/CU
    dcn_mfma_kernel<128, 128, 128, 64, 1, 4, true, false>
        <<<4 * (16384 / 64), 256, 39168, stream>>>(
        up, om2, om2, w2hi, w2lo, b2, g2v, be2, m2, v2, outf);
}

// Round 12
// 396.166 us; speedup vs baseline: 3.3918x; 1.4208x over previous
//
#include <hip/hip_runtime.h>
#include <hip/hip_bf16.h>
#include <cmath>

// ---------------------------------------------------------------------------
// Pipeline: y1 = bn_relu(dcn(x, w_off1, b_off1, w1, b1))        (4,128,64,64)
//           up = up_depthwise(y1, w_up, f=2)                    (4,128,128,128)
//           out = bn_relu(dcn(up, w_off2, b_off2, w2, b2))      (4,128,128,128)
// ALL GEMM-shaped work (both DCNs AND both offset convs) on
// mfma_f32_16x16x32_bf16 with split-bf16 (hi/lo, 3 products).
// conv_off -> conv_mfma: M=27 padded to 32 (2 m-tiles, zero-pad rows in the
// fragment-ordered weight split); B built by tap-sampler (1 clamped load x
// {0,1} weight). conv1: POS=16, KWAVES=4 -> 1024 blocks (grid-starved fix).
// dcn2 (ASTAGE): single-S alternating-phase pipeline (R11).
// Weights pre-permuted into per-chunk fragment order (coalesced A loads).
// Workspace: om1 | y1 | up | om2 ; w1+wo1 splits parked in `up`,
// w2+wo2 splits parked in `y1`.
// ---------------------------------------------------------------------------

#define EPSV 1e-5f

typedef __attribute__((ext_vector_type(8))) short short8;
typedef __attribute__((ext_vector_type(4))) float f32x4;

__device__ __forceinline__ ushort f2bf(float f) {
    union { float f; uint u; } v; v.f = f;
    const uint r = v.u + 0x7fffu + ((v.u >> 16) & 1u);   // RNE
    return (ushort)(r >> 16);
}
__device__ __forceinline__ float bf2f(ushort h) {
    union { uint u; float f; } v; v.u = ((uint)h) << 16;
    return v.f;
}
__device__ __forceinline__ float2 ld2u(const float* p) {
    float2 v; __builtin_memcpy(&v, p, sizeof(float2)); return v;
}

// ---- pack 8 fp32 -> bf16 hi/lo rows of S --------------------------------
template <int KS>
__device__ __forceinline__ void pack_store8(
    const float* s, ushort* __restrict__ Shi, ushort* __restrict__ Slo,
    int pp, int j0)
{
    uint hw[4], lw[4];
#pragma unroll
    for (int q = 0; q < 4; ++q) {
        const ushort h0 = f2bf(s[2 * q]);
        const ushort h1 = f2bf(s[2 * q + 1]);
        const float  l0 = s[2 * q]     - bf2f(h0);
        const float  l1 = s[2 * q + 1] - bf2f(h1);
        hw[q] = (uint)h0 | ((uint)h1 << 16);
        lw[q] = (uint)f2bf(l0) | ((uint)f2bf(l1) << 16);
    }
    uint4 hv; hv.x = hw[0]; hv.y = hw[1]; hv.z = hw[2]; hv.w = hw[3];
    uint4 lv; lv.x = lw[0]; lv.y = lw[1]; lv.z = lw[2]; lv.w = lw[3];
    *(uint4*)&Shi[pp * KS + j0] = hv;
    *(uint4*)&Slo[pp * KS + j0] = lv;
}

// ------- weight split: fp32 -> bf16 hi/lo in per-chunk FRAGMENT order -------
// dst[((ch*8 + mt)*64 + lane)*8 + j] = w[co][k], k = c*9+k9 (channel-major),
// ch = k>>5, kq = (k&31)>>3, j = k&7, mt = co>>4, lane = (co&15) | (kq<<4).
__global__ __launch_bounds__(256) void wsplit_perm_kernel(
    const float* __restrict__ w, ushort* __restrict__ hi,
    ushort* __restrict__ lo, int cin, int n)
{
    const int i = blockIdx.x * 256 + threadIdx.x;
    if (i >= n) return;
    const int cin9 = cin * 9;
    const int co = i / cin9;
    const int k  = i - co * cin9;            // channel-major K index
    const int ch = k >> 5;
    const int kq = (k & 31) >> 3;
    const int j  = k & 7;
    const int mt = co >> 4;
    const int lane = (co & 15) | (kq << 4);
    const size_t dst = ((size_t)(ch * 8 + mt) * 64 + lane) * 8 + j;
    const float f = w[i];
    const ushort h = f2bf(f);
    hi[dst] = h;
    lo[dst] = f2bf(f - bf2f(h));
}

// ------- conv weight split: (27,CIN,3,3) -> M=32 zero-padded frag order -----
// dst[((ch*2 + mt)*64 + lane)*8 + j], co in [0,32): zero rows for co>=27.
__global__ __launch_bounds__(256) void wsplit_perm_conv_kernel(
    const float* __restrict__ w, ushort* __restrict__ hi,
    ushort* __restrict__ lo, int cin, int n)   // n = 32*cin*9
{
    const int i = blockIdx.x * 256 + threadIdx.x;
    if (i >= n) return;
    const int cin9 = cin * 9;
    const int co = i / cin9;
    const int k  = i - co * cin9;
    const int ch = k >> 5;
    const int kq = (k & 31) >> 3;
    const int j  = k & 7;
    const int mt = co >> 4;
    const int lane = (co & 15) | (kq << 4);
    const size_t dst = ((size_t)(ch * 2 + mt) * 64 + lane) * 8 + j;
    const float f = (co < 27) ? w[(size_t)co * cin9 + k] : 0.f;
    const ushort h = f2bf(f);
    hi[dst] = h;
    lo[dst] = f2bf(f - bf2f(h));
}

// ---------------- offset conv on MFMA: 3x3, pad 1, 27(->32) outputs ---------
// B built by tap-sampler: 1 clamped load x {0,1} weight per (k,pos).
template <int CIN, int HH, int WW, int POS, int KS>
__device__ __forceinline__ void conv_sample_chunk(
    const float* __restrict__ xb, const uint* __restrict__ toff,
    const float* __restrict__ twt, ushort* __restrict__ Shi,
    ushort* __restrict__ Slo, int tt, int kbase)
{
    constexpr int HW = HH * WW;
    const int pp = tt & (POS - 1);
    const int j0 = (tt / POS) * 8;
    float s[8];
#pragma unroll
    for (int j = 0; j < 8; ++j) {
        const int kg = kbase + j0 + j;
        const int c  = (kg * 7282) >> 16;       // /9 (exact for kg<2304)
        const int k9 = kg - c * 9;
        const int ei = k9 * POS + pp;
        s[j] = xb[(size_t)c * HW + toff[ei]] * twt[ei];
    }
    pack_store8<KS>(s, Shi, Slo, pp, j0);
}

template <int CIN, int HH, int WW, int POS, int KWAVES, int MINW>
__global__ __launch_bounds__((POS / 16) * KWAVES * 64, MINW) void conv_mfma_kernel(
    const float* __restrict__ in,    // (B, CIN, HH, WW)
    const ushort* __restrict__ whi,  // (32, CIN*9) frag order, zero-padded
    const ushort* __restrict__ wlo,
    const float* __restrict__ bias,  // (27)
    float* __restrict__ om)          // (B, 27, HH*WW)
{
    constexpr int HW   = HH * WW;
    constexpr int K    = CIN * 9;
    constexpr int NPQ  = POS / 16;
    constexpr int NT   = NPQ * KWAVES * 64;
    constexpr int KC   = 32;
    constexpr int KS   = 40;
    constexpr int NCHT = K / KC;
    constexpr int NCH  = NCHT / KWAVES;
    constexpr int SBUF = POS * KS;

    extern __shared__ __align__(16) char smem[];
    uint*   toff  = (uint*)smem;              // 9*POS
    float*  twt   = (float*)(toff + 9 * POS); // 9*POS
    ushort* Sbase = (ushort*)(twt + 9 * POS);

    const int tid = threadIdx.x;
    const int nt  = HW / POS;
    const int cpx = gridDim.x >> 3;
    const int bid = (blockIdx.x & 7) * cpx + (blockIdx.x >> 3);
    const int b   = bid / nt;
    const int p0  = (bid - b * nt) * POS;

    for (int i = tid; i < 9 * POS; i += NT) {
        const int k9 = i / POS, pp = i - k9 * POS;
        const int p  = p0 + pp;
        const int yy = p / WW, xx = p - yy * WW;
        const int ky = (k9 * 11) >> 5, kx = k9 - ky * 3;
        const int iy = yy + ky - 1, ix = xx + kx - 1;
        const bool v = (iy >= 0) && (iy < HH) && (ix >= 0) && (ix < WW);
        const int cy = min(max(iy, 0), HH - 1);
        const int cx = min(max(ix, 0), WW - 1);
        toff[i] = (uint)(cy * WW + cx);
        twt[i]  = v ? 1.f : 0.f;
    }
    __syncthreads();

    const float* xb = in + (size_t)b * CIN * HW;
    const int lane = tid & 63;
    const int w    = tid >> 6;
    const int wq   = w & (NPQ - 1);
    const int kgid = w / NPQ;
    const int tt   = tid & (NPQ * 64 - 1);
    ushort* S00 = Sbase + kgid * (4 * SBUF);

    f32x4 acc[2];
    acc[0] = (f32x4){0.f, 0.f, 0.f, 0.f};
    acc[1] = (f32x4){0.f, 0.f, 0.f, 0.f};
    const int mrow = lane & 15;
    const int kq   = lane >> 4;

    conv_sample_chunk<CIN, HH, WW, POS, KS>(xb, toff, twt, S00, S00 + SBUF,
                                            tt, kgid * NCH * KC);
    __syncthreads();

    for (int ch = 0; ch < NCH; ++ch) {
        const int cur = ch & 1;
        ushort* Sc = S00 + (cur * 2) * SBUF;
        const int boff = (wq * 16 + mrow) * KS + kq * 8;
        const short8 bh = *(const short8*)&Sc[boff];
        const short8 bl = *(const short8*)&Sc[SBUF + boff];
        if (ch + 1 < NCH) {
            ushort* Sn = S00 + ((cur ^ 1) * 2) * SBUF;
            conv_sample_chunk<CIN, HH, WW, POS, KS>(xb, toff, twt,
                                                    Sn, Sn + SBUF, tt,
                                                    (kgid * NCH + ch + 1) * KC);
        }
        const size_t abase = (size_t)((kgid * NCH + ch) * 2) * 512;
#pragma unroll
        for (int mt = 0; mt < 2; ++mt) {
            const size_t ao = abase + (size_t)((mt * 64 + lane) * 8);
            const short8 ah = *(const short8*)(whi + ao);
            const short8 al = *(const short8*)(wlo + ao);
            acc[mt] = __builtin_amdgcn_mfma_f32_16x16x32_bf16(al, bh, acc[mt], 0, 0, 0);
            acc[mt] = __builtin_amdgcn_mfma_f32_16x16x32_bf16(ah, bl, acc[mt], 0, 0, 0);
            acc[mt] = __builtin_amdgcn_mfma_f32_16x16x32_bf16(ah, bh, acc[mt], 0, 0, 0);
        }
        __syncthreads();
    }

    const int pcolb = wq * 16 + mrow;
    constexpr int RS = POS + 1;
    constexpr int SL = 32 * RS;
    float* red = (float*)Sbase;

    if constexpr (KWAVES == 4) {
        if (kgid >= 2) {
#pragma unroll
            for (int mt = 0; mt < 2; ++mt)
#pragma unroll
                for (int r = 0; r < 4; ++r) {
                    const int co = mt * 16 + kq * 4 + r;
                    red[(kgid - 2) * SL + co * RS + pcolb] = acc[mt][r];
                }
        }
        __syncthreads();
        if (kgid < 2) {
#pragma unroll
            for (int mt = 0; mt < 2; ++mt)
#pragma unroll
                for (int r = 0; r < 4; ++r) {
                    const int co = mt * 16 + kq * 4 + r;
                    acc[mt][r] += red[kgid * SL + co * RS + pcolb];
                }
        }
        __syncthreads();
        if (kgid == 1) {
#pragma unroll
            for (int mt = 0; mt < 2; ++mt)
#pragma unroll
                for (int r = 0; r < 4; ++r) {
                    const int co = mt * 16 + kq * 4 + r;
                    red[co * RS + pcolb] = acc[mt][r];
                }
        }
        __syncthreads();
        if (kgid == 0) {
#pragma unroll
            for (int mt = 0; mt < 2; ++mt)
#pragma unroll
                for (int r = 0; r < 4; ++r) {
                    const int co = mt * 16 + kq * 4 + r;
                    acc[mt][r] += red[co * RS + pcolb];
                }
        }
    } else if constexpr (KWAVES == 2) {
        if (kgid == 1) {
#pragma unroll
            for (int mt = 0; mt < 2; ++mt)
#pragma unroll
                for (int r = 0; r < 4; ++r) {
                    const int co = mt * 16 + kq * 4 + r;
                    red[co * RS + pcolb] = acc[mt][r];
                }
        }
        __syncthreads();
        if (kgid == 0) {
#pragma unroll
            for (int mt = 0; mt < 2; ++mt)
#pragma unroll
                for (int r = 0; r < 4; ++r) {
                    const int co = mt * 16 + kq * 4 + r;
                    acc[mt][r] += red[co * RS + pcolb];
                }
        }
    }

    if (kgid == 0) {
        float* ob = om + (size_t)b * 27 * HW + p0 + pcolb;
#pragma unroll
        for (int mt = 0; mt < 2; ++mt)
#pragma unroll
            for (int r = 0; r < 4; ++r) {
                const int co = mt * 16 + kq * 4 + r;
                if (co < 27)
                    ob[(size_t)co * HW] = acc[mt][r] + bias[co];
            }
    }
}

// ---------------- paired sampler: issue / finish ----------------------------
template <int CIN, int HH, int WW, int POS>
__device__ __forceinline__ void sample_issue(
    const float* __restrict__ xb, const uint* __restrict__ eoff2,
    float2* v0, float2* v1, int tt, int kbase)
{
    constexpr int HW = HH * WW;
    const int pp = tt & (POS - 1);
    const int j0 = (tt / POS) * 8;
#pragma unroll
    for (int j = 0; j < 8; ++j) {
        const int kg = kbase + j0 + j;
        const int c  = (kg * 7282) >> 16;       // /9 (exact for kg<2304)
        const int k9 = kg - c * 9;
        const uint e = eoff2[k9 * POS + pp];
        const float* chp = xb + (size_t)c * HW;
        v0[j] = ld2u(chp + (e & 0xffffu));
        v1[j] = ld2u(chp + (e >> 16));
    }
}

template <int CIN, int HH, int WW, int POS, int KS>
__device__ __forceinline__ void sample_finish(
    const float4* __restrict__ ewt, const float2* v0, const float2* v1,
    ushort* __restrict__ Shi, ushort* __restrict__ Slo, int tt, int kbase)
{
    const int pp = tt & (POS - 1);
    const int j0 = (tt / POS) * 8;
    float s[8];
#pragma unroll
    for (int j = 0; j < 8; ++j) {
        const int kg = kbase + j0 + j;
        const int c  = (kg * 7282) >> 16;
        const int k9 = kg - c * 9;
        const float4 wv = ewt[k9 * POS + pp];
        s[j] = v0[j].x * wv.x + v0[j].y * wv.y
             + v1[j].x * wv.z + v1[j].y * wv.w;
    }
    pack_store8<KS>(s, Shi, Slo, pp, j0);
}

template <int CIN, int HH, int WW, int POS, int KS>
__device__ __forceinline__ void sample_chunk(
    const float* __restrict__ xb, const uint* __restrict__ eoff2,
    const float4* __restrict__ ewt, ushort* __restrict__ Shi,
    ushort* __restrict__ Slo, int tt, int kbase)
{
    float2 v0[8], v1[8];
    sample_issue<CIN, HH, WW, POS>(xb, eoff2, v0, v1, tt, kbase);
    sample_finish<CIN, HH, WW, POS, KS>(ewt, v0, v1, Shi, Slo, tt, kbase);
}

// ---------------- fused DCN on MFMA: sample + GEMM + bias + BN + ReLU -------
template <int CIN, int HH, int WW, int POS, int KWAVES, int MINW,
          bool ASTAGE, bool OMS>
__global__ __launch_bounds__((POS / 16) * KWAVES * 64, MINW) void dcn_mfma_kernel(
    const float* __restrict__ xin,   // (B, CIN, HH, WW)
    const float* __restrict__ om,    // (B, 27, HH, WW)
    const float* __restrict__ omB,   // partial (OMS only)
    const ushort* __restrict__ whi,  // (128, K) bf16 hi, fragment order
    const ushort* __restrict__ wlo,  // (128, K) bf16 lo, fragment order
    const float* __restrict__ bias,
    const float* __restrict__ gam, const float* __restrict__ bet,
    const float* __restrict__ mu,  const float* __restrict__ var,
    float* __restrict__ out)         // (B, 128, HH*WW)
{
    constexpr int HW   = HH * WW;
    constexpr int K    = CIN * 9;
    constexpr int NPQ  = POS / 16;
    constexpr int NT   = NPQ * KWAVES * 64;
    constexpr int KC   = 32;
    constexpr int KS   = 40;
    constexpr int NCHT = K / KC;
    constexpr int NCH  = NCHT / KWAVES;
    constexpr int SBUF = POS * KS;
    constexpr int ABN  = ASTAGE ? 8192 : 0;
    constexpr int SN   = ASTAGE ? 2 * SBUF : KWAVES * 4 * SBUF;

    extern __shared__ __align__(16) char smem[];
    uint*    eoff2 = (uint*)smem;
    float4*  ewt   = (float4*)(eoff2 + 9 * POS);
    float*   invp  = (float*)(ewt + 9 * POS);
    float*   shp   = invp + 128;
    ushort*  Abuf  = (ushort*)(shp + 128);
    ushort*  Sbase = Abuf + ABN;
    (void)SN;

    const int tid = threadIdx.x;
    const int nt  = HW / POS;
    const int cpx = gridDim.x >> 3;
    const int bid = (blockIdx.x & 7) * cpx + (blockIdx.x >> 3);
    const int b   = bid / nt;
    const int p0  = (bid - b * nt) * POS;

    const float* omb  = om + (size_t)b * 27 * HW;
    const float* ombB = OMS ? (omB + (size_t)b * 27 * HW) : nullptr;
    for (int i = tid; i < 9 * POS; i += NT) {
        const int k9 = i / POS, pp = i - k9 * POS;
        const int p  = p0 + pp;
        const int yy = p / WW;
        const int xx = p - yy * WW;
        float oy = omb[(size_t)k9 * HW + p];
        float ox = omb[(size_t)(9 + k9) * HW + p];
        float mv = omb[(size_t)(18 + k9) * HW + p];
        if constexpr (OMS) {
            oy += ombB[(size_t)k9 * HW + p];
            ox += ombB[(size_t)(9 + k9) * HW + p];
            mv += ombB[(size_t)(18 + k9) * HW + p];
        }
        const float m  = 1.0f / (1.0f + expf(-mv));
        const int ky = (k9 * 11) >> 5;
        const int kx = k9 - ky * 3;
        const float py = (float)(yy + ky - 1) + oy;
        const float px = (float)(xx + kx - 1) + ox;
        const float y0f = floorf(py), x0f = floorf(px);
        const int   y0  = (int)y0f,  x0 = (int)x0f;
        const int by0 = min(max(y0, 0), HH - 1);
        const int by1 = min(max(y0 + 1, 0), HH - 1);
        const int bx  = min(max(x0, 0), WW - 2);
        const float wy1 = py - y0f, wx1 = px - x0f;
        const float fy0 = (y0 >= 0  && y0 < HH)     ? (1.f - wy1) * m : 0.f;
        const float fy1 = (y0 >= -1 && y0 < HH - 1) ? wy1 * m         : 0.f;
        const float fx0v = 1.f - wx1, fx1v = wx1;
        float gx0 = 0.f, gx1 = 0.f;
        if (x0 >= 0 && x0 < WW)         { if (x0 == bx)     gx0 += fx0v; else gx1 += fx0v; }
        if (x0 + 1 >= 0 && x0 + 1 < WW) { if (x0 + 1 == bx) gx0 += fx1v; else gx1 += fx1v; }
        eoff2[i] = (uint)(by0 * WW + bx) | ((uint)(by1 * WW + bx) << 16);
        float4 wv; wv.x = fy0 * gx0; wv.y = fy0 * gx1;
                   wv.z = fy1 * gx0; wv.w = fy1 * gx1;
        ewt[i] = wv;
    }
    for (int i = tid; i < 128; i += NT) {
        const float iv = gam[i] * rsqrtf(var[i] + EPSV);
        invp[i] = iv;
        shp[i]  = bet[i] - mu[i] * iv + bias[i] * iv;
    }
    __syncthreads();

    const float* xb   = xin + (size_t)b * CIN * HW;
    const int lane = tid & 63;
    const int w    = tid >> 6;
    const int wq   = w & (NPQ - 1);
    const int kgid = w / NPQ;
    const int tt   = tid & (NPQ * 64 - 1);

    f32x4 acc[8];
#pragma unroll
    for (int mt = 0; mt < 8; ++mt) acc[mt] = (f32x4){0.f, 0.f, 0.f, 0.f};

    const int mrow = lane & 15;
    const int kq   = lane >> 4;

    if constexpr (ASTAGE) {
        // ===== single-S-buffer alternating-phase pipeline =====
        ushort* Shi = Sbase;
        ushort* Slo = Sbase + SBUF;
        float2 v0[8], v1[8];
        sample_chunk<CIN, HH, WW, POS, KS>(xb, eoff2, ewt, Shi, Slo, tt, 0);
        {
#pragma unroll
            for (int t = 0; t < 1024 / NT; ++t) {
                const int u = tid + t * NT;
                const ushort* srcp = (u < 512)
                    ? (whi + (size_t)u * 8)
                    : (wlo + (size_t)(u - 512) * 8);
                *(short8*)&Abuf[(size_t)u * 8] = *(const short8*)srcp;
            }
        }
        if (NCH > 1)
            sample_issue<CIN, HH, WW, POS>(xb, eoff2, v0, v1, tt, KC);
        asm volatile("s_waitcnt lgkmcnt(0)" ::: "memory");
        __builtin_amdgcn_s_barrier();
        __builtin_amdgcn_sched_barrier(0);

        for (int ch = 0; ch < NCH; ++ch) {
            const int boff = (wq * 16 + mrow) * KS + kq * 8;
            const short8 bh = *(const short8*)&Shi[boff];
            const short8 bl = *(const short8*)&Slo[boff];
#pragma unroll
            for (int mt = 0; mt < 8; ++mt) {
                const int au = (mt * 64 + lane) * 8;
                const short8 ah = *(const short8*)&Abuf[au];
                const short8 al = *(const short8*)&Abuf[4096 + au];
                acc[mt] = __builtin_amdgcn_mfma_f32_16x16x32_bf16(al, bh, acc[mt], 0, 0, 0);
                acc[mt] = __builtin_amdgcn_mfma_f32_16x16x32_bf16(ah, bl, acc[mt], 0, 0, 0);
                acc[mt] = __builtin_amdgcn_mfma_f32_16x16x32_bf16(ah, bh, acc[mt], 0, 0, 0);
            }
            if (ch + 1 < NCH) {
                asm volatile("s_waitcnt lgkmcnt(0)" ::: "memory");
                __builtin_amdgcn_s_barrier();
                __builtin_amdgcn_sched_barrier(0);
                const size_t wb = (size_t)(ch + 1) * 4096;
#pragma unroll
                for (int t = 0; t < 1024 / NT; ++t) {
                    const int u = tid + t * NT;
                    const ushort* srcp = (u < 512)
                        ? (whi + wb + (size_t)u * 8)
                        : (wlo + wb + (size_t)(u - 512) * 8);
                    *(short8*)&Abuf[(size_t)u * 8] = *(const short8*)srcp;
                }
                sample_finish<CIN, HH, WW, POS, KS>(ewt, v0, v1, Shi, Slo,
                                                    tt, (ch + 1) * KC);
                if (ch + 2 < NCH)
                    sample_issue<CIN, HH, WW, POS>(xb, eoff2, v0, v1, tt,
                                                   (ch + 2) * KC);
                asm volatile("s_waitcnt lgkmcnt(0)" ::: "memory");
                __builtin_amdgcn_s_barrier();
                __builtin_amdgcn_sched_barrier(0);
            }
        }
    } else {
        ushort* S00 = Sbase + kgid * (4 * SBUF);
        sample_chunk<CIN, HH, WW, POS, KS>(xb, eoff2, ewt, S00, S00 + SBUF,
                                           tt, kgid * NCH * KC);
        __syncthreads();

        for (int ch = 0; ch < NCH; ++ch) {
            const int cur = ch & 1;
            ushort* Sc = S00 + (cur * 2) * SBUF;
            const int boff = (wq * 16 + mrow) * KS + kq * 8;
            const short8 bh = *(const short8*)&Sc[boff];
            const short8 bl = *(const short8*)&Sc[SBUF + boff];
            if (ch + 1 < NCH) {
                ushort* Sn = S00 + ((cur ^ 1) * 2) * SBUF;
                sample_chunk<CIN, HH, WW, POS, KS>(xb, eoff2, ewt,
                                                   Sn, Sn + SBUF, tt,
                                                   (kgid * NCH + ch + 1) * KC);
            }
            const size_t abase = (size_t)((kgid * NCH + ch) * 8) * 512;
#pragma unroll
            for (int mt = 0; mt < 8; ++mt) {
                const size_t ao = abase + (size_t)((mt * 64 + lane) * 8);
                const short8 ah = *(const short8*)(whi + ao);
                const short8 al = *(const short8*)(wlo + ao);
                acc[mt] = __builtin_amdgcn_mfma_f32_16x16x32_bf16(al, bh, acc[mt], 0, 0, 0);
                acc[mt] = __builtin_amdgcn_mfma_f32_16x16x32_bf16(ah, bl, acc[mt], 0, 0, 0);
                acc[mt] = __builtin_amdgcn_mfma_f32_16x16x32_bf16(ah, bh, acc[mt], 0, 0, 0);
            }
            __syncthreads();
        }
    }

    const int pcolb = wq * 16 + mrow;
    constexpr int RS = POS + 1;
    constexpr int SL = 128 * RS;
    float* red = (float*)Sbase;

    if constexpr (KWAVES == 4) {
        if (kgid >= 2) {
#pragma unroll
            for (int mt = 0; mt < 8; ++mt)
#pragma unroll
                for (int r = 0; r < 4; ++r) {
                    const int co = mt * 16 + kq * 4 + r;
                    red[(kgid - 2) * SL + co * RS + pcolb] = acc[mt][r];
                }
        }
        __syncthreads();
        if (kgid < 2) {
#pragma unroll
            for (int mt = 0; mt < 8; ++mt)
#pragma unroll
                for (int r = 0; r < 4; ++r) {
                    const int co = mt * 16 + kq * 4 + r;
                    acc[mt][r] += red[kgid * SL + co * RS + pcolb];
                }
        }
        __syncthreads();
        if (kgid == 1) {
#pragma unroll
            for (int mt = 0; mt < 8; ++mt)
#pragma unroll
                for (int r = 0; r < 4; ++r) {
                    const int co = mt * 16 + kq * 4 + r;
                    red[co * RS + pcolb] = acc[mt][r];
                }
        }
        __syncthreads();
        if (kgid == 0) {
#pragma unroll
            for (int mt = 0; mt < 8; ++mt)
#pragma unroll
                for (int r = 0; r < 4; ++r) {
                    const int co = mt * 16 + kq * 4 + r;
                    acc[mt][r] += red[co * RS + pcolb];
                }
        }
    } else if constexpr (KWAVES == 2) {
        if (kgid == 1) {
#pragma unroll
            for (int mt = 0; mt < 8; ++mt)
#pragma unroll
                for (int r = 0; r < 4; ++r) {
                    const int co = mt * 16 + kq * 4 + r;
                    red[co * RS + pcolb] = acc[mt][r];
                }
        }
        __syncthreads();
        if (kgid == 0) {
#pragma unroll
            for (int mt = 0; mt < 8; ++mt)
#pragma unroll
                for (int r = 0; r < 4; ++r) {
                    const int co = mt * 16 + kq * 4 + r;
                    acc[mt][r] += red[co * RS + pcolb];
                }
        }
    }

    if (kgid == 0) {
        float* outb = out + (size_t)b * 128 * HW + p0 + pcolb;
#pragma unroll
        for (int mt = 0; mt < 8; ++mt)
#pragma unroll
            for (int r = 0; r < 4; ++r) {
                const int co = mt * 16 + kq * 4 + r;
                outb[(size_t)co * HW] = fmaxf(acc[mt][r] * invp[co] + shp[co], 0.f);
            }
    }
}

// ---------------- depthwise transposed-conv upsample x2 (k=4, pad 2) --------
__global__ __launch_bounds__(256) void upsample_kernel(
    const float* __restrict__ y,    // (4,128,64,64)
    const float* __restrict__ wup,  // (128,1,4,4)
    float* __restrict__ out)        // (4,128,128,128)
{
    const int idx = blockIdx.x * 256 + threadIdx.x;
    const int ox = idx & 127;
    const int oy = (idx >> 7) & 127;
    const int c  = (idx >> 14) & 127;
    const int b  = idx >> 21;

    const float* yc = y + (size_t)(b * 128 + c) * 4096;
    const float* wc = wup + c * 16;

    float acc = 0.f;
#pragma unroll
    for (int ky = 0; ky < 4; ++ky) {
        const int qy = oy + ky - 2;
        if (qy & 1) continue;
        const int iy = qy >> 1;
        if (iy < 0 || iy >= 64) continue;
#pragma unroll
        for (int kx = 0; kx < 4; ++kx) {
            const int qx = ox + kx - 2;
            if (qx & 1) continue;
            const int ix = qx >> 1;
            if (ix < 0 || ix >= 64) continue;
            acc += yc[iy * 64 + ix] * wc[(3 - ky) * 4 + (3 - kx)];
        }
    }
    out[idx] = acc;
}

// ---------------------------------------------------------------------------
extern "C" void kernel_launch(void* const* d_in, const int* in_sizes, int n_in,
                              void* d_out, int out_size, void* d_ws, size_t ws_size,
                              hipStream_t stream) {
    const float* x      = (const float*)d_in[0];
    const float* w_off1 = (const float*)d_in[1];
    const float* b_off1 = (const float*)d_in[2];
    const float* w1     = (const float*)d_in[3];
    const float* b1     = (const float*)d_in[4];
    const float* g1v    = (const float*)d_in[5];
    const float* be1    = (const float*)d_in[6];
    const float* m1     = (const float*)d_in[7];
    const float* v1     = (const float*)d_in[8];
    const float* w_up   = (const float*)d_in[9];
    const float* w_off2 = (const float*)d_in[10];
    const float* b_off2 = (const float*)d_in[11];
    const float* w2     = (const float*)d_in[12];
    const float* b2     = (const float*)d_in[13];
    const float* g2v    = (const float*)d_in[14];
    const float* be2    = (const float*)d_in[15];
    const float* m2     = (const float*)d_in[16];
    const float* v2     = (const float*)d_in[17];

    float* ws  = (float*)d_ws;
    float* om1 = ws;                     // 4*27*4096   =   442368 f
    float* y1  = om1 + 442368;           // 4*128*4096  =  2097152 f
    float* up  = y1 + 2097152;           // 4*128*16384 =  8388608 f
    float* om2 = up + 8388608;           // 4*27*16384  =  1769472 f
    float* outf = (float*)d_out;

    // `up` region (dead until upsample writes it): w1 + w_off1 splits
    ushort* w1hi  = (ushort*)up;         // 294912
    ushort* w1lo  = w1hi + 294912;       // 294912
    ushort* wo1hi = w1lo + 294912;       // 32*2304 = 73728
    ushort* wo1lo = wo1hi + 73728;       // 73728
    // `y1` region (dead after upsample reads it): w2 + w_off2 splits
    ushort* w2hi  = (ushort*)y1;         // 147456
    ushort* w2lo  = w2hi + 147456;       // 147456
    ushort* wo2hi = w2lo + 147456;       // 32*1152 = 36864
    ushort* wo2lo = wo2hi + 36864;       // 36864

    // prep: w1 (dcn1) + w_off1 (conv1) splits, fragment order
    wsplit_perm_kernel<<<(294912 + 255) / 256, 256, 0, stream>>>(
        w1, w1hi, w1lo, 256, 294912);
    wsplit_perm_conv_kernel<<<(73728 + 255) / 256, 256, 0, stream>>>(
        w_off1, wo1hi, wo1lo, 256, 73728);

    // om1 = conv3x3(x, w_off1) + b_off1 — MFMA, POS=16, KWAVES=4
    // grid 4*(4096/16)=1024, 256 thr; LDS: 1152 + 20480 = 21632
    conv_mfma_kernel<256, 64, 64, 16, 4, 4>
        <<<1024, 256, 21632, stream>>>(x, wo1hi, wo1lo, b_off1, om1);

    // y1 = bn_relu(dcn1) — MFMA, POS=32, 4-way K-split
    // LDS: 1152 + 4608 + 1024 + 40960 = 47744
    dcn_mfma_kernel<256, 64, 64, 32, 4, 4, false, false>
        <<<4 * (4096 / 32), 512, 47744, stream>>>(
        x, om1, om1, w1hi, w1lo, b1, g1v, be1, m1, v1, y1);
    // up = depthwise transposed upsample (clobbers w1/wo1 splits — now dead)
    upsample_kernel<<<8388608 / 256, 256, 0, stream>>>(y1, w_up, up);

    // prep: w2 (dcn2) + w_off2 (conv2) splits (y1 now dead)
    wsplit_perm_kernel<<<(147456 + 255) / 256, 256, 0, stream>>>(
        w2, w2hi, w2lo, 128, 147456);
    wsplit_perm_conv_kernel<<<(36864 + 255) / 256, 256, 0, stream>>>(
        w_off2, wo2hi, wo2lo, 128, 36864);

    // om2 = conv3x3(up, w_off2) + b_off2 — MFMA, POS=64, KWAVES=1
    // grid 4*(16384/64)=1024, 256 thr; LDS: 4608 + 20480 = 25088
    conv_mfma_kernel<128, 128, 128, 64, 1, 4>
        <<<1024, 256, 25088, stream>>>(up, wo2hi, wo2lo, b_off2, om2);

    // out = bn_relu(dcn2) — MFMA, POS=64, A-staged, single-S pipeline
    // LDS: 2304 + 9216 + 1024 + 16384 + 10240 = 39168 -> 4 blocks/CU
    dcn_mfma_kernel<128, 128, 128, 64, 1, 4, true, false>
        <<<4 * (16384 / 64), 256, 39168, stream>>>(
        up, om2, om2, w2hi, w2lo, b2, g2v, be2, m2, v2, outf);
}

// Round 13
// 382.183 us; speedup vs baseline: 3.5159x; 1.0366x over previous
//
#include <hip/hip_runtime.h>
#include <hip/hip_bf16.h>
#include <cmath>

// ---------------------------------------------------------------------------
// Pipeline: y1 = bn_relu(dcn(x, w_off1, b_off1, w1, b1))        (4,128,64,64)
//           up = up_depthwise(y1, w_up, f=2)                    (4,128,128,128)
//           out = bn_relu(dcn(up, w_off2, b_off2, w2, b2))      (4,128,128,128)
// ALL GEMM-shaped work (both DCNs AND both offset convs) on
// mfma_f32_16x16x32_bf16 with split-bf16 (hi/lo, 3 products).
// R13: pack via v_cvt_pk_bf16_f32 (6 ops/pair vs ~20 bit-twiddled);
//      s_setprio(1) around MFMA clusters (T5 — phase-split regime).
// conv_off -> conv_mfma: M=27 padded to 32, tap-sampler B.
// dcn2 (ASTAGE): single-S alternating-phase pipeline (R11).
// Weights pre-permuted into per-chunk fragment order (coalesced A loads).
// Workspace: om1 | y1 | up | om2 ; w1+wo1 splits parked in `up`,
// w2+wo2 splits parked in `y1`.
// ---------------------------------------------------------------------------

#define EPSV 1e-5f

typedef __attribute__((ext_vector_type(8))) short short8;
typedef __attribute__((ext_vector_type(4))) float f32x4;

__device__ __forceinline__ ushort f2bf(float f) {
    union { float f; uint u; } v; v.f = f;
    const uint r = v.u + 0x7fffu + ((v.u >> 16) & 1u);   // RNE
    return (ushort)(r >> 16);
}
__device__ __forceinline__ float bf2f(ushort h) {
    union { uint u; float f; } v; v.u = ((uint)h) << 16;
    return v.f;
}
__device__ __forceinline__ float2 ld2u(const float* p) {
    float2 v; __builtin_memcpy(&v, p, sizeof(float2)); return v;
}
// packed bf16 RNE convert: dst.lo = bf16(a), dst.hi = bf16(b)
__device__ __forceinline__ uint cvtpk_bf16(float a, float b) {
    uint r;
    asm("v_cvt_pk_bf16_f32 %0, %1, %2" : "=v"(r) : "v"(a), "v"(b));
    return r;
}

// ---- pack 8 fp32 -> bf16 hi/lo rows of S (cvt_pk fast path) ----------------
template <int KS>
__device__ __forceinline__ void pack_store8(
    const float* s, ushort* __restrict__ Shi, ushort* __restrict__ Slo,
    int pp, int j0)
{
    uint hw[4], lw[4];
#pragma unroll
    for (int q = 0; q < 4; ++q) {
        const float s0 = s[2 * q], s1 = s[2 * q + 1];
        const uint h = cvtpk_bf16(s0, s1);
        union { uint u; float f; } h0, h1;
        h0.u = h << 16;
        h1.u = h & 0xffff0000u;
        hw[q] = h;
        lw[q] = cvtpk_bf16(s0 - h0.f, s1 - h1.f);
    }
    uint4 hv; hv.x = hw[0]; hv.y = hw[1]; hv.z = hw[2]; hv.w = hw[3];
    uint4 lv; lv.x = lw[0]; lv.y = lw[1]; lv.z = lw[2]; lv.w = lw[3];
    *(uint4*)&Shi[pp * KS + j0] = hv;
    *(uint4*)&Slo[pp * KS + j0] = lv;
}

// ------- weight split: fp32 -> bf16 hi/lo in per-chunk FRAGMENT order -------
// dst[((ch*8 + mt)*64 + lane)*8 + j] = w[co][k], k = c*9+k9 (channel-major),
// ch = k>>5, kq = (k&31)>>3, j = k&7, mt = co>>4, lane = (co&15) | (kq<<4).
__global__ __launch_bounds__(256) void wsplit_perm_kernel(
    const float* __restrict__ w, ushort* __restrict__ hi,
    ushort* __restrict__ lo, int cin, int n)
{
    const int i = blockIdx.x * 256 + threadIdx.x;
    if (i >= n) return;
    const int cin9 = cin * 9;
    const int co = i / cin9;
    const int k  = i - co * cin9;            // channel-major K index
    const int ch = k >> 5;
    const int kq = (k & 31) >> 3;
    const int j  = k & 7;
    const int mt = co >> 4;
    const int lane = (co & 15) | (kq << 4);
    const size_t dst = ((size_t)(ch * 8 + mt) * 64 + lane) * 8 + j;
    const float f = w[i];
    const ushort h = f2bf(f);
    hi[dst] = h;
    lo[dst] = f2bf(f - bf2f(h));
}

// ------- conv weight split: (27,CIN,3,3) -> M=32 zero-padded frag order -----
__global__ __launch_bounds__(256) void wsplit_perm_conv_kernel(
    const float* __restrict__ w, ushort* __restrict__ hi,
    ushort* __restrict__ lo, int cin, int n)   // n = 32*cin*9
{
    const int i = blockIdx.x * 256 + threadIdx.x;
    if (i >= n) return;
    const int cin9 = cin * 9;
    const int co = i / cin9;
    const int k  = i - co * cin9;
    const int ch = k >> 5;
    const int kq = (k & 31) >> 3;
    const int j  = k & 7;
    const int mt = co >> 4;
    const int lane = (co & 15) | (kq << 4);
    const size_t dst = ((size_t)(ch * 2 + mt) * 64 + lane) * 8 + j;
    const float f = (co < 27) ? w[(size_t)co * cin9 + k] : 0.f;
    const ushort h = f2bf(f);
    hi[dst] = h;
    lo[dst] = f2bf(f - bf2f(h));
}

// ---------------- offset conv on MFMA: 3x3, pad 1, 27(->32) outputs ---------
template <int CIN, int HH, int WW, int POS, int KS>
__device__ __forceinline__ void conv_sample_chunk(
    const float* __restrict__ xb, const uint* __restrict__ toff,
    const float* __restrict__ twt, ushort* __restrict__ Shi,
    ushort* __restrict__ Slo, int tt, int kbase)
{
    constexpr int HW = HH * WW;
    const int pp = tt & (POS - 1);
    const int j0 = (tt / POS) * 8;
    float s[8];
#pragma unroll
    for (int j = 0; j < 8; ++j) {
        const int kg = kbase + j0 + j;
        const int c  = (kg * 7282) >> 16;       // /9 (exact for kg<2304)
        const int k9 = kg - c * 9;
        const int ei = k9 * POS + pp;
        s[j] = xb[(size_t)c * HW + toff[ei]] * twt[ei];
    }
    pack_store8<KS>(s, Shi, Slo, pp, j0);
}

template <int CIN, int HH, int WW, int POS, int KWAVES, int MINW>
__global__ __launch_bounds__((POS / 16) * KWAVES * 64, MINW) void conv_mfma_kernel(
    const float* __restrict__ in,    // (B, CIN, HH, WW)
    const ushort* __restrict__ whi,  // (32, CIN*9) frag order, zero-padded
    const ushort* __restrict__ wlo,
    const float* __restrict__ bias,  // (27)
    float* __restrict__ om)          // (B, 27, HH*WW)
{
    constexpr int HW   = HH * WW;
    constexpr int K    = CIN * 9;
    constexpr int NPQ  = POS / 16;
    constexpr int NT   = NPQ * KWAVES * 64;
    constexpr int KC   = 32;
    constexpr int KS   = 40;
    constexpr int NCHT = K / KC;
    constexpr int NCH  = NCHT / KWAVES;
    constexpr int SBUF = POS * KS;

    extern __shared__ __align__(16) char smem[];
    uint*   toff  = (uint*)smem;              // 9*POS
    float*  twt   = (float*)(toff + 9 * POS); // 9*POS
    ushort* Sbase = (ushort*)(twt + 9 * POS);

    const int tid = threadIdx.x;
    const int nt  = HW / POS;
    const int cpx = gridDim.x >> 3;
    const int bid = (blockIdx.x & 7) * cpx + (blockIdx.x >> 3);
    const int b   = bid / nt;
    const int p0  = (bid - b * nt) * POS;

    for (int i = tid; i < 9 * POS; i += NT) {
        const int k9 = i / POS, pp = i - k9 * POS;
        const int p  = p0 + pp;
        const int yy = p / WW, xx = p - yy * WW;
        const int ky = (k9 * 11) >> 5, kx = k9 - ky * 3;
        const int iy = yy + ky - 1, ix = xx + kx - 1;
        const bool v = (iy >= 0) && (iy < HH) && (ix >= 0) && (ix < WW);
        const int cy = min(max(iy, 0), HH - 1);
        const int cx = min(max(ix, 0), WW - 1);
        toff[i] = (uint)(cy * WW + cx);
        twt[i]  = v ? 1.f : 0.f;
    }
    __syncthreads();

    const float* xb = in + (size_t)b * CIN * HW;
    const int lane = tid & 63;
    const int w    = tid >> 6;
    const int wq   = w & (NPQ - 1);
    const int kgid = w / NPQ;
    const int tt   = tid & (NPQ * 64 - 1);
    ushort* S00 = Sbase + kgid * (4 * SBUF);

    f32x4 acc[2];
    acc[0] = (f32x4){0.f, 0.f, 0.f, 0.f};
    acc[1] = (f32x4){0.f, 0.f, 0.f, 0.f};
    const int mrow = lane & 15;
    const int kq   = lane >> 4;

    conv_sample_chunk<CIN, HH, WW, POS, KS>(xb, toff, twt, S00, S00 + SBUF,
                                            tt, kgid * NCH * KC);
    __syncthreads();

    for (int ch = 0; ch < NCH; ++ch) {
        const int cur = ch & 1;
        ushort* Sc = S00 + (cur * 2) * SBUF;
        const int boff = (wq * 16 + mrow) * KS + kq * 8;
        const short8 bh = *(const short8*)&Sc[boff];
        const short8 bl = *(const short8*)&Sc[SBUF + boff];
        if (ch + 1 < NCH) {
            ushort* Sn = S00 + ((cur ^ 1) * 2) * SBUF;
            conv_sample_chunk<CIN, HH, WW, POS, KS>(xb, toff, twt,
                                                    Sn, Sn + SBUF, tt,
                                                    (kgid * NCH + ch + 1) * KC);
        }
        const size_t abase = (size_t)((kgid * NCH + ch) * 2) * 512;
        __builtin_amdgcn_s_setprio(1);
#pragma unroll
        for (int mt = 0; mt < 2; ++mt) {
            const size_t ao = abase + (size_t)((mt * 64 + lane) * 8);
            const short8 ah = *(const short8*)(whi + ao);
            const short8 al = *(const short8*)(wlo + ao);
            acc[mt] = __builtin_amdgcn_mfma_f32_16x16x32_bf16(al, bh, acc[mt], 0, 0, 0);
            acc[mt] = __builtin_amdgcn_mfma_f32_16x16x32_bf16(ah, bl, acc[mt], 0, 0, 0);
            acc[mt] = __builtin_amdgcn_mfma_f32_16x16x32_bf16(ah, bh, acc[mt], 0, 0, 0);
        }
        __builtin_amdgcn_s_setprio(0);
        __syncthreads();
    }

    const int pcolb = wq * 16 + mrow;
    constexpr int RS = POS + 1;
    constexpr int SL = 32 * RS;
    float* red = (float*)Sbase;

    if constexpr (KWAVES == 4) {
        if (kgid >= 2) {
#pragma unroll
            for (int mt = 0; mt < 2; ++mt)
#pragma unroll
                for (int r = 0; r < 4; ++r) {
                    const int co = mt * 16 + kq * 4 + r;
                    red[(kgid - 2) * SL + co * RS + pcolb] = acc[mt][r];
                }
        }
        __syncthreads();
        if (kgid < 2) {
#pragma unroll
            for (int mt = 0; mt < 2; ++mt)
#pragma unroll
                for (int r = 0; r < 4; ++r) {
                    const int co = mt * 16 + kq * 4 + r;
                    acc[mt][r] += red[kgid * SL + co * RS + pcolb];
                }
        }
        __syncthreads();
        if (kgid == 1) {
#pragma unroll
            for (int mt = 0; mt < 2; ++mt)
#pragma unroll
                for (int r = 0; r < 4; ++r) {
                    const int co = mt * 16 + kq * 4 + r;
                    red[co * RS + pcolb] = acc[mt][r];
                }
        }
        __syncthreads();
        if (kgid == 0) {
#pragma unroll
            for (int mt = 0; mt < 2; ++mt)
#pragma unroll
                for (int r = 0; r < 4; ++r) {
                    const int co = mt * 16 + kq * 4 + r;
                    acc[mt][r] += red[co * RS + pcolb];
                }
        }
    } else if constexpr (KWAVES == 2) {
        if (kgid == 1) {
#pragma unroll
            for (int mt = 0; mt < 2; ++mt)
#pragma unroll
                for (int r = 0; r < 4; ++r) {
                    const int co = mt * 16 + kq * 4 + r;
                    red[co * RS + pcolb] = acc[mt][r];
                }
        }
        __syncthreads();
        if (kgid == 0) {
#pragma unroll
            for (int mt = 0; mt < 2; ++mt)
#pragma unroll
                for (int r = 0; r < 4; ++r) {
                    const int co = mt * 16 + kq * 4 + r;
                    acc[mt][r] += red[co * RS + pcolb];
                }
        }
    }

    if (kgid == 0) {
        float* ob = om + (size_t)b * 27 * HW + p0 + pcolb;
#pragma unroll
        for (int mt = 0; mt < 2; ++mt)
#pragma unroll
            for (int r = 0; r < 4; ++r) {
                const int co = mt * 16 + kq * 4 + r;
                if (co < 27)
                    ob[(size_t)co * HW] = acc[mt][r] + bias[co];
            }
    }
}

// ---------------- paired sampler: issue / finish ----------------------------
template <int CIN, int HH, int WW, int POS>
__device__ __forceinline__ void sample_issue(
    const float* __restrict__ xb, const uint* __restrict__ eoff2,
    float2* v0, float2* v1, int tt, int kbase)
{
    constexpr int HW = HH * WW;
    const int pp = tt & (POS - 1);
    const int j0 = (tt / POS) * 8;
#pragma unroll
    for (int j = 0; j < 8; ++j) {
        const int kg = kbase + j0 + j;
        const int c  = (kg * 7282) >> 16;       // /9 (exact for kg<2304)
        const int k9 = kg - c * 9;
        const uint e = eoff2[k9 * POS + pp];
        const float* chp = xb + (size_t)c * HW;
        v0[j] = ld2u(chp + (e & 0xffffu));
        v1[j] = ld2u(chp + (e >> 16));
    }
}

template <int CIN, int HH, int WW, int POS, int KS>
__device__ __forceinline__ void sample_finish(
    const float4* __restrict__ ewt, const float2* v0, const float2* v1,
    ushort* __restrict__ Shi, ushort* __restrict__ Slo, int tt, int kbase)
{
    const int pp = tt & (POS - 1);
    const int j0 = (tt / POS) * 8;
    float s[8];
#pragma unroll
    for (int j = 0; j < 8; ++j) {
        const int kg = kbase + j0 + j;
        const int c  = (kg * 7282) >> 16;
        const int k9 = kg - c * 9;
        const float4 wv = ewt[k9 * POS + pp];
        s[j] = v0[j].x * wv.x + v0[j].y * wv.y
             + v1[j].x * wv.z + v1[j].y * wv.w;
    }
    pack_store8<KS>(s, Shi, Slo, pp, j0);
}

template <int CIN, int HH, int WW, int POS, int KS>
__device__ __forceinline__ void sample_chunk(
    const float* __restrict__ xb, const uint* __restrict__ eoff2,
    const float4* __restrict__ ewt, ushort* __restrict__ Shi,
    ushort* __restrict__ Slo, int tt, int kbase)
{
    float2 v0[8], v1[8];
    sample_issue<CIN, HH, WW, POS>(xb, eoff2, v0, v1, tt, kbase);
    sample_finish<CIN, HH, WW, POS, KS>(ewt, v0, v1, Shi, Slo, tt, kbase);
}

// ---------------- fused DCN on MFMA: sample + GEMM + bias + BN + ReLU -------
template <int CIN, int HH, int WW, int POS, int KWAVES, int MINW,
          bool ASTAGE, bool OMS>
__global__ __launch_bounds__((POS / 16) * KWAVES * 64, MINW) void dcn_mfma_kernel(
    const float* __restrict__ xin,   // (B, CIN, HH, WW)
    const float* __restrict__ om,    // (B, 27, HH, WW)
    const float* __restrict__ omB,   // partial (OMS only)
    const ushort* __restrict__ whi,  // (128, K) bf16 hi, fragment order
    const ushort* __restrict__ wlo,  // (128, K) bf16 lo, fragment order
    const float* __restrict__ bias,
    const float* __restrict__ gam, const float* __restrict__ bet,
    const float* __restrict__ mu,  const float* __restrict__ var,
    float* __restrict__ out)         // (B, 128, HH*WW)
{
    constexpr int HW   = HH * WW;
    constexpr int K    = CIN * 9;
    constexpr int NPQ  = POS / 16;
    constexpr int NT   = NPQ * KWAVES * 64;
    constexpr int KC   = 32;
    constexpr int KS   = 40;
    constexpr int NCHT = K / KC;
    constexpr int NCH  = NCHT / KWAVES;
    constexpr int SBUF = POS * KS;
    constexpr int ABN  = ASTAGE ? 8192 : 0;
    constexpr int SN   = ASTAGE ? 2 * SBUF : KWAVES * 4 * SBUF;

    extern __shared__ __align__(16) char smem[];
    uint*    eoff2 = (uint*)smem;
    float4*  ewt   = (float4*)(eoff2 + 9 * POS);
    float*   invp  = (float*)(ewt + 9 * POS);
    float*   shp   = invp + 128;
    ushort*  Abuf  = (ushort*)(shp + 128);
    ushort*  Sbase = Abuf + ABN;
    (void)SN;

    const int tid = threadIdx.x;
    const int nt  = HW / POS;
    const int cpx = gridDim.x >> 3;
    const int bid = (blockIdx.x & 7) * cpx + (blockIdx.x >> 3);
    const int b   = bid / nt;
    const int p0  = (bid - b * nt) * POS;

    const float* omb  = om + (size_t)b * 27 * HW;
    const float* ombB = OMS ? (omB + (size_t)b * 27 * HW) : nullptr;
    for (int i = tid; i < 9 * POS; i += NT) {
        const int k9 = i / POS, pp = i - k9 * POS;
        const int p  = p0 + pp;
        const int yy = p / WW;
        const int xx = p - yy * WW;
        float oy = omb[(size_t)k9 * HW + p];
        float ox = omb[(size_t)(9 + k9) * HW + p];
        float mv = omb[(size_t)(18 + k9) * HW + p];
        if constexpr (OMS) {
            oy += ombB[(size_t)k9 * HW + p];
            ox += ombB[(size_t)(9 + k9) * HW + p];
            mv += ombB[(size_t)(18 + k9) * HW + p];
        }
        const float m  = 1.0f / (1.0f + expf(-mv));
        const int ky = (k9 * 11) >> 5;
        const int kx = k9 - ky * 3;
        const float py = (float)(yy + ky - 1) + oy;
        const float px = (float)(xx + kx - 1) + ox;
        const float y0f = floorf(py), x0f = floorf(px);
        const int   y0  = (int)y0f,  x0 = (int)x0f;
        const int by0 = min(max(y0, 0), HH - 1);
        const int by1 = min(max(y0 + 1, 0), HH - 1);
        const int bx  = min(max(x0, 0), WW - 2);
        const float wy1 = py - y0f, wx1 = px - x0f;
        const float fy0 = (y0 >= 0  && y0 < HH)     ? (1.f - wy1) * m : 0.f;
        const float fy1 = (y0 >= -1 && y0 < HH - 1) ? wy1 * m         : 0.f;
        const float fx0v = 1.f - wx1, fx1v = wx1;
        float gx0 = 0.f, gx1 = 0.f;
        if (x0 >= 0 && x0 < WW)         { if (x0 == bx)     gx0 += fx0v; else gx1 += fx0v; }
        if (x0 + 1 >= 0 && x0 + 1 < WW) { if (x0 + 1 == bx) gx0 += fx1v; else gx1 += fx1v; }
        eoff2[i] = (uint)(by0 * WW + bx) | ((uint)(by1 * WW + bx) << 16);
        float4 wv; wv.x = fy0 * gx0; wv.y = fy0 * gx1;
                   wv.z = fy1 * gx0; wv.w = fy1 * gx1;
        ewt[i] = wv;
    }
    for (int i = tid; i < 128; i += NT) {
        const float iv = gam[i] * rsqrtf(var[i] + EPSV);
        invp[i] = iv;
        shp[i]  = bet[i] - mu[i] * iv + bias[i] * iv;
    }
    __syncthreads();

    const float* xb   = xin + (size_t)b * CIN * HW;
    const int lane = tid & 63;
    const int w    = tid >> 6;
    const int wq   = w & (NPQ - 1);
    const int kgid = w / NPQ;
    const int tt   = tid & (NPQ * 64 - 1);

    f32x4 acc[8];
#pragma unroll
    for (int mt = 0; mt < 8; ++mt) acc[mt] = (f32x4){0.f, 0.f, 0.f, 0.f};

    const int mrow = lane & 15;
    const int kq   = lane >> 4;

    if constexpr (ASTAGE) {
        // ===== single-S-buffer alternating-phase pipeline =====
        ushort* Shi = Sbase;
        ushort* Slo = Sbase + SBUF;
        float2 v0[8], v1[8];
        sample_chunk<CIN, HH, WW, POS, KS>(xb, eoff2, ewt, Shi, Slo, tt, 0);
        {
#pragma unroll
            for (int t = 0; t < 1024 / NT; ++t) {
                const int u = tid + t * NT;
                const ushort* srcp = (u < 512)
                    ? (whi + (size_t)u * 8)
                    : (wlo + (size_t)(u - 512) * 8);
                *(short8*)&Abuf[(size_t)u * 8] = *(const short8*)srcp;
            }
        }
        if (NCH > 1)
            sample_issue<CIN, HH, WW, POS>(xb, eoff2, v0, v1, tt, KC);
        asm volatile("s_waitcnt lgkmcnt(0)" ::: "memory");
        __builtin_amdgcn_s_barrier();
        __builtin_amdgcn_sched_barrier(0);

        for (int ch = 0; ch < NCH; ++ch) {
            const int boff = (wq * 16 + mrow) * KS + kq * 8;
            const short8 bh = *(const short8*)&Shi[boff];
            const short8 bl = *(const short8*)&Slo[boff];
            __builtin_amdgcn_s_setprio(1);
#pragma unroll
            for (int mt = 0; mt < 8; ++mt) {
                const int au = (mt * 64 + lane) * 8;
                const short8 ah = *(const short8*)&Abuf[au];
                const short8 al = *(const short8*)&Abuf[4096 + au];
                acc[mt] = __builtin_amdgcn_mfma_f32_16x16x32_bf16(al, bh, acc[mt], 0, 0, 0);
                acc[mt] = __builtin_amdgcn_mfma_f32_16x16x32_bf16(ah, bl, acc[mt], 0, 0, 0);
                acc[mt] = __builtin_amdgcn_mfma_f32_16x16x32_bf16(ah, bh, acc[mt], 0, 0, 0);
            }
            __builtin_amdgcn_s_setprio(0);
            if (ch + 1 < NCH) {
                asm volatile("s_waitcnt lgkmcnt(0)" ::: "memory");
                __builtin_amdgcn_s_barrier();
                __builtin_amdgcn_sched_barrier(0);
                const size_t wb = (size_t)(ch + 1) * 4096;
#pragma unroll
                for (int t = 0; t < 1024 / NT; ++t) {
                    const int u = tid + t * NT;
                    const ushort* srcp = (u < 512)
                        ? (whi + wb + (size_t)u * 8)
                        : (wlo + wb + (size_t)(u - 512) * 8);
                    *(short8*)&Abuf[(size_t)u * 8] = *(const short8*)srcp;
                }
                sample_finish<CIN, HH, WW, POS, KS>(ewt, v0, v1, Shi, Slo,
                                                    tt, (ch + 1) * KC);
                if (ch + 2 < NCH)
                    sample_issue<CIN, HH, WW, POS>(xb, eoff2, v0, v1, tt,
                                                   (ch + 2) * KC);
                asm volatile("s_waitcnt lgkmcnt(0)" ::: "memory");
                __builtin_amdgcn_s_barrier();
                __builtin_amdgcn_sched_barrier(0);
            }
        }
    } else {
        ushort* S00 = Sbase + kgid * (4 * SBUF);
        sample_chunk<CIN, HH, WW, POS, KS>(xb, eoff2, ewt, S00, S00 + SBUF,
                                           tt, kgid * NCH * KC);
        __syncthreads();

        for (int ch = 0; ch < NCH; ++ch) {
            const int cur = ch & 1;
            ushort* Sc = S00 + (cur * 2) * SBUF;
            const int boff = (wq * 16 + mrow) * KS + kq * 8;
            const short8 bh = *(const short8*)&Sc[boff];
            const short8 bl = *(const short8*)&Sc[SBUF + boff];
            if (ch + 1 < NCH) {
                ushort* Sn = S00 + ((cur ^ 1) * 2) * SBUF;
                sample_chunk<CIN, HH, WW, POS, KS>(xb, eoff2, ewt,
                                                   Sn, Sn + SBUF, tt,
                                                   (kgid * NCH + ch + 1) * KC);
            }
            const size_t abase = (size_t)((kgid * NCH + ch) * 8) * 512;
            __builtin_amdgcn_s_setprio(1);
#pragma unroll
            for (int mt = 0; mt < 8; ++mt) {
                const size_t ao = abase + (size_t)((mt * 64 + lane) * 8);
                const short8 ah = *(const short8*)(whi + ao);
                const short8 al = *(const short8*)(wlo + ao);
                acc[mt] = __builtin_amdgcn_mfma_f32_16x16x32_bf16(al, bh, acc[mt], 0, 0, 0);
                acc[mt] = __builtin_amdgcn_mfma_f32_16x16x32_bf16(ah, bl, acc[mt], 0, 0, 0);
                acc[mt] = __builtin_amdgcn_mfma_f32_16x16x32_bf16(ah, bh, acc[mt], 0, 0, 0);
            }
            __builtin_amdgcn_s_setprio(0);
            __syncthreads();
        }
    }

    const int pcolb = wq * 16 + mrow;
    constexpr int RS = POS + 1;
    constexpr int SL = 128 * RS;
    float* red = (float*)Sbase;

    if constexpr (KWAVES == 4) {
        if (kgid >= 2) {
#pragma unroll
            for (int mt = 0; mt < 8; ++mt)
#pragma unroll
                for (int r = 0; r < 4; ++r) {
                    const int co = mt * 16 + kq * 4 + r;
                    red[(kgid - 2) * SL + co * RS + pcolb] = acc[mt][r];
                }
        }
        __syncthreads();
        if (kgid < 2) {
#pragma unroll
            for (int mt = 0; mt < 8; ++mt)
#pragma unroll
                for (int r = 0; r < 4; ++r) {
                    const int co = mt * 16 + kq * 4 + r;
                    acc[mt][r] += red[kgid * SL + co * RS + pcolb];
                }
        }
        __syncthreads();
        if (kgid == 1) {
#pragma unroll
            for (int mt = 0; mt < 8; ++mt)
#pragma unroll
                for (int r = 0; r < 4; ++r) {
                    const int co = mt * 16 + kq * 4 + r;
                    red[co * RS + pcolb] = acc[mt][r];
                }
        }
        __syncthreads();
        if (kgid == 0) {
#pragma unroll
            for (int mt = 0; mt < 8; ++mt)
#pragma unroll
                for (int r = 0; r < 4; ++r) {
                    const int co = mt * 16 + kq * 4 + r;
                    acc[mt][r] += red[co * RS + pcolb];
                }
        }
    } else if constexpr (KWAVES == 2) {
        if (kgid == 1) {
#pragma unroll
            for (int mt = 0; mt < 8; ++mt)
#pragma unroll
                for (int r = 0; r < 4; ++r) {
                    const int co = mt * 16 + kq * 4 + r;
                    red[co * RS + pcolb] = acc[mt][r];
                }
        }
        __syncthreads();
        if (kgid == 0) {
#pragma unroll
            for (int mt = 0; mt < 8; ++mt)
#pragma unroll
                for (int r = 0; r < 4; ++r) {
                    const int co = mt * 16 + kq * 4 + r;
                    acc[mt][r] += red[co * RS + pcolb];
                }
        }
    }

    if (kgid == 0) {
        float* outb = out + (size_t)b * 128 * HW + p0 + pcolb;
#pragma unroll
        for (int mt = 0; mt < 8; ++mt)
#pragma unroll
            for (int r = 0; r < 4; ++r) {
                const int co = mt * 16 + kq * 4 + r;
                outb[(size_t)co * HW] = fmaxf(acc[mt][r] * invp[co] + shp[co], 0.f);
            }
    }
}

// ---------------- depthwise transposed-conv upsample x2 (k=4, pad 2) --------
__global__ __launch_bounds__(256) void upsample_kernel(
    const float* __restrict__ y,    // (4,128,64,64)
    const float* __restrict__ wup,  // (128,1,4,4)
    float* __restrict__ out)        // (4,128,128,128)
{
    const int idx = blockIdx.x * 256 + threadIdx.x;
    const int ox = idx & 127;
    const int oy = (idx >> 7) & 127;
    const int c  = (idx >> 14) & 127;
    const int b  = idx >> 21;

    const float* yc = y + (size_t)(b * 128 + c) * 4096;
    const float* wc = wup + c * 16;

    float acc = 0.f;
#pragma unroll
    for (int ky = 0; ky < 4; ++ky) {
        const int qy = oy + ky - 2;
        if (qy & 1) continue;
        const int iy = qy >> 1;
        if (iy < 0 || iy >= 64) continue;
#pragma unroll
        for (int kx = 0; kx < 4; ++kx) {
            const int qx = ox + kx - 2;
            if (qx & 1) continue;
            const int ix = qx >> 1;
            if (ix < 0 || ix >= 64) continue;
            acc += yc[iy * 64 + ix] * wc[(3 - ky) * 4 + (3 - kx)];
        }
    }
    out[idx] = acc;
}

// ---------------------------------------------------------------------------
extern "C" void kernel_launch(void* const* d_in, const int* in_sizes, int n_in,
                              void* d_out, int out_size, void* d_ws, size_t ws_size,
                              hipStream_t stream) {
    const float* x      = (const float*)d_in[0];
    const float* w_off1 = (const float*)d_in[1];
    const float* b_off1 = (const float*)d_in[2];
    const float* w1     = (const float*)d_in[3];
    const float* b1     = (const float*)d_in[4];
    const float* g1v    = (const float*)d_in[5];
    const float* be1    = (const float*)d_in[6];
    const float* m1     = (const float*)d_in[7];
    const float* v1     = (const float*)d_in[8];
    const float* w_up   = (const float*)d_in[9];
    const float* w_off2 = (const float*)d_in[10];
    const float* b_off2 = (const float*)d_in[11];
    const float* w2     = (const float*)d_in[12];
    const float* b2     = (const float*)d_in[13];
    const float* g2v    = (const float*)d_in[14];
    const float* be2    = (const float*)d_in[15];
    const float* m2     = (const float*)d_in[16];
    const float* v2     = (const float*)d_in[17];

    float* ws  = (float*)d_ws;
    float* om1 = ws;                     // 4*27*4096   =   442368 f
    float* y1  = om1 + 442368;           // 4*128*4096  =  2097152 f
    float* up  = y1 + 2097152;           // 4*128*16384 =  8388608 f
    float* om2 = up + 8388608;           // 4*27*16384  =  1769472 f
    float* outf = (float*)d_out;

    // `up` region (dead until upsample writes it): w1 + w_off1 splits
    ushort* w1hi  = (ushort*)up;         // 294912
    ushort* w1lo  = w1hi + 294912;       // 294912
    ushort* wo1hi = w1lo + 294912;       // 32*2304 = 73728
    ushort* wo1lo = wo1hi + 73728;       // 73728
    // `y1` region (dead after upsample reads it): w2 + w_off2 splits
    ushort* w2hi  = (ushort*)y1;         // 147456
    ushort* w2lo  = w2hi + 147456;       // 147456
    ushort* wo2hi = w2lo + 147456;       // 32*1152 = 36864
    ushort* wo2lo = wo2hi + 36864;       // 36864

    // prep: w1 (dcn1) + w_off1 (conv1) splits, fragment order
    wsplit_perm_kernel<<<(294912 + 255) / 256, 256, 0, stream>>>(
        w1, w1hi, w1lo, 256, 294912);
    wsplit_perm_conv_kernel<<<(73728 + 255) / 256, 256, 0, stream>>>(
        w_off1, wo1hi, wo1lo, 256, 73728);

    // om1 = conv3x3(x, w_off1) + b_off1 — MFMA, POS=16, KWAVES=4
    conv_mfma_kernel<256, 64, 64, 16, 4, 4>
        <<<1024, 256, 21632, stream>>>(x, wo1hi, wo1lo, b_off1, om1);

    // y1 = bn_relu(dcn1) — MFMA, POS=32, 4-way K-split
    dcn_mfma_kernel<256, 64, 64, 32, 4, 4, false, false>
        <<<4 * (4096 / 32), 512, 47744, stream>>>(
        x, om1, om1, w1hi, w1lo, b1, g1v, be1, m1, v1, y1);
    // up = depthwise transposed upsample (clobbers w1/wo1 splits — now dead)
    upsample_kernel<<<8388608 / 256, 256, 0, stream>>>(y1, w_up, up);

    // prep: w2 (dcn2) + w_off2 (conv2) splits (y1 now dead)
    wsplit_perm_kernel<<<(147456 + 255) / 256, 256, 0, stream>>>(
        w2, w2hi, w2lo, 128, 147456);
    wsplit_perm_conv_kernel<<<(36864 + 255) / 256, 256, 0, stream>>>(
        w_off2, wo2hi, wo2lo, 128, 36864);

    // om2 = conv3x3(up, w_off2) + b_off2 — MFMA, POS=64, KWAVES=1
    conv_mfma_kernel<128, 128, 128, 64, 1, 4>
        <<<1024, 256, 25088, stream>>>(up, wo2hi, wo2lo, b_off2, om2);

    // out = bn_relu(dcn2) — MFMA, POS=64, A-staged, single-S pipeline
    dcn_mfma_kernel<128, 128, 128, 64, 1, 4, true, false>
        <<<4 * (16384 / 64), 256, 39168, stream>>>(
        up, om2, om2, w2hi, w2lo, b2, g2v, be2, m2, v2, outf);
}

// Round 14
// 366.804 us; speedup vs baseline: 3.6633x; 1.0419x over previous
//
#include <hip/hip_runtime.h>
#include <hip/hip_bf16.h>
#include <cmath>

// ---------------------------------------------------------------------------
// Pipeline: y1 = bn_relu(dcn(x, w_off1, b_off1, w1, b1))        (4,128,64,64)
//           up = up_depthwise(y1, w_up, f=2)                    (4,128,128,128)
//           out = bn_relu(dcn(up, w_off2, b_off2, w2, b2))      (4,128,128,128)
// ALL GEMM-shaped work on mfma_f32_16x16x32_bf16, split-bf16 (hi/lo, 3 prod).
// R14: M-SPLIT wave mapping in dcn kernels — each wave owns MTW=8/NPQ m-tiles
//      x ALL positions; A fragments read once/chunk into regs and reused
//      across NPT pos-tiles (dcn2 LDS reads 18->12/thread/chunk; dcn1 A
//      global loads 16->8). Bitwise-identical accumulation order.
// pack via v_cvt_pk_bf16_f32; s_setprio(1) around MFMA clusters.
// conv_off -> conv_mfma (M=27 padded to 32, tap-sampler B).
// dcn2 (ASTAGE): single-S alternating-phase pipeline.
// Weights pre-permuted into per-chunk fragment order (coalesced A loads).
// Workspace: om1 | y1 | up | om2 ; w1+wo1 splits parked in `up`,
// w2+wo2 splits parked in `y1`.
// ---------------------------------------------------------------------------

#define EPSV 1e-5f

typedef __attribute__((ext_vector_type(8))) short short8;
typedef __attribute__((ext_vector_type(4))) float f32x4;

__device__ __forceinline__ ushort f2bf(float f) {
    union { float f; uint u; } v; v.f = f;
    const uint r = v.u + 0x7fffu + ((v.u >> 16) & 1u);   // RNE
    return (ushort)(r >> 16);
}
__device__ __forceinline__ float bf2f(ushort h) {
    union { uint u; float f; } v; v.u = ((uint)h) << 16;
    return v.f;
}
__device__ __forceinline__ float2 ld2u(const float* p) {
    float2 v; __builtin_memcpy(&v, p, sizeof(float2)); return v;
}
// packed bf16 RNE convert: dst.lo = bf16(a), dst.hi = bf16(b)
__device__ __forceinline__ uint cvtpk_bf16(float a, float b) {
    uint r;
    asm("v_cvt_pk_bf16_f32 %0, %1, %2" : "=v"(r) : "v"(a), "v"(b));
    return r;
}

// ---- pack 8 fp32 -> bf16 hi/lo rows of S (cvt_pk fast path) ----------------
template <int KS>
__device__ __forceinline__ void pack_store8(
    const float* s, ushort* __restrict__ Shi, ushort* __restrict__ Slo,
    int pp, int j0)
{
    uint hw[4], lw[4];
#pragma unroll
    for (int q = 0; q < 4; ++q) {
        const float s0 = s[2 * q], s1 = s[2 * q + 1];
        const uint h = cvtpk_bf16(s0, s1);
        union { uint u; float f; } h0, h1;
        h0.u = h << 16;
        h1.u = h & 0xffff0000u;
        hw[q] = h;
        lw[q] = cvtpk_bf16(s0 - h0.f, s1 - h1.f);
    }
    uint4 hv; hv.x = hw[0]; hv.y = hw[1]; hv.z = hw[2]; hv.w = hw[3];
    uint4 lv; lv.x = lw[0]; lv.y = lw[1]; lv.z = lw[2]; lv.w = lw[3];
    *(uint4*)&Shi[pp * KS + j0] = hv;
    *(uint4*)&Slo[pp * KS + j0] = lv;
}

// ------- weight split: fp32 -> bf16 hi/lo in per-chunk FRAGMENT order -------
__global__ __launch_bounds__(256) void wsplit_perm_kernel(
    const float* __restrict__ w, ushort* __restrict__ hi,
    ushort* __restrict__ lo, int cin, int n)
{
    const int i = blockIdx.x * 256 + threadIdx.x;
    if (i >= n) return;
    const int cin9 = cin * 9;
    const int co = i / cin9;
    const int k  = i - co * cin9;            // channel-major K index
    const int ch = k >> 5;
    const int kq = (k & 31) >> 3;
    const int j  = k & 7;
    const int mt = co >> 4;
    const int lane = (co & 15) | (kq << 4);
    const size_t dst = ((size_t)(ch * 8 + mt) * 64 + lane) * 8 + j;
    const float f = w[i];
    const ushort h = f2bf(f);
    hi[dst] = h;
    lo[dst] = f2bf(f - bf2f(h));
}

// ------- conv weight split: (27,CIN,3,3) -> M=32 zero-padded frag order -----
__global__ __launch_bounds__(256) void wsplit_perm_conv_kernel(
    const float* __restrict__ w, ushort* __restrict__ hi,
    ushort* __restrict__ lo, int cin, int n)   // n = 32*cin*9
{
    const int i = blockIdx.x * 256 + threadIdx.x;
    if (i >= n) return;
    const int cin9 = cin * 9;
    const int co = i / cin9;
    const int k  = i - co * cin9;
    const int ch = k >> 5;
    const int kq = (k & 31) >> 3;
    const int j  = k & 7;
    const int mt = co >> 4;
    const int lane = (co & 15) | (kq << 4);
    const size_t dst = ((size_t)(ch * 2 + mt) * 64 + lane) * 8 + j;
    const float f = (co < 27) ? w[(size_t)co * cin9 + k] : 0.f;
    const ushort h = f2bf(f);
    hi[dst] = h;
    lo[dst] = f2bf(f - bf2f(h));
}

// ---------------- offset conv on MFMA: 3x3, pad 1, 27(->32) outputs ---------
template <int CIN, int HH, int WW, int POS, int KS>
__device__ __forceinline__ void conv_sample_chunk(
    const float* __restrict__ xb, const uint* __restrict__ toff,
    const float* __restrict__ twt, ushort* __restrict__ Shi,
    ushort* __restrict__ Slo, int tt, int kbase)
{
    constexpr int HW = HH * WW;
    const int pp = tt & (POS - 1);
    const int j0 = (tt / POS) * 8;
    float s[8];
#pragma unroll
    for (int j = 0; j < 8; ++j) {
        const int kg = kbase + j0 + j;
        const int c  = (kg * 7282) >> 16;       // /9 (exact for kg<2304)
        const int k9 = kg - c * 9;
        const int ei = k9 * POS + pp;
        s[j] = xb[(size_t)c * HW + toff[ei]] * twt[ei];
    }
    pack_store8<KS>(s, Shi, Slo, pp, j0);
}

template <int CIN, int HH, int WW, int POS, int KWAVES, int MINW>
__global__ __launch_bounds__((POS / 16) * KWAVES * 64, MINW) void conv_mfma_kernel(
    const float* __restrict__ in,    // (B, CIN, HH, WW)
    const ushort* __restrict__ whi,  // (32, CIN*9) frag order, zero-padded
    const ushort* __restrict__ wlo,
    const float* __restrict__ bias,  // (27)
    float* __restrict__ om)          // (B, 27, HH*WW)
{
    constexpr int HW   = HH * WW;
    constexpr int K    = CIN * 9;
    constexpr int NPQ  = POS / 16;
    constexpr int NT   = NPQ * KWAVES * 64;
    constexpr int KC   = 32;
    constexpr int KS   = 40;
    constexpr int NCHT = K / KC;
    constexpr int NCH  = NCHT / KWAVES;
    constexpr int SBUF = POS * KS;

    extern __shared__ __align__(16) char smem[];
    uint*   toff  = (uint*)smem;              // 9*POS
    float*  twt   = (float*)(toff + 9 * POS); // 9*POS
    ushort* Sbase = (ushort*)(twt + 9 * POS);

    const int tid = threadIdx.x;
    const int nt  = HW / POS;
    const int cpx = gridDim.x >> 3;
    const int bid = (blockIdx.x & 7) * cpx + (blockIdx.x >> 3);
    const int b   = bid / nt;
    const int p0  = (bid - b * nt) * POS;

    for (int i = tid; i < 9 * POS; i += NT) {
        const int k9 = i / POS, pp = i - k9 * POS;
        const int p  = p0 + pp;
        const int yy = p / WW, xx = p - yy * WW;
        const int ky = (k9 * 11) >> 5, kx = k9 - ky * 3;
        const int iy = yy + ky - 1, ix = xx + kx - 1;
        const bool v = (iy >= 0) && (iy < HH) && (ix >= 0) && (ix < WW);
        const int cy = min(max(iy, 0), HH - 1);
        const int cx = min(max(ix, 0), WW - 1);
        toff[i] = (uint)(cy * WW + cx);
        twt[i]  = v ? 1.f : 0.f;
    }
    __syncthreads();

    const float* xb = in + (size_t)b * CIN * HW;
    const int lane = tid & 63;
    const int w    = tid >> 6;
    const int wq   = w & (NPQ - 1);
    const int kgid = w / NPQ;
    const int tt   = tid & (NPQ * 64 - 1);
    ushort* S00 = Sbase + kgid * (4 * SBUF);

    f32x4 acc[2];
    acc[0] = (f32x4){0.f, 0.f, 0.f, 0.f};
    acc[1] = (f32x4){0.f, 0.f, 0.f, 0.f};
    const int mrow = lane & 15;
    const int kq   = lane >> 4;

    conv_sample_chunk<CIN, HH, WW, POS, KS>(xb, toff, twt, S00, S00 + SBUF,
                                            tt, kgid * NCH * KC);
    __syncthreads();

    for (int ch = 0; ch < NCH; ++ch) {
        const int cur = ch & 1;
        ushort* Sc = S00 + (cur * 2) * SBUF;
        const int boff = (wq * 16 + mrow) * KS + kq * 8;
        const short8 bh = *(const short8*)&Sc[boff];
        const short8 bl = *(const short8*)&Sc[SBUF + boff];
        if (ch + 1 < NCH) {
            ushort* Sn = S00 + ((cur ^ 1) * 2) * SBUF;
            conv_sample_chunk<CIN, HH, WW, POS, KS>(xb, toff, twt,
                                                    Sn, Sn + SBUF, tt,
                                                    (kgid * NCH + ch + 1) * KC);
        }
        const size_t abase = (size_t)((kgid * NCH + ch) * 2) * 512;
        __builtin_amdgcn_s_setprio(1);
#pragma unroll
        for (int mt = 0; mt < 2; ++mt) {
            const size_t ao = abase + (size_t)((mt * 64 + lane) * 8);
            const short8 ah = *(const short8*)(whi + ao);
            const short8 al = *(const short8*)(wlo + ao);
            acc[mt] = __builtin_amdgcn_mfma_f32_16x16x32_bf16(al, bh, acc[mt], 0, 0, 0);
            acc[mt] = __builtin_amdgcn_mfma_f32_16x16x32_bf16(ah, bl, acc[mt], 0, 0, 0);
            acc[mt] = __builtin_amdgcn_mfma_f32_16x16x32_bf16(ah, bh, acc[mt], 0, 0, 0);
        }
        __builtin_amdgcn_s_setprio(0);
        __syncthreads();
    }

    const int pcolb = wq * 16 + mrow;
    constexpr int RS = POS + 1;
    constexpr int SL = 32 * RS;
    float* red = (float*)Sbase;

    if constexpr (KWAVES == 4) {
        if (kgid >= 2) {
#pragma unroll
            for (int mt = 0; mt < 2; ++mt)
#pragma unroll
                for (int r = 0; r < 4; ++r) {
                    const int co = mt * 16 + kq * 4 + r;
                    red[(kgid - 2) * SL + co * RS + pcolb] = acc[mt][r];
                }
        }
        __syncthreads();
        if (kgid < 2) {
#pragma unroll
            for (int mt = 0; mt < 2; ++mt)
#pragma unroll
                for (int r = 0; r < 4; ++r) {
                    const int co = mt * 16 + kq * 4 + r;
                    acc[mt][r] += red[kgid * SL + co * RS + pcolb];
                }
        }
        __syncthreads();
        if (kgid == 1) {
#pragma unroll
            for (int mt = 0; mt < 2; ++mt)
#pragma unroll
                for (int r = 0; r < 4; ++r) {
                    const int co = mt * 16 + kq * 4 + r;
                    red[co * RS + pcolb] = acc[mt][r];
                }
        }
        __syncthreads();
        if (kgid == 0) {
#pragma unroll
            for (int mt = 0; mt < 2; ++mt)
#pragma unroll
                for (int r = 0; r < 4; ++r) {
                    const int co = mt * 16 + kq * 4 + r;
                    acc[mt][r] += red[co * RS + pcolb];
                }
        }
    } else if constexpr (KWAVES == 2) {
        if (kgid == 1) {
#pragma unroll
            for (int mt = 0; mt < 2; ++mt)
#pragma unroll
                for (int r = 0; r < 4; ++r) {
                    const int co = mt * 16 + kq * 4 + r;
                    red[co * RS + pcolb] = acc[mt][r];
                }
        }
        __syncthreads();
        if (kgid == 0) {
#pragma unroll
            for (int mt = 0; mt < 2; ++mt)
#pragma unroll
                for (int r = 0; r < 4; ++r) {
                    const int co = mt * 16 + kq * 4 + r;
                    acc[mt][r] += red[co * RS + pcolb];
                }
        }
    }

    if (kgid == 0) {
        float* ob = om + (size_t)b * 27 * HW + p0 + pcolb;
#pragma unroll
        for (int mt = 0; mt < 2; ++mt)
#pragma unroll
            for (int r = 0; r < 4; ++r) {
                const int co = mt * 16 + kq * 4 + r;
                if (co < 27)
                    ob[(size_t)co * HW] = acc[mt][r] + bias[co];
            }
    }
}

// ---------------- paired sampler: issue / finish ----------------------------
template <int CIN, int HH, int WW, int POS>
__device__ __forceinline__ void sample_issue(
    const float* __restrict__ xb, const uint* __restrict__ eoff2,
    float2* v0, float2* v1, int tt, int kbase)
{
    constexpr int HW = HH * WW;
    const int pp = tt & (POS - 1);
    const int j0 = (tt / POS) * 8;
#pragma unroll
    for (int j = 0; j < 8; ++j) {
        const int kg = kbase + j0 + j;
        const int c  = (kg * 7282) >> 16;       // /9 (exact for kg<2304)
        const int k9 = kg - c * 9;
        const uint e = eoff2[k9 * POS + pp];
        const float* chp = xb + (size_t)c * HW;
        v0[j] = ld2u(chp + (e & 0xffffu));
        v1[j] = ld2u(chp + (e >> 16));
    }
}

template <int CIN, int HH, int WW, int POS, int KS>
__device__ __forceinline__ void sample_finish(
    const float4* __restrict__ ewt, const float2* v0, const float2* v1,
    ushort* __restrict__ Shi, ushort* __restrict__ Slo, int tt, int kbase)
{
    const int pp = tt & (POS - 1);
    const int j0 = (tt / POS) * 8;
    float s[8];
#pragma unroll
    for (int j = 0; j < 8; ++j) {
        const int kg = kbase + j0 + j;
        const int c  = (kg * 7282) >> 16;
        const int k9 = kg - c * 9;
        const float4 wv = ewt[k9 * POS + pp];
        s[j] = v0[j].x * wv.x + v0[j].y * wv.y
             + v1[j].x * wv.z + v1[j].y * wv.w;
    }
    pack_store8<KS>(s, Shi, Slo, pp, j0);
}

template <int CIN, int HH, int WW, int POS, int KS>
__device__ __forceinline__ void sample_chunk(
    const float* __restrict__ xb, const uint* __restrict__ eoff2,
    const float4* __restrict__ ewt, ushort* __restrict__ Shi,
    ushort* __restrict__ Slo, int tt, int kbase)
{
    float2 v0[8], v1[8];
    sample_issue<CIN, HH, WW, POS>(xb, eoff2, v0, v1, tt, kbase);
    sample_finish<CIN, HH, WW, POS, KS>(ewt, v0, v1, Shi, Slo, tt, kbase);
}

// ---------------- fused DCN on MFMA: sample + GEMM + bias + BN + ReLU -------
// M-SPLIT: wave wm owns MTW = 8/NPQ m-tiles x all POS positions (NPT tiles).
template <int CIN, int HH, int WW, int POS, int KWAVES, int MINW,
          bool ASTAGE, bool OMS>
__global__ __launch_bounds__((POS / 16) * KWAVES * 64, MINW) void dcn_mfma_kernel(
    const float* __restrict__ xin,   // (B, CIN, HH, WW)
    const float* __restrict__ om,    // (B, 27, HH, WW)
    const float* __restrict__ omB,   // partial (OMS only)
    const ushort* __restrict__ whi,  // (128, K) bf16 hi, fragment order
    const ushort* __restrict__ wlo,  // (128, K) bf16 lo, fragment order
    const float* __restrict__ bias,
    const float* __restrict__ gam, const float* __restrict__ bet,
    const float* __restrict__ mu,  const float* __restrict__ var,
    float* __restrict__ out)         // (B, 128, HH*WW)
{
    constexpr int HW   = HH * WW;
    constexpr int K    = CIN * 9;
    constexpr int NPQ  = POS / 16;
    constexpr int NT   = NPQ * KWAVES * 64;
    constexpr int KC   = 32;
    constexpr int KS   = 40;
    constexpr int NCHT = K / KC;
    constexpr int NCH  = NCHT / KWAVES;
    constexpr int SBUF = POS * KS;
    constexpr int ABN  = ASTAGE ? 8192 : 0;
    constexpr int MTW  = 8 / NPQ;             // m-tiles per wave
    constexpr int NPT  = POS / 16;            // pos-tiles per wave

    extern __shared__ __align__(16) char smem[];
    uint*    eoff2 = (uint*)smem;
    float4*  ewt   = (float4*)(eoff2 + 9 * POS);
    float*   invp  = (float*)(ewt + 9 * POS);
    float*   shp   = invp + 128;
    ushort*  Abuf  = (ushort*)(shp + 128);
    ushort*  Sbase = Abuf + ABN;

    const int tid = threadIdx.x;
    const int nt  = HW / POS;
    const int cpx = gridDim.x >> 3;
    const int bid = (blockIdx.x & 7) * cpx + (blockIdx.x >> 3);
    const int b   = bid / nt;
    const int p0  = (bid - b * nt) * POS;

    const float* omb  = om + (size_t)b * 27 * HW;
    const float* ombB = OMS ? (omB + (size_t)b * 27 * HW) : nullptr;
    for (int i = tid; i < 9 * POS; i += NT) {
        const int k9 = i / POS, pp = i - k9 * POS;
        const int p  = p0 + pp;
        const int yy = p / WW;
        const int xx = p - yy * WW;
        float oy = omb[(size_t)k9 * HW + p];
        float ox = omb[(size_t)(9 + k9) * HW + p];
        float mv = omb[(size_t)(18 + k9) * HW + p];
        if constexpr (OMS) {
            oy += ombB[(size_t)k9 * HW + p];
            ox += ombB[(size_t)(9 + k9) * HW + p];
            mv += ombB[(size_t)(18 + k9) * HW + p];
        }
        const float m  = 1.0f / (1.0f + expf(-mv));
        const int ky = (k9 * 11) >> 5;
        const int kx = k9 - ky * 3;
        const float py = (float)(yy + ky - 1) + oy;
        const float px = (float)(xx + kx - 1) + ox;
        const float y0f = floorf(py), x0f = floorf(px);
        const int   y0  = (int)y0f,  x0 = (int)x0f;
        const int by0 = min(max(y0, 0), HH - 1);
        const int by1 = min(max(y0 + 1, 0), HH - 1);
        const int bx  = min(max(x0, 0), WW - 2);
        const float wy1 = py - y0f, wx1 = px - x0f;
        const float fy0 = (y0 >= 0  && y0 < HH)     ? (1.f - wy1) * m : 0.f;
        const float fy1 = (y0 >= -1 && y0 < HH - 1) ? wy1 * m         : 0.f;
        const float fx0v = 1.f - wx1, fx1v = wx1;
        float gx0 = 0.f, gx1 = 0.f;
        if (x0 >= 0 && x0 < WW)         { if (x0 == bx)     gx0 += fx0v; else gx1 += fx0v; }
        if (x0 + 1 >= 0 && x0 + 1 < WW) { if (x0 + 1 == bx) gx0 += fx1v; else gx1 += fx1v; }
        eoff2[i] = (uint)(by0 * WW + bx) | ((uint)(by1 * WW + bx) << 16);
        float4 wv; wv.x = fy0 * gx0; wv.y = fy0 * gx1;
                   wv.z = fy1 * gx0; wv.w = fy1 * gx1;
        ewt[i] = wv;
    }
    for (int i = tid; i < 128; i += NT) {
        const float iv = gam[i] * rsqrtf(var[i] + EPSV);
        invp[i] = iv;
        shp[i]  = bet[i] - mu[i] * iv + bias[i] * iv;
    }
    __syncthreads();

    const float* xb   = xin + (size_t)b * CIN * HW;
    const int lane = tid & 63;
    const int w    = tid >> 6;
    const int wm   = w & (NPQ - 1);          // m-group of this wave
    const int kgid = w / NPQ;
    const int tt   = tid & (NPQ * 64 - 1);
    const int m0   = wm * MTW;

    f32x4 acc[8];                             // [mt2][pt] flattened
#pragma unroll
    for (int mt = 0; mt < 8; ++mt) acc[mt] = (f32x4){0.f, 0.f, 0.f, 0.f};

    const int mrow = lane & 15;
    const int kq   = lane >> 4;

    if constexpr (ASTAGE) {
        // ===== single-S-buffer alternating-phase pipeline =====
        ushort* Shi = Sbase;
        ushort* Slo = Sbase + SBUF;
        float2 v0[8], v1[8];
        sample_chunk<CIN, HH, WW, POS, KS>(xb, eoff2, ewt, Shi, Slo, tt, 0);
        {
#pragma unroll
            for (int t = 0; t < 1024 / NT; ++t) {
                const int u = tid + t * NT;
                const ushort* srcp = (u < 512)
                    ? (whi + (size_t)u * 8)
                    : (wlo + (size_t)(u - 512) * 8);
                *(short8*)&Abuf[(size_t)u * 8] = *(const short8*)srcp;
            }
        }
        if (NCH > 1)
            sample_issue<CIN, HH, WW, POS>(xb, eoff2, v0, v1, tt, KC);
        asm volatile("s_waitcnt lgkmcnt(0)" ::: "memory");
        __builtin_amdgcn_s_barrier();
        __builtin_amdgcn_sched_barrier(0);

        for (int ch = 0; ch < NCH; ++ch) {
            __builtin_amdgcn_s_setprio(1);
            // A fragments for this wave's m-tiles, read ONCE per chunk
            short8 ahv[MTW], alv[MTW];
#pragma unroll
            for (int mt2 = 0; mt2 < MTW; ++mt2) {
                const int au = ((m0 + mt2) * 64 + lane) * 8;
                ahv[mt2] = *(const short8*)&Abuf[au];
                alv[mt2] = *(const short8*)&Abuf[4096 + au];
            }
#pragma unroll
            for (int pt = 0; pt < NPT; ++pt) {
                const int boff = (pt * 16 + mrow) * KS + kq * 8;
                const short8 bh = *(const short8*)&Shi[boff];
                const short8 bl = *(const short8*)&Slo[boff];
#pragma unroll
                for (int mt2 = 0; mt2 < MTW; ++mt2) {
                    f32x4 a = acc[mt2 * NPT + pt];
                    a = __builtin_amdgcn_mfma_f32_16x16x32_bf16(alv[mt2], bh, a, 0, 0, 0);
                    a = __builtin_amdgcn_mfma_f32_16x16x32_bf16(ahv[mt2], bl, a, 0, 0, 0);
                    a = __builtin_amdgcn_mfma_f32_16x16x32_bf16(ahv[mt2], bh, a, 0, 0, 0);
                    acc[mt2 * NPT + pt] = a;
                }
            }
            __builtin_amdgcn_s_setprio(0);
            if (ch + 1 < NCH) {
                asm volatile("s_waitcnt lgkmcnt(0)" ::: "memory");
                __builtin_amdgcn_s_barrier();
                __builtin_amdgcn_sched_barrier(0);
                const size_t wb = (size_t)(ch + 1) * 4096;
#pragma unroll
                for (int t = 0; t < 1024 / NT; ++t) {
                    const int u = tid + t * NT;
                    const ushort* srcp = (u < 512)
                        ? (whi + wb + (size_t)u * 8)
                        : (wlo + wb + (size_t)(u - 512) * 8);
                    *(short8*)&Abuf[(size_t)u * 8] = *(const short8*)srcp;
                }
                sample_finish<CIN, HH, WW, POS, KS>(ewt, v0, v1, Shi, Slo,
                                                    tt, (ch + 1) * KC);
                if (ch + 2 < NCH)
                    sample_issue<CIN, HH, WW, POS>(xb, eoff2, v0, v1, tt,
                                                   (ch + 2) * KC);
                asm volatile("s_waitcnt lgkmcnt(0)" ::: "memory");
                __builtin_amdgcn_s_barrier();
                __builtin_amdgcn_sched_barrier(0);
            }
        }
    } else {
        ushort* S00 = Sbase + kgid * (4 * SBUF);
        sample_chunk<CIN, HH, WW, POS, KS>(xb, eoff2, ewt, S00, S00 + SBUF,
                                           tt, kgid * NCH * KC);
        __syncthreads();

        for (int ch = 0; ch < NCH; ++ch) {
            const int cur = ch & 1;
            ushort* Sc = S00 + (cur * 2) * SBUF;
            // B fragments for all pos-tiles (held across the sampler)
            short8 bhv[NPT], blv[NPT];
#pragma unroll
            for (int pt = 0; pt < NPT; ++pt) {
                const int boff = (pt * 16 + mrow) * KS + kq * 8;
                bhv[pt] = *(const short8*)&Sc[boff];
                blv[pt] = *(const short8*)&Sc[SBUF + boff];
            }
            if (ch + 1 < NCH) {
                ushort* Sn = S00 + ((cur ^ 1) * 2) * SBUF;
                sample_chunk<CIN, HH, WW, POS, KS>(xb, eoff2, ewt,
                                                   Sn, Sn + SBUF, tt,
                                                   (kgid * NCH + ch + 1) * KC);
            }
            // A fragments just-in-time from global (fragment order, coalesced)
            const size_t abase = (size_t)((kgid * NCH + ch) * 8) * 512;
            __builtin_amdgcn_s_setprio(1);
#pragma unroll
            for (int mt2 = 0; mt2 < MTW; ++mt2) {
                const size_t ao = abase + (size_t)(((m0 + mt2) * 64 + lane) * 8);
                const short8 ah = *(const short8*)(whi + ao);
                const short8 al = *(const short8*)(wlo + ao);
#pragma unroll
                for (int pt = 0; pt < NPT; ++pt) {
                    f32x4 a = acc[mt2 * NPT + pt];
                    a = __builtin_amdgcn_mfma_f32_16x16x32_bf16(al, bhv[pt], a, 0, 0, 0);
                    a = __builtin_amdgcn_mfma_f32_16x16x32_bf16(ah, blv[pt], a, 0, 0, 0);
                    a = __builtin_amdgcn_mfma_f32_16x16x32_bf16(ah, bhv[pt], a, 0, 0, 0);
                    acc[mt2 * NPT + pt] = a;
                }
            }
            __builtin_amdgcn_s_setprio(0);
            __syncthreads();
        }
    }

    constexpr int RS = POS + 1;
    constexpr int SL = 128 * RS;
    float* red = (float*)Sbase;

    if constexpr (KWAVES == 4) {
        if (kgid >= 2) {
#pragma unroll
            for (int mt2 = 0; mt2 < MTW; ++mt2)
#pragma unroll
                for (int pt = 0; pt < NPT; ++pt)
#pragma unroll
                    for (int r = 0; r < 4; ++r) {
                        const int co = (m0 + mt2) * 16 + kq * 4 + r;
                        red[(kgid - 2) * SL + co * RS + pt * 16 + mrow] =
                            acc[mt2 * NPT + pt][r];
                    }
        }
        __syncthreads();
        if (kgid < 2) {
#pragma unroll
            for (int mt2 = 0; mt2 < MTW; ++mt2)
#pragma unroll
                for (int pt = 0; pt < NPT; ++pt)
#pragma unroll
                    for (int r = 0; r < 4; ++r) {
                        const int co = (m0 + mt2) * 16 + kq * 4 + r;
                        acc[mt2 * NPT + pt][r] +=
                            red[kgid * SL + co * RS + pt * 16 + mrow];
                    }
        }
        __syncthreads();
        if (kgid == 1) {
#pragma unroll
            for (int mt2 = 0; mt2 < MTW; ++mt2)
#pragma unroll
                for (int pt = 0; pt < NPT; ++pt)
#pragma unroll
                    for (int r = 0; r < 4; ++r) {
                        const int co = (m0 + mt2) * 16 + kq * 4 + r;
                        red[co * RS + pt * 16 + mrow] = acc[mt2 * NPT + pt][r];
                    }
        }
        __syncthreads();
        if (kgid == 0) {
#pragma unroll
            for (int mt2 = 0; mt2 < MTW; ++mt2)
#pragma unroll
                for (int pt = 0; pt < NPT; ++pt)
#pragma unroll
                    for (int r = 0; r < 4; ++r) {
                        const int co = (m0 + mt2) * 16 + kq * 4 + r;
                        acc[mt2 * NPT + pt][r] += red[co * RS + pt * 16 + mrow];
                    }
        }
    } else if constexpr (KWAVES == 2) {
        if (kgid == 1) {
#pragma unroll
            for (int mt2 = 0; mt2 < MTW; ++mt2)
#pragma unroll
                for (int pt = 0; pt < NPT; ++pt)
#pragma unroll
                    for (int r = 0; r < 4; ++r) {
                        const int co = (m0 + mt2) * 16 + kq * 4 + r;
                        red[co * RS + pt * 16 + mrow] = acc[mt2 * NPT + pt][r];
                    }
        }
        __syncthreads();
        if (kgid == 0) {
#pragma unroll
            for (int mt2 = 0; mt2 < MTW; ++mt2)
#pragma unroll
                for (int pt = 0; pt < NPT; ++pt)
#pragma unroll
                    for (int r = 0; r < 4; ++r) {
                        const int co = (m0 + mt2) * 16 + kq * 4 + r;
                        acc[mt2 * NPT + pt][r] += red[co * RS + pt * 16 + mrow];
                    }
        }
    }

    if (kgid == 0) {
        float* outb = out + (size_t)b * 128 * HW + p0;
#pragma unroll
        for (int mt2 = 0; mt2 < MTW; ++mt2)
#pragma unroll
            for (int pt = 0; pt < NPT; ++pt)
#pragma unroll
                for (int r = 0; r < 4; ++r) {
                    const int co = (m0 + mt2) * 16 + kq * 4 + r;
                    outb[(size_t)co * HW + pt * 16 + mrow] =
                        fmaxf(acc[mt2 * NPT + pt][r] * invp[co] + shp[co], 0.f);
                }
    }
}

// ---------------- depthwise transposed-conv upsample x2 (k=4, pad 2) --------
__global__ __launch_bounds__(256) void upsample_kernel(
    const float* __restrict__ y,    // (4,128,64,64)
    const float* __restrict__ wup,  // (128,1,4,4)
    float* __restrict__ out)        // (4,128,128,128)
{
    const int idx = blockIdx.x * 256 + threadIdx.x;
    const int ox = idx & 127;
    const int oy = (idx >> 7) & 127;
    const int c  = (idx >> 14) & 127;
    const int b  = idx >> 21;

    const float* yc = y + (size_t)(b * 128 + c) * 4096;
    const float* wc = wup + c * 16;

    float acc = 0.f;
#pragma unroll
    for (int ky = 0; ky < 4; ++ky) {
        const int qy = oy + ky - 2;
        if (qy & 1) continue;
        const int iy = qy >> 1;
        if (iy < 0 || iy >= 64) continue;
#pragma unroll
        for (int kx = 0; kx < 4; ++kx) {
            const int qx = ox + kx - 2;
            if (qx & 1) continue;
            const int ix = qx >> 1;
            if (ix < 0 || ix >= 64) continue;
            acc += yc[iy * 64 + ix] * wc[(3 - ky) * 4 + (3 - kx)];
        }
    }
    out[idx] = acc;
}

// ---------------------------------------------------------------------------
extern "C" void kernel_launch(void* const* d_in, const int* in_sizes, int n_in,
                              void* d_out, int out_size, void* d_ws, size_t ws_size,
                              hipStream_t stream) {
    const float* x      = (const float*)d_in[0];
    const float* w_off1 = (const float*)d_in[1];
    const float* b_off1 = (const float*)d_in[2];
    const float* w1     = (const float*)d_in[3];
    const float* b1     = (const float*)d_in[4];
    const float* g1v    = (const float*)d_in[5];
    const float* be1    = (const float*)d_in[6];
    const float* m1     = (const float*)d_in[7];
    const float* v1     = (const float*)d_in[8];
    const float* w_up   = (const float*)d_in[9];
    const float* w_off2 = (const float*)d_in[10];
    const float* b_off2 = (const float*)d_in[11];
    const float* w2     = (const float*)d_in[12];
    const float* b2     = (const float*)d_in[13];
    const float* g2v    = (const float*)d_in[14];
    const float* be2    = (const float*)d_in[15];
    const float* m2     = (const float*)d_in[16];
    const float* v2     = (const float*)d_in[17];

    float* ws  = (float*)d_ws;
    float* om1 = ws;                     // 4*27*4096   =   442368 f
    float* y1  = om1 + 442368;           // 4*128*4096  =  2097152 f
    float* up  = y1 + 2097152;           // 4*128*16384 =  8388608 f
    float* om2 = up + 8388608;           // 4*27*16384  =  1769472 f
    float* outf = (float*)d_out;

    // `up` region (dead until upsample writes it): w1 + w_off1 splits
    ushort* w1hi  = (ushort*)up;         // 294912
    ushort* w1lo  = w1hi + 294912;       // 294912
    ushort* wo1hi = w1lo + 294912;       // 32*2304 = 73728
    ushort* wo1lo = wo1hi + 73728;       // 73728
    // `y1` region (dead after upsample reads it): w2 + w_off2 splits
    ushort* w2hi  = (ushort*)y1;         // 147456
    ushort* w2lo  = w2hi + 147456;       // 147456
    ushort* wo2hi = w2lo + 147456;       // 32*1152 = 36864
    ushort* wo2lo = wo2hi + 36864;       // 36864

    // prep: w1 (dcn1) + w_off1 (conv1) splits, fragment order
    wsplit_perm_kernel<<<(294912 + 255) / 256, 256, 0, stream>>>(
        w1, w1hi, w1lo, 256, 294912);
    wsplit_perm_conv_kernel<<<(73728 + 255) / 256, 256, 0, stream>>>(
        w_off1, wo1hi, wo1lo, 256, 73728);

    // om1 = conv3x3(x, w_off1) + b_off1 — MFMA, POS=16, KWAVES=4
    conv_mfma_kernel<256, 64, 64, 16, 4, 4>
        <<<1024, 256, 21632, stream>>>(x, wo1hi, wo1lo, b_off1, om1);

    // y1 = bn_relu(dcn1) — MFMA, POS=32, 4-way K-split, M-split waves
    dcn_mfma_kernel<256, 64, 64, 32, 4, 4, false, false>
        <<<4 * (4096 / 32), 512, 47744, stream>>>(
        x, om1, om1, w1hi, w1lo, b1, g1v, be1, m1, v1, y1);
    // up = depthwise transposed upsample (clobbers w1/wo1 splits — now dead)
    upsample_kernel<<<8388608 / 256, 256, 0, stream>>>(y1, w_up, up);

    // prep: w2 (dcn2) + w_off2 (conv2) splits (y1 now dead)
    wsplit_perm_kernel<<<(147456 + 255) / 256, 256, 0, stream>>>(
        w2, w2hi, w2lo, 128, 147456);
    wsplit_perm_conv_kernel<<<(36864 + 255) / 256, 256, 0, stream>>>(
        w_off2, wo2hi, wo2lo, 128, 36864);

    // om2 = conv3x3(up, w_off2) + b_off2 — MFMA, POS=64, KWAVES=1
    conv_mfma_kernel<128, 128, 128, 64, 1, 4>
        <<<1024, 256, 25088, stream>>>(up, wo2hi, wo2lo, b_off2, om2);

    // out = bn_relu(dcn2) — MFMA, POS=64, A-staged, single-S, M-split waves
    dcn_mfma_kernel<128, 128, 128, 64, 1, 4, true, false>
        <<<4 * (16384 / 64), 256, 39168, stream>>>(
        up, om2, om2, w2hi, w2lo, b2, g2v, be2, m2, v2, outf);
}

// Round 15
// 358.179 us; speedup vs baseline: 3.7515x; 1.0241x over previous
//
#include <hip/hip_runtime.h>
#include <hip/hip_bf16.h>
#include <cmath>

// ---------------------------------------------------------------------------
// Pipeline: y1 = bn_relu(dcn(x, w_off1, b_off1, w1, b1))        (4,128,64,64)
//           up = up_depthwise(y1, w_up, f=2)                    (4,128,128,128)
//           out = bn_relu(dcn(up, w_off2, b_off2, w2, b2))      (4,128,128,128)
// ALL GEMM-shaped work on mfma_f32_16x16x32_bf16, split-bf16 (hi/lo, 3 prod).
// R15: dcn2 A-stage T14-split — A global loads for ch+1 issued into regs
//      BEFORE the pre-MFMA barrier (a full MFMA phase to land); write phase
//      only ds_writes from regs. Removes serial L2 latency from write phase.
// R14: M-split wave mapping (A frags read once/chunk, reused over pos-tiles).
// pack via v_cvt_pk_bf16_f32; s_setprio(1) around MFMA clusters.
// conv_off -> conv_mfma (M=27 padded to 32, tap-sampler B).
// Weights pre-permuted into per-chunk fragment order (coalesced A loads).
// Workspace: om1 | y1 | up | om2 ; w1+wo1 splits parked in `up`,
// w2+wo2 splits parked in `y1`.
// ---------------------------------------------------------------------------

#define EPSV 1e-5f

typedef __attribute__((ext_vector_type(8))) short short8;
typedef __attribute__((ext_vector_type(4))) float f32x4;

__device__ __forceinline__ ushort f2bf(float f) {
    union { float f; uint u; } v; v.f = f;
    const uint r = v.u + 0x7fffu + ((v.u >> 16) & 1u);   // RNE
    return (ushort)(r >> 16);
}
__device__ __forceinline__ float bf2f(ushort h) {
    union { uint u; float f; } v; v.u = ((uint)h) << 16;
    return v.f;
}
__device__ __forceinline__ float2 ld2u(const float* p) {
    float2 v; __builtin_memcpy(&v, p, sizeof(float2)); return v;
}
// packed bf16 RNE convert: dst.lo = bf16(a), dst.hi = bf16(b)
__device__ __forceinline__ uint cvtpk_bf16(float a, float b) {
    uint r;
    asm("v_cvt_pk_bf16_f32 %0, %1, %2" : "=v"(r) : "v"(a), "v"(b));
    return r;
}

// ---- pack 8 fp32 -> bf16 hi/lo rows of S (cvt_pk fast path) ----------------
template <int KS>
__device__ __forceinline__ void pack_store8(
    const float* s, ushort* __restrict__ Shi, ushort* __restrict__ Slo,
    int pp, int j0)
{
    uint hw[4], lw[4];
#pragma unroll
    for (int q = 0; q < 4; ++q) {
        const float s0 = s[2 * q], s1 = s[2 * q + 1];
        const uint h = cvtpk_bf16(s0, s1);
        union { uint u; float f; } h0, h1;
        h0.u = h << 16;
        h1.u = h & 0xffff0000u;
        hw[q] = h;
        lw[q] = cvtpk_bf16(s0 - h0.f, s1 - h1.f);
    }
    uint4 hv; hv.x = hw[0]; hv.y = hw[1]; hv.z = hw[2]; hv.w = hw[3];
    uint4 lv; lv.x = lw[0]; lv.y = lw[1]; lv.z = lw[2]; lv.w = lw[3];
    *(uint4*)&Shi[pp * KS + j0] = hv;
    *(uint4*)&Slo[pp * KS + j0] = lv;
}

// ------- weight split: fp32 -> bf16 hi/lo in per-chunk FRAGMENT order -------
__global__ __launch_bounds__(256) void wsplit_perm_kernel(
    const float* __restrict__ w, ushort* __restrict__ hi,
    ushort* __restrict__ lo, int cin, int n)
{
    const int i = blockIdx.x * 256 + threadIdx.x;
    if (i >= n) return;
    const int cin9 = cin * 9;
    const int co = i / cin9;
    const int k  = i - co * cin9;            // channel-major K index
    const int ch = k >> 5;
    const int kq = (k & 31) >> 3;
    const int j  = k & 7;
    const int mt = co >> 4;
    const int lane = (co & 15) | (kq << 4);
    const size_t dst = ((size_t)(ch * 8 + mt) * 64 + lane) * 8 + j;
    const float f = w[i];
    const ushort h = f2bf(f);
    hi[dst] = h;
    lo[dst] = f2bf(f - bf2f(h));
}

// ------- conv weight split: (27,CIN,3,3) -> M=32 zero-padded frag order -----
__global__ __launch_bounds__(256) void wsplit_perm_conv_kernel(
    const float* __restrict__ w, ushort* __restrict__ hi,
    ushort* __restrict__ lo, int cin, int n)   // n = 32*cin*9
{
    const int i = blockIdx.x * 256 + threadIdx.x;
    if (i >= n) return;
    const int cin9 = cin * 9;
    const int co = i / cin9;
    const int k  = i - co * cin9;
    const int ch = k >> 5;
    const int kq = (k & 31) >> 3;
    const int j  = k & 7;
    const int mt = co >> 4;
    const int lane = (co & 15) | (kq << 4);
    const size_t dst = ((size_t)(ch * 2 + mt) * 64 + lane) * 8 + j;
    const float f = (co < 27) ? w[(size_t)co * cin9 + k] : 0.f;
    const ushort h = f2bf(f);
    hi[dst] = h;
    lo[dst] = f2bf(f - bf2f(h));
}

// ---------------- offset conv on MFMA: 3x3, pad 1, 27(->32) outputs ---------
template <int CIN, int HH, int WW, int POS, int KS>
__device__ __forceinline__ void conv_sample_chunk(
    const float* __restrict__ xb, const uint* __restrict__ toff,
    const float* __restrict__ twt, ushort* __restrict__ Shi,
    ushort* __restrict__ Slo, int tt, int kbase)
{
    constexpr int HW = HH * WW;
    const int pp = tt & (POS - 1);
    const int j0 = (tt / POS) * 8;
    float s[8];
#pragma unroll
    for (int j = 0; j < 8; ++j) {
        const int kg = kbase + j0 + j;
        const int c  = (kg * 7282) >> 16;       // /9 (exact for kg<2304)
        const int k9 = kg - c * 9;
        const int ei = k9 * POS + pp;
        s[j] = xb[(size_t)c * HW + toff[ei]] * twt[ei];
    }
    pack_store8<KS>(s, Shi, Slo, pp, j0);
}

template <int CIN, int HH, int WW, int POS, int KWAVES, int MINW>
__global__ __launch_bounds__((POS / 16) * KWAVES * 64, MINW) void conv_mfma_kernel(
    const float* __restrict__ in,    // (B, CIN, HH, WW)
    const ushort* __restrict__ whi,  // (32, CIN*9) frag order, zero-padded
    const ushort* __restrict__ wlo,
    const float* __restrict__ bias,  // (27)
    float* __restrict__ om)          // (B, 27, HH*WW)
{
    constexpr int HW   = HH * WW;
    constexpr int K    = CIN * 9;
    constexpr int NPQ  = POS / 16;
    constexpr int NT   = NPQ * KWAVES * 64;
    constexpr int KC   = 32;
    constexpr int KS   = 40;
    constexpr int NCHT = K / KC;
    constexpr int NCH  = NCHT / KWAVES;
    constexpr int SBUF = POS * KS;

    extern __shared__ __align__(16) char smem[];
    uint*   toff  = (uint*)smem;              // 9*POS
    float*  twt   = (float*)(toff + 9 * POS); // 9*POS
    ushort* Sbase = (ushort*)(twt + 9 * POS);

    const int tid = threadIdx.x;
    const int nt  = HW / POS;
    const int cpx = gridDim.x >> 3;
    const int bid = (blockIdx.x & 7) * cpx + (blockIdx.x >> 3);
    const int b   = bid / nt;
    const int p0  = (bid - b * nt) * POS;

    for (int i = tid; i < 9 * POS; i += NT) {
        const int k9 = i / POS, pp = i - k9 * POS;
        const int p  = p0 + pp;
        const int yy = p / WW, xx = p - yy * WW;
        const int ky = (k9 * 11) >> 5, kx = k9 - ky * 3;
        const int iy = yy + ky - 1, ix = xx + kx - 1;
        const bool v = (iy >= 0) && (iy < HH) && (ix >= 0) && (ix < WW);
        const int cy = min(max(iy, 0), HH - 1);
        const int cx = min(max(ix, 0), WW - 1);
        toff[i] = (uint)(cy * WW + cx);
        twt[i]  = v ? 1.f : 0.f;
    }
    __syncthreads();

    const float* xb = in + (size_t)b * CIN * HW;
    const int lane = tid & 63;
    const int w    = tid >> 6;
    const int wq   = w & (NPQ - 1);
    const int kgid = w / NPQ;
    const int tt   = tid & (NPQ * 64 - 1);
    ushort* S00 = Sbase + kgid * (4 * SBUF);

    f32x4 acc[2];
    acc[0] = (f32x4){0.f, 0.f, 0.f, 0.f};
    acc[1] = (f32x4){0.f, 0.f, 0.f, 0.f};
    const int mrow = lane & 15;
    const int kq   = lane >> 4;

    conv_sample_chunk<CIN, HH, WW, POS, KS>(xb, toff, twt, S00, S00 + SBUF,
                                            tt, kgid * NCH * KC);
    __syncthreads();

    for (int ch = 0; ch < NCH; ++ch) {
        const int cur = ch & 1;
        ushort* Sc = S00 + (cur * 2) * SBUF;
        const int boff = (wq * 16 + mrow) * KS + kq * 8;
        const short8 bh = *(const short8*)&Sc[boff];
        const short8 bl = *(const short8*)&Sc[SBUF + boff];
        if (ch + 1 < NCH) {
            ushort* Sn = S00 + ((cur ^ 1) * 2) * SBUF;
            conv_sample_chunk<CIN, HH, WW, POS, KS>(xb, toff, twt,
                                                    Sn, Sn + SBUF, tt,
                                                    (kgid * NCH + ch + 1) * KC);
        }
        const size_t abase = (size_t)((kgid * NCH + ch) * 2) * 512;
        __builtin_amdgcn_s_setprio(1);
#pragma unroll
        for (int mt = 0; mt < 2; ++mt) {
            const size_t ao = abase + (size_t)((mt * 64 + lane) * 8);
            const short8 ah = *(const short8*)(whi + ao);
            const short8 al = *(const short8*)(wlo + ao);
            acc[mt] = __builtin_amdgcn_mfma_f32_16x16x32_bf16(al, bh, acc[mt], 0, 0, 0);
            acc[mt] = __builtin_amdgcn_mfma_f32_16x16x32_bf16(ah, bl, acc[mt], 0, 0, 0);
            acc[mt] = __builtin_amdgcn_mfma_f32_16x16x32_bf16(ah, bh, acc[mt], 0, 0, 0);
        }
        __builtin_amdgcn_s_setprio(0);
        __syncthreads();
    }

    const int pcolb = wq * 16 + mrow;
    constexpr int RS = POS + 1;
    constexpr int SL = 32 * RS;
    float* red = (float*)Sbase;

    if constexpr (KWAVES == 4) {
        if (kgid >= 2) {
#pragma unroll
            for (int mt = 0; mt < 2; ++mt)
#pragma unroll
                for (int r = 0; r < 4; ++r) {
                    const int co = mt * 16 + kq * 4 + r;
                    red[(kgid - 2) * SL + co * RS + pcolb] = acc[mt][r];
                }
        }
        __syncthreads();
        if (kgid < 2) {
#pragma unroll
            for (int mt = 0; mt < 2; ++mt)
#pragma unroll
                for (int r = 0; r < 4; ++r) {
                    const int co = mt * 16 + kq * 4 + r;
                    acc[mt][r] += red[kgid * SL + co * RS + pcolb];
                }
        }
        __syncthreads();
        if (kgid == 1) {
#pragma unroll
            for (int mt = 0; mt < 2; ++mt)
#pragma unroll
                for (int r = 0; r < 4; ++r) {
                    const int co = mt * 16 + kq * 4 + r;
                    red[co * RS + pcolb] = acc[mt][r];
                }
        }
        __syncthreads();
        if (kgid == 0) {
#pragma unroll
            for (int mt = 0; mt < 2; ++mt)
#pragma unroll
                for (int r = 0; r < 4; ++r) {
                    const int co = mt * 16 + kq * 4 + r;
                    acc[mt][r] += red[co * RS + pcolb];
                }
        }
    } else if constexpr (KWAVES == 2) {
        if (kgid == 1) {
#pragma unroll
            for (int mt = 0; mt < 2; ++mt)
#pragma unroll
                for (int r = 0; r < 4; ++r) {
                    const int co = mt * 16 + kq * 4 + r;
                    red[co * RS + pcolb] = acc[mt][r];
                }
        }
        __syncthreads();
        if (kgid == 0) {
#pragma unroll
            for (int mt = 0; mt < 2; ++mt)
#pragma unroll
                for (int r = 0; r < 4; ++r) {
                    const int co = mt * 16 + kq * 4 + r;
                    acc[mt][r] += red[co * RS + pcolb];
                }
        }
    }

    if (kgid == 0) {
        float* ob = om + (size_t)b * 27 * HW + p0 + pcolb;
#pragma unroll
        for (int mt = 0; mt < 2; ++mt)
#pragma unroll
            for (int r = 0; r < 4; ++r) {
                const int co = mt * 16 + kq * 4 + r;
                if (co < 27)
                    ob[(size_t)co * HW] = acc[mt][r] + bias[co];
            }
    }
}

// ---------------- paired sampler: issue / finish ----------------------------
template <int CIN, int HH, int WW, int POS>
__device__ __forceinline__ void sample_issue(
    const float* __restrict__ xb, const uint* __restrict__ eoff2,
    float2* v0, float2* v1, int tt, int kbase)
{
    constexpr int HW = HH * WW;
    const int pp = tt & (POS - 1);
    const int j0 = (tt / POS) * 8;
#pragma unroll
    for (int j = 0; j < 8; ++j) {
        const int kg = kbase + j0 + j;
        const int c  = (kg * 7282) >> 16;       // /9 (exact for kg<2304)
        const int k9 = kg - c * 9;
        const uint e = eoff2[k9 * POS + pp];
        const float* chp = xb + (size_t)c * HW;
        v0[j] = ld2u(chp + (e & 0xffffu));
        v1[j] = ld2u(chp + (e >> 16));
    }
}

template <int CIN, int HH, int WW, int POS, int KS>
__device__ __forceinline__ void sample_finish(
    const float4* __restrict__ ewt, const float2* v0, const float2* v1,
    ushort* __restrict__ Shi, ushort* __restrict__ Slo, int tt, int kbase)
{
    const int pp = tt & (POS - 1);
    const int j0 = (tt / POS) * 8;
    float s[8];
#pragma unroll
    for (int j = 0; j < 8; ++j) {
        const int kg = kbase + j0 + j;
        const int c  = (kg * 7282) >> 16;
        const int k9 = kg - c * 9;
        const float4 wv = ewt[k9 * POS + pp];
        s[j] = v0[j].x * wv.x + v0[j].y * wv.y
             + v1[j].x * wv.z + v1[j].y * wv.w;
    }
    pack_store8<KS>(s, Shi, Slo, pp, j0);
}

template <int CIN, int HH, int WW, int POS, int KS>
__device__ __forceinline__ void sample_chunk(
    const float* __restrict__ xb, const uint* __restrict__ eoff2,
    const float4* __restrict__ ewt, ushort* __restrict__ Shi,
    ushort* __restrict__ Slo, int tt, int kbase)
{
    float2 v0[8], v1[8];
    sample_issue<CIN, HH, WW, POS>(xb, eoff2, v0, v1, tt, kbase);
    sample_finish<CIN, HH, WW, POS, KS>(ewt, v0, v1, Shi, Slo, tt, kbase);
}

// ---------------- fused DCN on MFMA: sample + GEMM + bias + BN + ReLU -------
// M-SPLIT: wave wm owns MTW = 8/NPQ m-tiles x all POS positions (NPT tiles).
template <int CIN, int HH, int WW, int POS, int KWAVES, int MINW,
          bool ASTAGE, bool OMS>
__global__ __launch_bounds__((POS / 16) * KWAVES * 64, MINW) void dcn_mfma_kernel(
    const float* __restrict__ xin,   // (B, CIN, HH, WW)
    const float* __restrict__ om,    // (B, 27, HH, WW)
    const float* __restrict__ omB,   // partial (OMS only)
    const ushort* __restrict__ whi,  // (128, K) bf16 hi, fragment order
    const ushort* __restrict__ wlo,  // (128, K) bf16 lo, fragment order
    const float* __restrict__ bias,
    const float* __restrict__ gam, const float* __restrict__ bet,
    const float* __restrict__ mu,  const float* __restrict__ var,
    float* __restrict__ out)         // (B, 128, HH*WW)
{
    constexpr int HW   = HH * WW;
    constexpr int K    = CIN * 9;
    constexpr int NPQ  = POS / 16;
    constexpr int NT   = NPQ * KWAVES * 64;
    constexpr int KC   = 32;
    constexpr int KS   = 40;
    constexpr int NCHT = K / KC;
    constexpr int NCH  = NCHT / KWAVES;
    constexpr int SBUF = POS * KS;
    constexpr int ABN  = ASTAGE ? 8192 : 0;
    constexpr int MTW  = 8 / NPQ;             // m-tiles per wave
    constexpr int NPT  = POS / 16;            // pos-tiles per wave

    extern __shared__ __align__(16) char smem[];
    uint*    eoff2 = (uint*)smem;
    float4*  ewt   = (float4*)(eoff2 + 9 * POS);
    float*   invp  = (float*)(ewt + 9 * POS);
    float*   shp   = invp + 128;
    ushort*  Abuf  = (ushort*)(shp + 128);
    ushort*  Sbase = Abuf + ABN;

    const int tid = threadIdx.x;
    const int nt  = HW / POS;
    const int cpx = gridDim.x >> 3;
    const int bid = (blockIdx.x & 7) * cpx + (blockIdx.x >> 3);
    const int b   = bid / nt;
    const int p0  = (bid - b * nt) * POS;

    const float* omb  = om + (size_t)b * 27 * HW;
    const float* ombB = OMS ? (omB + (size_t)b * 27 * HW) : nullptr;
    for (int i = tid; i < 9 * POS; i += NT) {
        const int k9 = i / POS, pp = i - k9 * POS;
        const int p  = p0 + pp;
        const int yy = p / WW;
        const int xx = p - yy * WW;
        float oy = omb[(size_t)k9 * HW + p];
        float ox = omb[(size_t)(9 + k9) * HW + p];
        float mv = omb[(size_t)(18 + k9) * HW + p];
        if constexpr (OMS) {
            oy += ombB[(size_t)k9 * HW + p];
            ox += ombB[(size_t)(9 + k9) * HW + p];
            mv += ombB[(size_t)(18 + k9) * HW + p];
        }
        const float m  = 1.0f / (1.0f + expf(-mv));
        const int ky = (k9 * 11) >> 5;
        const int kx = k9 - ky * 3;
        const float py = (float)(yy + ky - 1) + oy;
        const float px = (float)(xx + kx - 1) + ox;
        const float y0f = floorf(py), x0f = floorf(px);
        const int   y0  = (int)y0f,  x0 = (int)x0f;
        const int by0 = min(max(y0, 0), HH - 1);
        const int by1 = min(max(y0 + 1, 0), HH - 1);
        const int bx  = min(max(x0, 0), WW - 2);
        const float wy1 = py - y0f, wx1 = px - x0f;
        const float fy0 = (y0 >= 0  && y0 < HH)     ? (1.f - wy1) * m : 0.f;
        const float fy1 = (y0 >= -1 && y0 < HH - 1) ? wy1 * m         : 0.f;
        const float fx0v = 1.f - wx1, fx1v = wx1;
        float gx0 = 0.f, gx1 = 0.f;
        if (x0 >= 0 && x0 < WW)         { if (x0 == bx)     gx0 += fx0v; else gx1 += fx0v; }
        if (x0 + 1 >= 0 && x0 + 1 < WW) { if (x0 + 1 == bx) gx0 += fx1v; else gx1 += fx1v; }
        eoff2[i] = (uint)(by0 * WW + bx) | ((uint)(by1 * WW + bx) << 16);
        float4 wv; wv.x = fy0 * gx0; wv.y = fy0 * gx1;
                   wv.z = fy1 * gx0; wv.w = fy1 * gx1;
        ewt[i] = wv;
    }
    for (int i = tid; i < 128; i += NT) {
        const float iv = gam[i] * rsqrtf(var[i] + EPSV);
        invp[i] = iv;
        shp[i]  = bet[i] - mu[i] * iv + bias[i] * iv;
    }
    __syncthreads();

    const float* xb   = xin + (size_t)b * CIN * HW;
    const int lane = tid & 63;
    const int w    = tid >> 6;
    const int wm   = w & (NPQ - 1);          // m-group of this wave
    const int kgid = w / NPQ;
    const int tt   = tid & (NPQ * 64 - 1);
    const int m0   = wm * MTW;

    f32x4 acc[8];                             // [mt2][pt] flattened
#pragma unroll
    for (int mt = 0; mt < 8; ++mt) acc[mt] = (f32x4){0.f, 0.f, 0.f, 0.f};

    const int mrow = lane & 15;
    const int kq   = lane >> 4;

    if constexpr (ASTAGE) {
        // ===== single-S-buffer alternating-phase pipeline (A also split) ====
        ushort* Shi = Sbase;
        ushort* Slo = Sbase + SBUF;
        float2 v0[8], v1[8];
        short8 ar0, ar1, ar2, ar3;            // A-stage regs for ch+1
        sample_chunk<CIN, HH, WW, POS, KS>(xb, eoff2, ewt, Shi, Slo, tt, 0);
        {   // stage A(0) directly (once; latency exposed only here)
#pragma unroll
            for (int t = 0; t < 1024 / NT; ++t) {
                const int u = tid + t * NT;
                const ushort* srcp = (u < 512)
                    ? (whi + (size_t)u * 8)
                    : (wlo + (size_t)(u - 512) * 8);
                *(short8*)&Abuf[(size_t)u * 8] = *(const short8*)srcp;
            }
        }
        if (NCH > 1) {
            sample_issue<CIN, HH, WW, POS>(xb, eoff2, v0, v1, tt, KC);
            // issue A-loads(1) into regs (land during MFMA phase)
            const size_t wb = (size_t)1 * 4096;
            const int u0 = tid, u1 = tid + NT, u2 = tid + 2 * NT, u3 = tid + 3 * NT;
            ar0 = *(const short8*)((u0 < 512 ? whi + wb + (size_t)u0 * 8
                                             : wlo + wb + (size_t)(u0 - 512) * 8));
            ar1 = *(const short8*)((u1 < 512 ? whi + wb + (size_t)u1 * 8
                                             : wlo + wb + (size_t)(u1 - 512) * 8));
            ar2 = *(const short8*)((u2 < 512 ? whi + wb + (size_t)u2 * 8
                                             : wlo + wb + (size_t)(u2 - 512) * 8));
            ar3 = *(const short8*)((u3 < 512 ? whi + wb + (size_t)u3 * 8
                                             : wlo + wb + (size_t)(u3 - 512) * 8));
        }
        asm volatile("s_waitcnt lgkmcnt(0)" ::: "memory");
        __builtin_amdgcn_s_barrier();
        __builtin_amdgcn_sched_barrier(0);

        for (int ch = 0; ch < NCH; ++ch) {
            __builtin_amdgcn_s_setprio(1);
            // A fragments for this wave's m-tiles, read ONCE per chunk
            short8 ahv[MTW], alv[MTW];
#pragma unroll
            for (int mt2 = 0; mt2 < MTW; ++mt2) {
                const int au = ((m0 + mt2) * 64 + lane) * 8;
                ahv[mt2] = *(const short8*)&Abuf[au];
                alv[mt2] = *(const short8*)&Abuf[4096 + au];
            }
#pragma unroll
            for (int pt = 0; pt < NPT; ++pt) {
                const int boff = (pt * 16 + mrow) * KS + kq * 8;
                const short8 bh = *(const short8*)&Shi[boff];
                const short8 bl = *(const short8*)&Slo[boff];
#pragma unroll
                for (int mt2 = 0; mt2 < MTW; ++mt2) {
                    f32x4 a = acc[mt2 * NPT + pt];
                    a = __builtin_amdgcn_mfma_f32_16x16x32_bf16(alv[mt2], bh, a, 0, 0, 0);
                    a = __builtin_amdgcn_mfma_f32_16x16x32_bf16(ahv[mt2], bl, a, 0, 0, 0);
                    a = __builtin_amdgcn_mfma_f32_16x16x32_bf16(ahv[mt2], bh, a, 0, 0, 0);
                    acc[mt2 * NPT + pt] = a;
                }
            }
            __builtin_amdgcn_s_setprio(0);
            if (ch + 1 < NCH) {
                asm volatile("s_waitcnt lgkmcnt(0)" ::: "memory");
                __builtin_amdgcn_s_barrier();
                __builtin_amdgcn_sched_barrier(0);
                // ---- write phase: ds_write A(ch+1) from regs (loads landed),
                //      finish gathers -> S, issue next gathers + next A ----
                {
                    const int u0 = tid, u1 = tid + NT;
                    const int u2 = tid + 2 * NT, u3 = tid + 3 * NT;
                    *(short8*)&Abuf[(size_t)u0 * 8] = ar0;
                    *(short8*)&Abuf[(size_t)u1 * 8] = ar1;
                    *(short8*)&Abuf[(size_t)u2 * 8] = ar2;
                    *(short8*)&Abuf[(size_t)u3 * 8] = ar3;
                }
                sample_finish<CIN, HH, WW, POS, KS>(ewt, v0, v1, Shi, Slo,
                                                    tt, (ch + 1) * KC);
                if (ch + 2 < NCH) {
                    sample_issue<CIN, HH, WW, POS>(xb, eoff2, v0, v1, tt,
                                                   (ch + 2) * KC);
                    const size_t wb = (size_t)(ch + 2) * 4096;
                    const int u0 = tid, u1 = tid + NT;
                    const int u2 = tid + 2 * NT, u3 = tid + 3 * NT;
                    ar0 = *(const short8*)((u0 < 512 ? whi + wb + (size_t)u0 * 8
                                                     : wlo + wb + (size_t)(u0 - 512) * 8));
                    ar1 = *(const short8*)((u1 < 512 ? whi + wb + (size_t)u1 * 8
                                                     : wlo + wb + (size_t)(u1 - 512) * 8));
                    ar2 = *(const short8*)((u2 < 512 ? whi + wb + (size_t)u2 * 8
                                                     : wlo + wb + (size_t)(u2 - 512) * 8));
                    ar3 = *(const short8*)((u3 < 512 ? whi + wb + (size_t)u3 * 8
                                                     : wlo + wb + (size_t)(u3 - 512) * 8));
                }
                asm volatile("s_waitcnt lgkmcnt(0)" ::: "memory");
                __builtin_amdgcn_s_barrier();
                __builtin_amdgcn_sched_barrier(0);
            }
        }
    } else {
        ushort* S00 = Sbase + kgid * (4 * SBUF);
        sample_chunk<CIN, HH, WW, POS, KS>(xb, eoff2, ewt, S00, S00 + SBUF,
                                           tt, kgid * NCH * KC);
        __syncthreads();

        for (int ch = 0; ch < NCH; ++ch) {
            const int cur = ch & 1;
            ushort* Sc = S00 + (cur * 2) * SBUF;
            // B fragments for all pos-tiles (held across the sampler)
            short8 bhv[NPT], blv[NPT];
#pragma unroll
            for (int pt = 0; pt < NPT; ++pt) {
                const int boff = (pt * 16 + mrow) * KS + kq * 8;
                bhv[pt] = *(const short8*)&Sc[boff];
                blv[pt] = *(const short8*)&Sc[SBUF + boff];
            }
            if (ch + 1 < NCH) {
                ushort* Sn = S00 + ((cur ^ 1) * 2) * SBUF;
                sample_chunk<CIN, HH, WW, POS, KS>(xb, eoff2, ewt,
                                                   Sn, Sn + SBUF, tt,
                                                   (kgid * NCH + ch + 1) * KC);
            }
            // A fragments just-in-time from global (fragment order, coalesced)
            const size_t abase = (size_t)((kgid * NCH + ch) * 8) * 512;
            __builtin_amdgcn_s_setprio(1);
#pragma unroll
            for (int mt2 = 0; mt2 < MTW; ++mt2) {
                const size_t ao = abase + (size_t)(((m0 + mt2) * 64 + lane) * 8);
                const short8 ah = *(const short8*)(whi + ao);
                const short8 al = *(const short8*)(wlo + ao);
#pragma unroll
                for (int pt = 0; pt < NPT; ++pt) {
                    f32x4 a = acc[mt2 * NPT + pt];
                    a = __builtin_amdgcn_mfma_f32_16x16x32_bf16(al, bhv[pt], a, 0, 0, 0);
                    a = __builtin_amdgcn_mfma_f32_16x16x32_bf16(ah, blv[pt], a, 0, 0, 0);
                    a = __builtin_amdgcn_mfma_f32_16x16x32_bf16(ah, bhv[pt], a, 0, 0, 0);
                    acc[mt2 * NPT + pt] = a;
                }
            }
            __builtin_amdgcn_s_setprio(0);
            __syncthreads();
        }
    }

    constexpr int RS = POS + 1;
    constexpr int SL = 128 * RS;
    float* red = (float*)Sbase;

    if constexpr (KWAVES == 4) {
        if (kgid >= 2) {
#pragma unroll
            for (int mt2 = 0; mt2 < MTW; ++mt2)
#pragma unroll
                for (int pt = 0; pt < NPT; ++pt)
#pragma unroll
                    for (int r = 0; r < 4; ++r) {
                        const int co = (m0 + mt2) * 16 + kq * 4 + r;
                        red[(kgid - 2) * SL + co * RS + pt * 16 + mrow] =
                            acc[mt2 * NPT + pt][r];
                    }
        }
        __syncthreads();
        if (kgid < 2) {
#pragma unroll
            for (int mt2 = 0; mt2 < MTW; ++mt2)
#pragma unroll
                for (int pt = 0; pt < NPT; ++pt)
#pragma unroll
                    for (int r = 0; r < 4; ++r) {
                        const int co = (m0 + mt2) * 16 + kq * 4 + r;
                        acc[mt2 * NPT + pt][r] +=
                            red[kgid * SL + co * RS + pt * 16 + mrow];
                    }
        }
        __syncthreads();
        if (kgid == 1) {
#pragma unroll
            for (int mt2 = 0; mt2 < MTW; ++mt2)
#pragma unroll
                for (int pt = 0; pt < NPT; ++pt)
#pragma unroll
                    for (int r = 0; r < 4; ++r) {
                        const int co = (m0 + mt2) * 16 + kq * 4 + r;
                        red[co * RS + pt * 16 + mrow] = acc[mt2 * NPT + pt][r];
                    }
        }
        __syncthreads();
        if (kgid == 0) {
#pragma unroll
            for (int mt2 = 0; mt2 < MTW; ++mt2)
#pragma unroll
                for (int pt = 0; pt < NPT; ++pt)
#pragma unroll
                    for (int r = 0; r < 4; ++r) {
                        const int co = (m0 + mt2) * 16 + kq * 4 + r;
                        acc[mt2 * NPT + pt][r] += red[co * RS + pt * 16 + mrow];
                    }
        }
    } else if constexpr (KWAVES == 2) {
        if (kgid == 1) {
#pragma unroll
            for (int mt2 = 0; mt2 < MTW; ++mt2)
#pragma unroll
                for (int pt = 0; pt < NPT; ++pt)
#pragma unroll
                    for (int r = 0; r < 4; ++r) {
                        const int co = (m0 + mt2) * 16 + kq * 4 + r;
                        red[co * RS + pt * 16 + mrow] = acc[mt2 * NPT + pt][r];
                    }
        }
        __syncthreads();
        if (kgid == 0) {
#pragma unroll
            for (int mt2 = 0; mt2 < MTW; ++mt2)
#pragma unroll
                for (int pt = 0; pt < NPT; ++pt)
#pragma unroll
                    for (int r = 0; r < 4; ++r) {
                        const int co = (m0 + mt2) * 16 + kq * 4 + r;
                        acc[mt2 * NPT + pt][r] += red[co * RS + pt * 16 + mrow];
                    }
        }
    }

    if (kgid == 0) {
        float* outb = out + (size_t)b * 128 * HW + p0;
#pragma unroll
        for (int mt2 = 0; mt2 < MTW; ++mt2)
#pragma unroll
            for (int pt = 0; pt < NPT; ++pt)
#pragma unroll
                for (int r = 0; r < 4; ++r) {
                    const int co = (m0 + mt2) * 16 + kq * 4 + r;
                    outb[(size_t)co * HW + pt * 16 + mrow] =
                        fmaxf(acc[mt2 * NPT + pt][r] * invp[co] + shp[co], 0.f);
                }
    }
}

// ---------------- depthwise transposed-conv upsample x2 (k=4, pad 2) --------
__global__ __launch_bounds__(256) void upsample_kernel(
    const float* __restrict__ y,    // (4,128,64,64)
    const float* __restrict__ wup,  // (128,1,4,4)
    float* __restrict__ out)        // (4,128,128,128)
{
    const int idx = blockIdx.x * 256 + threadIdx.x;
    const int ox = idx & 127;
    const int oy = (idx >> 7) & 127;
    const int c  = (idx >> 14) & 127;
    const int b  = idx >> 21;

    const float* yc = y + (size_t)(b * 128 + c) * 4096;
    const float* wc = wup + c * 16;

    float acc = 0.f;
#pragma unroll
    for (int ky = 0; ky < 4; ++ky) {
        const int qy = oy + ky - 2;
        if (qy & 1) continue;
        const int iy = qy >> 1;
        if (iy < 0 || iy >= 64) continue;
#pragma unroll
        for (int kx = 0; kx < 4; ++kx) {
            const int qx = ox + kx - 2;
            if (qx & 1) continue;
            const int ix = qx >> 1;
            if (ix < 0 || ix >= 64) continue;
            acc += yc[iy * 64 + ix] * wc[(3 - ky) * 4 + (3 - kx)];
        }
    }
    out[idx] = acc;
}

// ---------------------------------------------------------------------------
extern "C" void kernel_launch(void* const* d_in, const int* in_sizes, int n_in,
                              void* d_out, int out_size, void* d_ws, size_t ws_size,
                              hipStream_t stream) {
    const float* x      = (const float*)d_in[0];
    const float* w_off1 = (const float*)d_in[1];
    const float* b_off1 = (const float*)d_in[2];
    const float* w1     = (const float*)d_in[3];
    const float* b1     = (const float*)d_in[4];
    const float* g1v    = (const float*)d_in[5];
    const float* be1    = (const float*)d_in[6];
    const float* m1     = (const float*)d_in[7];
    const float* v1     = (const float*)d_in[8];
    const float* w_up   = (const float*)d_in[9];
    const float* w_off2 = (const float*)d_in[10];
    const float* b_off2 = (const float*)d_in[11];
    const float* w2     = (const float*)d_in[12];
    const float* b2     = (const float*)d_in[13];
    const float* g2v    = (const float*)d_in[14];
    const float* be2    = (const float*)d_in[15];
    const float* m2     = (const float*)d_in[16];
    const float* v2     = (const float*)d_in[17];

    float* ws  = (float*)d_ws;
    float* om1 = ws;                     // 4*27*4096   =   442368 f
    float* y1  = om1 + 442368;           // 4*128*4096  =  2097152 f
    float* up  = y1 + 2097152;           // 4*128*16384 =  8388608 f
    float* om2 = up + 8388608;           // 4*27*16384  =  1769472 f
    float* outf = (float*)d_out;

    // `up` region (dead until upsample writes it): w1 + w_off1 splits
    ushort* w1hi  = (ushort*)up;         // 294912
    ushort* w1lo  = w1hi + 294912;       // 294912
    ushort* wo1hi = w1lo + 294912;       // 32*2304 = 73728
    ushort* wo1lo = wo1hi + 73728;       // 73728
    // `y1` region (dead after upsample reads it): w2 + w_off2 splits
    ushort* w2hi  = (ushort*)y1;         // 147456
    ushort* w2lo  = w2hi + 147456;       // 147456
    ushort* wo2hi = w2lo + 147456;       // 32*1152 = 36864
    ushort* wo2lo = wo2hi + 36864;       // 36864

    // prep: w1 (dcn1) + w_off1 (conv1) splits, fragment order
    wsplit_perm_kernel<<<(294912 + 255) / 256, 256, 0, stream>>>(
        w1, w1hi, w1lo, 256, 294912);
    wsplit_perm_conv_kernel<<<(73728 + 255) / 256, 256, 0, stream>>>(
        w_off1, wo1hi, wo1lo, 256, 73728);

    // om1 = conv3x3(x, w_off1) + b_off1 — MFMA, POS=16, KWAVES=4
    conv_mfma_kernel<256, 64, 64, 16, 4, 4>
        <<<1024, 256, 21632, stream>>>(x, wo1hi, wo1lo, b_off1, om1);

    // y1 = bn_relu(dcn1) — MFMA, POS=32, 4-way K-split, M-split waves
    dcn_mfma_kernel<256, 64, 64, 32, 4, 4, false, false>
        <<<4 * (4096 / 32), 512, 47744, stream>>>(
        x, om1, om1, w1hi, w1lo, b1, g1v, be1, m1, v1, y1);
    // up = depthwise transposed upsample (clobbers w1/wo1 splits — now dead)
    upsample_kernel<<<8388608 / 256, 256, 0, stream>>>(y1, w_up, up);

    // prep: w2 (dcn2) + w_off2 (conv2) splits (y1 now dead)
    wsplit_perm_kernel<<<(147456 + 255) / 256, 256, 0, stream>>>(
        w2, w2hi, w2lo, 128, 147456);
    wsplit_perm_conv_kernel<<<(36864 + 255) / 256, 256, 0, stream>>>(
        w_off2, wo2hi, wo2lo, 128, 36864);

    // om2 = conv3x3(up, w_off2) + b_off2 — MFMA, POS=64, KWAVES=1
    conv_mfma_kernel<128, 128, 128, 64, 1, 4>
        <<<1024, 256, 25088, stream>>>(up, wo2hi, wo2lo, b_off2, om2);

    // out = bn_relu(dcn2) — MFMA, POS=64, A-staged (split), single-S, M-split
    dcn_mfma_kernel<128, 128, 128, 64, 1, 4, true, false>
        <<<4 * (16384 / 64), 256, 39168, stream>>>(
        up, om2, om2, w2hi, w2lo, b2, g2v, be2, m2, v2, outf);
}